// Round 12
// baseline (242.854 us; speedup 1.0000x reference)
//
#include <hip/hip_runtime.h>
#include <hip/hip_bf16.h>

// GravNetConv: N=16384, C_IN=128, S=4, P=32, K=16, C_OUT=128.
// Mask-free list path: [k1] proj (fp64 s) -> [k2t] threshold + FUSED operand pack
// (+ t2 store) -> [k2b_mfma] N^2 Gram via mfma_f32_32x32x16_bf16; per-lane predicate
// words decoded IN-KERNEL to compact per-(q, j-quarter) candidate lists (single
// writer per region, register cursor, no atomics; LCAP=24, u16 count) ->
// [k3_sel2] prefix-sum list gather (+ exact-predicate rescan for overflowed
// quarters) -> exact fp32 re-rank (r10 machinery) -> aggregation ->
// [k4a/k4_out2] out = x@W1^T + agg@W2^T + b2.
// Fallback path (ws_size < 41MB): round-2 kernels.

#define NPTS 16384
#define CIN  128
#define SD   4
#define PD   32
#define KNN  16
#define COUT 128
#define FLTMAX 3.4028234663852886e+38f
#define NBIN 33
#define QPB  8      // k3 queries per block
#define QCAP 512    // per-query candidate cap
#define MCAP 192    // k3 per-query qualifier cap (ultra-rare recompute fallback beyond)
#define LCAP 24     // per-(q, j-quarter) list cap; overflow -> exact rescan in k3
#define EPAD 1e-3f  // mask-inclusion pad >> bf16x2 Gram error bound (~2e-4)

typedef float v2f __attribute__((ext_vector_type(2)));
typedef unsigned int uint;
typedef unsigned long long u64;
typedef unsigned short u16;
typedef __attribute__((ext_vector_type(8))) short bf16x8;
typedef __attribute__((ext_vector_type(16))) float f32x16;

// ---- shared offsets (both paths) ----
#define WS_S4     0            // N * float4 = 256 KB
#define WS_H      0x40000      // N * 32 f32 = 2 MB
// ---- list-path offsets ----
#define WS_AGG_M  0x280000     // [N][64] f32 = 4 MB (written by k3, after k2b)
#define WS_SA     0x280000     // aliases AGG: N*16 bf16 = 512 KB, dead before k3
#define WS_SB     0x300000     // aliases AGG: N*16 bf16 = 512 KB, dead before k3
#define WS_WT_M   0x680000     // [192][128] f32 = 96 KB
#define WS_T2     0x6A0000     // N f32 = 64 KB
#define WS_JLIST  0x700000     // 16 * N * LCAP u16 = 12 MB
#define WS_JCNT   0x1300000    // 16 * N u16 = 512 KB
#define WS_NEED_M 0x2700000    // 40.9 MB gate (unchanged)
// ---- fallback offsets ----
#define WS_CJ_F   0x400000
#define WS_AGG_F  0xC00000
#define WS_WT_F   0x1000000
#define JS   16
#define TJF  (NPTS/JS)

__device__ __forceinline__ float d2f(const float4 a, const float4 b) {
  v2f d0 = {a.x - b.x, a.y - b.y};
  v2f d1 = {a.z - b.z, a.w - b.w};
  v2f pr = d0*d0 + d1*d1;
  return pr.x + pr.y;
}

__device__ __forceinline__ u16 f2bf(float x) {   // RNE float->bf16
  uint u = __float_as_uint(x);
  uint r = (u + 0x7FFFu + ((u >> 16) & 1u)) >> 16;
  return (u16)r;
}
__device__ __forceinline__ float bf2f(u16 h) {
  return __uint_as_float(((uint)h) << 16);
}

// ---------------- Kernel 1: s (fp64 accumulate) and h projections ----------------
__global__ __launch_bounds__(256) void k1_proj(
    const float* __restrict__ x, const float* __restrict__ Ws, const float* __restrict__ bs,
    const float* __restrict__ Wh, const float* __restrict__ bh,
    float4* __restrict__ s4, float* __restrict__ h) {
  __shared__ float  lw[36*128];
  __shared__ float  lx[64*132];
  __shared__ double rs[3*64*5];
  __shared__ float  rh[3*64*33];
  const int t = threadIdx.x;
  const int row0 = blockIdx.x * 64;
  for (int i2 = t; i2 < 36*128; i2 += 256)
    lw[i2] = (i2 < 512) ? Ws[i2] : Wh[i2 - 512];
#pragma unroll
  for (int g = 0; g < 8; ++g) {
    int fi = g*256 + t;
    int r = fi >> 5, c4 = fi & 31;
    *(float4*)&lx[r*132 + c4*4] = *(const float4*)&x[(size_t)(row0 + r)*CIN + c4*4];
  }
  __syncthreads();
  const int kq = t >> 6;
  const int r  = t & 63;
  const int kb = kq * 32;
  double sacc[4] = {0.0, 0.0, 0.0, 0.0};
  float  hacc[32];
#pragma unroll
  for (int p = 0; p < 32; ++p) hacc[p] = 0.f;
#pragma unroll
  for (int k4 = 0; k4 < 8; ++k4) {
    float4 xv = *(const float4*)&lx[r*132 + kb + k4*4];
    int kg = kb + k4*4;
#pragma unroll
    for (int p = 0; p < 4; ++p) {
      float4 wv = *(const float4*)&lw[p*128 + kg];
      sacc[p] = fma((double)xv.x, (double)wv.x, sacc[p]);
      sacc[p] = fma((double)xv.y, (double)wv.y, sacc[p]);
      sacc[p] = fma((double)xv.z, (double)wv.z, sacc[p]);
      sacc[p] = fma((double)xv.w, (double)wv.w, sacc[p]);
    }
#pragma unroll
    for (int p = 0; p < 32; ++p) {
      float4 wv = *(const float4*)&lw[(4+p)*128 + kg];
      hacc[p] = fmaf(xv.x, wv.x, fmaf(xv.y, wv.y, fmaf(xv.z, wv.z, fmaf(xv.w, wv.w, hacc[p]))));
    }
  }
  if (kq > 0) {
    const int bq = kq - 1;
#pragma unroll
    for (int d = 0; d < 4; ++d) rs[(bq*64 + r)*5 + d] = sacc[d];
#pragma unroll
    for (int p = 0; p < 32; ++p) rh[(bq*64 + r)*33 + p] = hacc[p];
  }
  __syncthreads();
  if (kq == 0) {
    const int row = row0 + r;
    float so[4];
#pragma unroll
    for (int d = 0; d < 4; ++d) {
      double sd = sacc[d] + rs[(0*64 + r)*5 + d] + rs[(1*64 + r)*5 + d]
                + rs[(2*64 + r)*5 + d] + (double)bs[d];
      so[d] = (float)sd;
    }
    s4[row] = make_float4(so[0], so[1], so[2], so[3]);
#pragma unroll
    for (int p4 = 0; p4 < 8; ++p4) {
      float o[4];
#pragma unroll
      for (int c = 0; c < 4; ++c) {
        int p = p4*4 + c;
        o[c] = hacc[p] + rh[(0*64 + r)*33 + p] + rh[(1*64 + r)*33 + p]
             + rh[(2*64 + r)*33 + p] + bh[p];
      }
      *(float4*)&h[(size_t)row*PD + p4*4] = make_float4(o[0], o[1], o[2], o[3]);
    }
  }
}

// ---------------- Kernel 2t: threshold via radix-ladder histogram + FUSED pack ------
__global__ __launch_bounds__(256) void k2t_thresh(
    const float4* __restrict__ s4, uint4* __restrict__ sA, uint4* __restrict__ sB,
    float* __restrict__ t2g) {
  __shared__ float4 tile[2064];
  __shared__ uint   lhist[256*NBIN];
  const int t = threadIdx.x;
#pragma unroll
  for (int g = 0; g < 8; ++g) {
    int j = g*256 + t;
    tile[j + (j >> 7)] = s4[j];
  }
#pragma unroll
  for (int b = 0; b < NBIN; ++b) lhist[t*NBIN + b] = 0u;
  const int ql = t >> 4, tq = t & 15;
  const int q  = blockIdx.x*16 + ql;
  const float4 sq = s4[q];
  __syncthreads();
  float tau = d2f(sq, tile[tq*129]);
#pragma unroll
  for (int m = 1; m < 16; m <<= 1) tau = fmaxf(tau, __shfl_xor(tau, m, 16));
  const int ktop = (int)(__float_as_uint(tau) >> 21);
  const int hb = t*NBIN;
#pragma unroll 4
  for (int u = 0; u < 128; ++u) {
    float4 p = tile[tq*129 + u];
    float e = d2f(sq, p);
    int key = (int)(__float_as_uint(e) >> 21);
    int rel = ktop - key;
    rel = rel < 0 ? 0 : (rel > 32 ? 32 : rel);
    atomicAdd(&lhist[hb + rel], 1u);
  }
  __syncthreads();
  uint c0 = 0, c1 = 0;
  const int qb = ql*16;
  for (int u = 0; u < 16; ++u) {
    c0 += lhist[(qb + u)*NBIN + tq*2];
    c1 += (tq*2 + 1 < NBIN) ? lhist[(qb + u)*NBIN + tq*2 + 1] : 0u;
  }
  int S = (int)(c0 + c1);
#pragma unroll
  for (int d = 1; d < 16; d <<= 1) {
    int v = __shfl_down(S, d, 16);
    S += (tq + d < 16) ? v : 0;
  }
  int g = -1;
  if (S >= KNN) g = 2*tq;
  if (S - (int)c0 >= KNN) g = 2*tq + 1;
#pragma unroll
  for (int m = 1; m < 16; m <<= 1) g = max(g, __shfl_xor(g, m, 16));
  if (tq == 0) {
    uint K = (uint)(ktop - g);
    const float tv = __uint_as_float((K << 21) | 0x1FFFFFu);
    t2g[q] = tv;
    // ---- fused pack ----
    float sv[4] = {sq.x, sq.y, sq.z, sq.w};
    const float n2 = sq.x*sq.x + sq.y*sq.y + sq.z*sq.z + sq.w*sq.w;
    u16 hbv[4], lbv[4];
#pragma unroll
    for (int d = 0; d < 4; ++d) {
      u16 hh = f2bf(sv[d]);
      hbv[d] = hh;
      lbv[d] = f2bf(sv[d] - bf2f(hh));
    }
    const float aq = -0.5f*(n2 - tv) + EPAD;
    const float bn = -0.5f*n2;
    u16 aqh = f2bf(aq); u16 aql = f2bf(aq - bf2f(aqh));
    u16 bnh = f2bf(bn); u16 bnl = f2bf(bn - bf2f(bnh));
    const uint oneone = 0x3F803F80u;
    uint a0 = (uint)hbv[0] | ((uint)hbv[1] << 16);
    uint a1 = (uint)hbv[2] | ((uint)hbv[3] << 16);
    uint l0 = (uint)lbv[0] | ((uint)lbv[1] << 16);
    uint l1 = (uint)lbv[2] | ((uint)lbv[3] << 16);
    uint aqw = (uint)aqh | ((uint)aql << 16);
    uint bnw = (uint)bnh | ((uint)bnl << 16);
    uint4 A0; A0.x = a0; A0.y = a1; A0.z = a0; A0.w = a1;
    uint4 A1; A1.x = l0; A1.y = l1; A1.z = oneone; A1.w = aqw;
    uint4 B0; B0.x = a0; B0.y = a1; B0.z = l0; B0.w = l1;
    uint4 B1; B1.x = a0; B1.y = a1; B1.z = bnw; B1.w = oneone;
    sA[(size_t)q*2]     = A0;
    sA[(size_t)q*2 + 1] = A1;
    sB[(size_t)q*2]     = B0;
    sB[(size_t)q*2 + 1] = B1;
  }
}

// per-lane pack of 16 predicate bits from a 32x32 MFMA accumulator.
__device__ __forceinline__ uint packbits16(const f32x16 a, const int shft) {
  uint b[4];
#pragma unroll
  for (int g = 0; g < 4; ++g) {
    uint bg = 0u;
#pragma unroll
    for (int e = 3; e >= 0; --e)
      bg = bg + bg + ((~__float_as_uint(a[4*g + e])) >> 31);
    b[g] = bg;
  }
  return (b[0] | (b[1] << 8) | (b[2] << 16) | (b[3] << 24)) << shft;
}

// ---------------- Kernel 2b: N^2 Gram via 32x32x16 MFMA -> compact candidate lists ---
// Block: 4 waves x 64 q = 256 q, x 1024 j (quarter jq = blockIdx&15). Lane ln owns
// query qbase+ln; after shfl_xor(32) merge it holds the full predicate word and
// appends candidate j's to its PRIVATE region jlist[(jq*N+q)*LCAP ...] with a
// register cursor (no atomics, single writer). Count (may exceed LCAP) -> jcnt.
__global__ __launch_bounds__(256) void k2b_mfma(
    const u16* __restrict__ sA, const u16* __restrict__ sB,
    u16* __restrict__ jlist, u16* __restrict__ jcnt) {
  __shared__ u16 lB[1024*16];                // 32 KB: 1024 j-rows x 32 B
  const int t   = threadIdx.x;
  const int wv  = t >> 6, ln = t & 63;
  const int l31 = ln & 31, hi = ln >> 5;
  const int jq  = blockIdx.x & 15;
  const int qbase = (blockIdx.x >> 4) * 256 + wv * 64;
  const int j0    = jq * 1024;
  for (int r = t; r < 1024; r += 256) {
    const uint4* src = (const uint4*)&sB[(size_t)(j0 + r)*16];
    uint4 v0 = src[0], v1 = src[1];
    *(uint4*)&lB[r*16]     = v0;
    *(uint4*)&lB[r*16 + 8] = v1;
  }
  const bf16x8 qf0 = *(const bf16x8*)&sA[(size_t)(qbase + l31)*16 + hi*8];
  const bf16x8 qf1 = *(const bf16x8*)&sA[(size_t)(qbase + 32 + l31)*16 + hi*8];
  __syncthreads();
  const int sh = hi * 4;
  const f32x16 zc = {0.f,0.f,0.f,0.f,0.f,0.f,0.f,0.f,0.f,0.f,0.f,0.f,0.f,0.f,0.f,0.f};
  int cur = 0;
  const size_t lbase = ((size_t)jq*NPTS + (qbase + ln))*LCAP;
#pragma unroll 1
  for (int cc = 0; cc < 8; ++cc) {
    uint w0[4], w1[4];
#pragma unroll
    for (int jt = 0; jt < 4; ++jt) {
      const bf16x8 af = *(const bf16x8*)&lB[(cc*128 + jt*32 + l31)*16 + hi*8];
      f32x16 a0 = __builtin_amdgcn_mfma_f32_32x32x16_bf16(af, qf0, zc, 0, 0, 0);
      f32x16 a1 = __builtin_amdgcn_mfma_f32_32x32x16_bf16(af, qf1, zc, 0, 0, 0);
      w0[jt] = packbits16(a0, sh);
      w1[jt] = packbits16(a1, sh);
    }
#pragma unroll
    for (int jt = 0; jt < 4; ++jt) {
      uint f0 = w0[jt] | (uint)__shfl_xor((int)w0[jt], 32);
      uint f1 = w1[jt] | (uint)__shfl_xor((int)w1[jt], 32);
      uint bits = hi ? f1 : f0;
      const int jb = j0 + cc*128 + jt*32;
      while (bits) {
        int b = __builtin_ctz(bits); bits &= bits - 1;
        if (cur < LCAP) jlist[lbase + cur] = (u16)(jb + b);
        ++cur;
      }
    }
  }
  jcnt[(size_t)jq*NPTS + qbase + ln] = (u16)cur;
}

// ---------------- Kernel 3: list gather + exact re-rank + aggregation ----------------
// block = 8 queries x 32 lanes. Phase A: 16 region counts -> shfl prefix ->
// binary-search copy of list entries (2-way ILP); overflowed quarters (cnt>LCAP)
// rescanned with the EXACT predicate d2 <= t2+2*EPAD (superset-correct).
// Downstream (pass1/hist/boundary/compact/rank/agg) identical to r10.
__global__ __launch_bounds__(256) void k3_sel2(
    const float4* __restrict__ s4, const float* __restrict__ h,
    const u16* __restrict__ jlist, const u16* __restrict__ jcnt,
    const float* __restrict__ t2g, float* __restrict__ agg) {
  __shared__ unsigned short jl[QPB*QCAP];   // 8 KB
  __shared__ u16  cls[QPB*QCAP];            // 8 KB
  __shared__ u64  qbuf[QPB*MCAP];           // 12 KB
  __shared__ u64  win[QPB*KNN];             // 1 KB
  __shared__ uint hist[QPB*32];             // 1 KB
  __shared__ uint po[QPB*18];               // offsets + total
  __shared__ uint ovfl[QPB];
  __shared__ uint cnts[QPB];
  __shared__ uint mc[QPB];
  const int t  = threadIdx.x;
  const int ql = t >> 5, ln = t & 31;
  const int q  = blockIdx.x*QPB + ql;
  if (ln == 0) { mc[ql] = 0u; ovfl[ql] = 0u; }
  hist[ql*32 + ln] = 0u;
  if (ln < KNN) win[ql*KNN + ln] = 0ull;
  const float4 sq = s4[q];
  __syncthreads();
  // ---- phase A0: region counts, overflow flags, prefix sum ----
  uint eff = 0;
  if (ln < 16) {
    uint cr = (uint)jcnt[(size_t)ln*NPTS + q];
    if (cr > (uint)LCAP) { atomicOr(&ovfl[ql], 1u << ln); eff = 0u; }
    else eff = cr;
  }
  uint inc = eff;
#pragma unroll
  for (int d = 1; d < 16; d <<= 1) {
    uint v = (uint)__shfl_up((int)inc, d, 16);
    if ((ln & 15) >= d) inc += v;
  }
  if (ln < 16) po[ql*18 + ln] = inc - eff;
  if (ln == 15) po[ql*18 + 16] = inc;
  __syncthreads();
  // ---- phase A1: copy normal entries (binary-search region, 2-way ILP) ----
  const int Tn = (int)po[ql*18 + 16];
  {
    int u = ln;
    for (; u + 32 < Tn; u += 64) {
      int ua = u, ub = u + 32;
      int ra = 0, rb = 0;
#pragma unroll
      for (int st = 8; st > 0; st >>= 1) {
        int ca = ra + st, cb2 = rb + st;
        if (ca <= 15 && (int)po[ql*18 + ca] <= ua) ra = ca;
        if (cb2 <= 15 && (int)po[ql*18 + cb2] <= ub) rb = cb2;
      }
      u16 va = jlist[((size_t)ra*NPTS + q)*LCAP + (ua - (int)po[ql*18 + ra])];
      u16 vb = jlist[((size_t)rb*NPTS + q)*LCAP + (ub - (int)po[ql*18 + rb])];
      jl[ql*QCAP + ua] = va;
      jl[ql*QCAP + ub] = vb;
    }
    if (u < Tn) {
      int r = 0;
#pragma unroll
      for (int st = 8; st > 0; st >>= 1) {
        int c = r + st;
        if (c <= 15 && (int)po[ql*18 + c] <= u) r = c;
      }
      jl[ql*QCAP + u] = jlist[((size_t)r*NPTS + q)*LCAP + (u - (int)po[ql*18 + r])];
    }
  }
  if (ln == 0) cnts[ql] = (uint)Tn;
  __syncthreads();
  // ---- phase A2: overflow rescan (rare) with exact predicate ----
  uint ofm = ovfl[ql];
  if (ofm) {
    const float lim = t2g[q] + 2.f*EPAD;
    while (ofm) {
      int r = __builtin_ctz(ofm); ofm &= ofm - 1;
      const int jend = r*1024 + 1024;
      for (int jj = r*1024 + ln; jj < jend; jj += 32) {
        float e = d2f(sq, s4[jj]);
        if (e <= lim) {
          uint pos = atomicAdd(&cnts[ql], 1u);
          if (pos < QCAP) jl[ql*QCAP + pos] = (unsigned short)jj;
        }
      }
    }
  }
  __syncthreads();
  const int cnt = min((int)cnts[ql], QCAP);
  // ---- pass 1: gather d2 once (2-way ILP), store class, track kmax ----
  uint kmax = 0u;
  {
    int u = ln;
    for (; u + 32 < cnt; u += 64) {
      int ja = jl[ql*QCAP + u];
      int jb = jl[ql*QCAP + u + 32];
      float ea = d2f(sq, s4[ja]);
      float eb = d2f(sq, s4[jb]);
      uint ca = __float_as_uint(ea) >> 21;
      uint cb = __float_as_uint(eb) >> 21;
      cls[ql*QCAP + u]      = (u16)ca;
      cls[ql*QCAP + u + 32] = (u16)cb;
      kmax = max(kmax, max(ca, cb));
    }
    if (u < cnt) {
      int j = jl[ql*QCAP + u];
      float e = d2f(sq, s4[j]);
      uint cv = __float_as_uint(e) >> 21;
      cls[ql*QCAP + u] = (u16)cv;
      kmax = max(kmax, cv);
    }
  }
#pragma unroll
  for (int m2 = 1; m2 < 32; m2 <<= 1) kmax = max(kmax, (uint)__shfl_xor((int)kmax, m2, 32));
  for (int u = ln; u < cnt; u += 32) {
    uint cv = cls[ql*QCAP + u];
    uint rel = min(kmax - cv, 31u);
    atomicAdd(&hist[ql*32 + rel], 1u);
  }
  __syncthreads();
  // ---- boundary: largest r* with cum(r*) >= need; bcls = kmax - r* ----
  uint cum = hist[ql*32 + ln];
#pragma unroll
  for (int d = 1; d < 32; d <<= 1) {
    uint v = (uint)__shfl_down((int)cum, d, 32);
    if (ln + d < 32) cum += v;
  }
  const uint need = (uint)(cnt < KNN ? cnt : KNN);
  u64 bal = __ballot(cum >= need);
  uint half = (uint)(bal >> (((t >> 5) & 1) * 32));
  const uint rstar = 31u - (uint)__builtin_clz(half);
  const uint bcls = kmax - rstar;
  __syncthreads();
  // ---- compact qualifiers: recompute exact d2 (bit-identical), build u64 key ----
  for (int u = ln; u < cnt; u += 32) {
    if ((uint)cls[ql*QCAP + u] <= bcls) {
      int j = jl[ql*QCAP + u];
      float e = d2f(sq, s4[j]);
      u64 key = ((u64)__float_as_uint(e) << 14) | (uint)j;
      uint pos = atomicAdd(&mc[ql], 1u);
      if (pos < MCAP) qbuf[ql*MCAP + pos] = key;
    }
  }
  __syncthreads();
  const int mcnt = (int)mc[ql];
  if (mcnt <= MCAP) {
    for (int w = ln; w < mcnt; w += 32) {
      u64 key = qbuf[ql*MCAP + w];
      int rank = 0;
      for (int v = 0; v < mcnt; ++v) rank += (qbuf[ql*MCAP + v] < key) ? 1 : 0;
      if (rank < KNN) win[ql*KNN + rank] = key;
    }
  } else {
    for (int u = ln; u < cnt; u += 32) {
      if ((uint)cls[ql*QCAP + u] <= bcls) {
        int j = jl[ql*QCAP + u];
        float e = d2f(sq, s4[j]);
        u64 key = ((u64)__float_as_uint(e) << 14) | (uint)j;
        int rank = 0;
        for (int v = 0; v < cnt; ++v) {
          int jv = jl[ql*QCAP + v];
          float ev = d2f(sq, s4[jv]);
          u64 kv2 = ((u64)__float_as_uint(ev) << 14) | (uint)jv;
          rank += (kv2 < key) ? 1 : 0;
        }
        if (rank < KNN) win[ql*KNN + rank] = key;
      }
    }
  }
  __syncthreads();
  // ---- aggregation: 4-way unrolled (independent win->h gather chains) ----
  float sum = 0.f, mx = -FLTMAX;
#pragma unroll
  for (int r4 = 0; r4 < 4; ++r4) {
    u64 k0 = win[ql*KNN + r4*4 + 0];
    u64 k1 = win[ql*KNN + r4*4 + 1];
    u64 k2 = win[ql*KNN + r4*4 + 2];
    u64 k3v = win[ql*KNN + r4*4 + 3];
    int j0 = (int)(k0 & 16383u), j1 = (int)(k1 & 16383u);
    int j2 = (int)(k2 & 16383u), j3 = (int)(k3v & 16383u);
    float h0 = h[(size_t)j0*PD + ln];
    float h1 = h[(size_t)j1*PD + ln];
    float h2 = h[(size_t)j2*PD + ln];
    float h3 = h[(size_t)j3*PD + ln];
    float w0 = __expf(-10.f * __uint_as_float((uint)(k0 >> 14)));
    float w1 = __expf(-10.f * __uint_as_float((uint)(k1 >> 14)));
    float w2 = __expf(-10.f * __uint_as_float((uint)(k2 >> 14)));
    float w3 = __expf(-10.f * __uint_as_float((uint)(k3v >> 14)));
    float m0 = w0*h0, m1 = w1*h1, m2 = w2*h2, m3 = w3*h3;
    sum += m0 + m1 + m2 + m3;
    mx = fmaxf(mx, fmaxf(fmaxf(m0, m1), fmaxf(m2, m3)));
  }
  agg[(size_t)q*64 + ln]      = sum * 0.0625f;
  agg[(size_t)q*64 + 32 + ln] = mx;
}

// ================= Fallback path (round-2, proven) =================
__global__ __launch_bounds__(256) void k2_knn_fb(
    const float4* __restrict__ s4, unsigned short* __restrict__ cand_j) {
  __shared__ float4 tile[TJF];
  __shared__ int    lbuf[256*33];
  const int t  = threadIdx.x;
  const int ib = blockIdx.x & 31;
  const int jc = blockIdx.x >> 5;
  const int jbase = jc * TJF;
#pragma unroll
  for (int g = 0; g < 4; ++g) tile[g*256 + t] = s4[jbase + g*256 + t];
  const int ia = ib*256 + t;
  const int ic = ia + 8192;
  const float4 sa = s4[ia];
  const float4 sc = s4[ic];
  __syncthreads();
  float va[KNN], vb[KNN]; int ja[KNN], jb[KNN];
#pragma unroll
  for (int q = 0; q < KNN; ++q) { va[q] = FLTMAX; ja[q] = 0; vb[q] = FLTMAX; jb[q] = 0; }
  float cma = FLTMAX, cmb = FLTMAX;
  int cpa = 0, cpb = 0, ca = 0, cb = 0;
  auto insertA = [&](float e, int jj) {
#pragma unroll
    for (int q = 0; q < KNN; ++q) if (q == cpa) { va[q] = e; ja[q] = jj; }
    cma = va[0]; cpa = 0;
#pragma unroll
    for (int q = 1; q < KNN; ++q) { if (va[q] > cma) { cma = va[q]; cpa = q; } }
  };
  auto insertB = [&](float e, int jj) {
#pragma unroll
    for (int q = 0; q < KNN; ++q) if (q == cpb) { vb[q] = e; jb[q] = jj; }
    cmb = vb[0]; cpb = 0;
#pragma unroll
    for (int q = 1; q < KNN; ++q) { if (vb[q] > cmb) { cmb = vb[q]; cpb = q; } }
  };
  auto compactA = [&]() {
    for (int u = 0; u < ca; ++u) {
      int jj = lbuf[t*33 + u];
      float e = d2f(sa, tile[jj]);
      if (e < cma) insertA(e, jj);
    }
    ca = 0;
  };
  auto compactB = [&]() {
    for (int u = 0; u < cb; ++u) {
      int jj = lbuf[t*33 + 16 + u];
      float e = d2f(sc, tile[jj]);
      if (e < cmb) insertB(e, jj);
    }
    cb = 0;
  };
  for (int ob = 0; ob < TJF/8; ++ob) {
#pragma unroll
    for (int u = 0; u < 8; ++u) {
      int jj = ob*8 + u;
      float4 p = tile[jj];
      float ea = d2f(sa, p);
      float eb = d2f(sc, p);
      if (ea < cma) { lbuf[t*33 + ca] = jj; ++ca; }
      if (eb < cmb) { lbuf[t*33 + 16 + cb] = jj; ++cb; }
    }
    if (__any(ca > 8)) compactA();
    if (__any(cb > 8)) compactB();
  }
  compactA(); compactB();
#pragma unroll
  for (int q = 0; q < KNN; ++q) {
    int c = jc*KNN + q;
    cand_j[(size_t)c*NPTS + ia] = (unsigned short)(ja[q] + jbase);
    cand_j[(size_t)c*NPTS + ic] = (unsigned short)(jb[q] + jbase);
  }
}

__global__ __launch_bounds__(256) void k3_merge_fb(
    const float4* __restrict__ s4, const float4* __restrict__ h4,
    const unsigned short* __restrict__ cand_j, float* __restrict__ agg) {
  __shared__ float le[64*67];
  __shared__ int   lj[64*67];
  const int t  = threadIdx.x;
  const int il = t & 63, tq = t >> 6;
  const int i  = blockIdx.x*64 + il;
  const float4 si = s4[i];
  float val[KNN]; int vid[KNN];
#pragma unroll
  for (int q = 0; q < KNN; ++q) { val[q] = FLTMAX; vid[q] = 0; }
  float cmax = FLTMAX; int cpos = 0;
  for (int u = 0; u < 64; ++u) {
    int c = tq*64 + u;
    int j = cand_j[(size_t)c*NPTS + i];
    float e = d2f(si, s4[j]);
    if (e < cmax) {
#pragma unroll
      for (int q = 0; q < KNN; ++q) if (q == cpos) { val[q] = e; vid[q] = j; }
      cmax = val[0]; cpos = 0;
#pragma unroll
      for (int q = 1; q < KNN; ++q) { if (val[q] > cmax) { cmax = val[q]; cpos = q; } }
    }
  }
#pragma unroll
  for (int q = 0; q < KNN; ++q) {
    le[il*67 + tq*16 + q] = val[q];
    lj[il*67 + tq*16 + q] = vid[q];
  }
  __syncthreads();
  if (t < 64) {
    float mv[KNN]; int mj[KNN];
#pragma unroll
    for (int q = 0; q < KNN; ++q) { mv[q] = FLTMAX; mj[q] = 0; }
    float cm2 = FLTMAX; int cp2 = 0;
    for (int u = 0; u < 64; ++u) {
      float e = le[t*67 + u];
      int   j = lj[t*67 + u];
      if (e < cm2) {
#pragma unroll
        for (int q = 0; q < KNN; ++q) if (q == cp2) { mv[q] = e; mj[q] = j; }
        cm2 = mv[0]; cp2 = 0;
#pragma unroll
        for (int q = 1; q < KNN; ++q) { if (mv[q] > cm2) { cm2 = mv[q]; cp2 = q; } }
      }
    }
#pragma unroll
    for (int q = 0; q < KNN; ++q) {
      le[t*67 + q] = __expf(-10.f * mv[q]);
      lj[t*67 + q] = mj[q];
    }
  }
  __syncthreads();
  float ms[8], mm[8];
#pragma unroll
  for (int p = 0; p < 8; ++p) { ms[p] = 0.f; mm[p] = -FLTMAX; }
#pragma unroll 1
  for (int q = 0; q < KNN; ++q) {
    float w = le[il*67 + q];
    int   j = lj[il*67 + q];
    float4 a = h4[(size_t)j*8 + tq*2];
    float4 b = h4[(size_t)j*8 + tq*2 + 1];
    float m0 = a.x*w, m1 = a.y*w, m2 = a.z*w, m3 = a.w*w;
    float m4 = b.x*w, m5 = b.y*w, m6 = b.z*w, m7 = b.w*w;
    ms[0] += m0; mm[0] = fmaxf(mm[0], m0);
    ms[1] += m1; mm[1] = fmaxf(mm[1], m1);
    ms[2] += m2; mm[2] = fmaxf(mm[2], m2);
    ms[3] += m3; mm[3] = fmaxf(mm[3], m3);
    ms[4] += m4; mm[4] = fmaxf(mm[4], m4);
    ms[5] += m5; mm[5] = fmaxf(mm[5], m5);
    ms[6] += m6; mm[6] = fmaxf(mm[6], m6);
    ms[7] += m7; mm[7] = fmaxf(mm[7], m7);
  }
  float4 o0 = make_float4(ms[0]*0.0625f, ms[1]*0.0625f, ms[2]*0.0625f, ms[3]*0.0625f);
  float4 o1 = make_float4(ms[4]*0.0625f, ms[5]*0.0625f, ms[6]*0.0625f, ms[7]*0.0625f);
  *(float4*)&agg[(size_t)i*64 + tq*8]      = o0;
  *(float4*)&agg[(size_t)i*64 + tq*8 + 4]  = o1;
  *(float4*)&agg[(size_t)i*64 + 32 + tq*8]     = make_float4(mm[0], mm[1], mm[2], mm[3]);
  *(float4*)&agg[(size_t)i*64 + 32 + tq*8 + 4] = make_float4(mm[4], mm[5], mm[6], mm[7]);
}

// ---------------- Kernel 4a: pack/transpose weights ----------------
__global__ __launch_bounds__(256) void k4a_wt(
    const float* __restrict__ W1, const float* __restrict__ W2, float* __restrict__ wT) {
  int idx = blockIdx.x*256 + threadIdx.x;
  if (idx >= 192*COUT) return;
  int k = idx >> 7, c = idx & 127;
  float v = (k < 128) ? W1[(size_t)c*128 + k] : W2[(size_t)c*64 + (k - 128)];
  wT[(size_t)k*COUT + c] = v;
}

// ---------------- Kernel 4: out = x@W1^T + agg@W2^T + b2 (32x128 tile, 4x4/thread) ----------
__global__ __launch_bounds__(256) void k4_out2(
    const float* __restrict__ x, const float* __restrict__ agg,
    const float* __restrict__ wT, const float* __restrict__ b2,
    float* __restrict__ out) {
  __shared__ float xa[32*192];
  const int t = threadIdx.x;
  const int row0 = blockIdx.x * 32;
#pragma unroll
  for (int g = 0; g < 4; ++g) {
    int fi = g*256 + t;
    int r = fi >> 5, c4 = fi & 31;
    *(float4*)&xa[r*192 + c4*4] = *(const float4*)&x[(size_t)(row0+r)*CIN + c4*4];
  }
#pragma unroll
  for (int g = 0; g < 2; ++g) {
    int fi = g*256 + t;
    int r = fi >> 4, c4 = fi & 15;
    *(float4*)&xa[r*192 + 128 + c4*4] = *(const float4*)&agg[(size_t)(row0+r)*64 + c4*4];
  }
  __syncthreads();
  const int c4 = t & 31;
  const int rg = t >> 5;
  float acc[4][4];
#pragma unroll
  for (int r = 0; r < 4; ++r) { acc[r][0]=0.f; acc[r][1]=0.f; acc[r][2]=0.f; acc[r][3]=0.f; }
  for (int k = 0; k < 192; k += 4) {
    float4 w0 = *(const float4*)&wT[(size_t)(k+0)*COUT + c4*4];
    float4 w1 = *(const float4*)&wT[(size_t)(k+1)*COUT + c4*4];
    float4 w2 = *(const float4*)&wT[(size_t)(k+2)*COUT + c4*4];
    float4 w3 = *(const float4*)&wT[(size_t)(k+3)*COUT + c4*4];
#pragma unroll
    for (int r = 0; r < 4; ++r) {
      float4 xv = *(const float4*)&xa[(rg*4 + r)*192 + k];
      acc[r][0] = fmaf(xv.x, w0.x, fmaf(xv.y, w1.x, fmaf(xv.z, w2.x, fmaf(xv.w, w3.x, acc[r][0]))));
      acc[r][1] = fmaf(xv.x, w0.y, fmaf(xv.y, w1.y, fmaf(xv.z, w2.y, fmaf(xv.w, w3.y, acc[r][1]))));
      acc[r][2] = fmaf(xv.x, w0.z, fmaf(xv.y, w1.z, fmaf(xv.z, w2.z, fmaf(xv.w, w3.z, acc[r][2]))));
      acc[r][3] = fmaf(xv.x, w0.w, fmaf(xv.y, w1.w, fmaf(xv.z, w2.w, fmaf(xv.w, w3.w, acc[r][3]))));
    }
  }
  float4 bias = *(const float4*)&b2[c4*4];
#pragma unroll
  for (int r = 0; r < 4; ++r) {
    float4 o = make_float4(acc[r][0]+bias.x, acc[r][1]+bias.y, acc[r][2]+bias.z, acc[r][3]+bias.w);
    *(float4*)&out[(size_t)(row0 + rg*4 + r)*COUT + c4*4] = o;
  }
}

extern "C" void kernel_launch(void* const* d_in, const int* in_sizes, int n_in,
                              void* d_out, int out_size, void* d_ws, size_t ws_size,
                              hipStream_t stream) {
  const float* x  = (const float*)d_in[0];
  const float* Ws = (const float*)d_in[1];
  const float* bs = (const float*)d_in[2];
  const float* Wh = (const float*)d_in[3];
  const float* bh = (const float*)d_in[4];
  const float* W1 = (const float*)d_in[5];
  const float* W2 = (const float*)d_in[6];
  const float* b2 = (const float*)d_in[7];
  float* out = (float*)d_out;

  char* ws = (char*)d_ws;
  float4* s4 = (float4*)(ws + WS_S4);
  float*  h  = (float*) (ws + WS_H);

  k1_proj<<<NPTS/64, 256, 0, stream>>>(x, Ws, bs, Wh, bh, s4, h);

  if (ws_size >= (size_t)WS_NEED_M) {
    float* agg = (float*)(ws + WS_AGG_M);
    float* wT  = (float*)(ws + WS_WT_M);
    uint4* sa  = (uint4*)(ws + WS_SA);
    uint4* sb  = (uint4*)(ws + WS_SB);
    float* t2  = (float*)(ws + WS_T2);
    u16*   jls = (u16*)  (ws + WS_JLIST);
    u16*   jcn = (u16*)  (ws + WS_JCNT);
    k2t_thresh<<<NPTS/16, 256, 0, stream>>>(s4, sa, sb, t2);
    k2b_mfma<<<1024, 256, 0, stream>>>((const u16*)sa, (const u16*)sb, jls, jcn);
    k3_sel2<<<NPTS/QPB, 256, 0, stream>>>(s4, h, (const u16*)jls, (const u16*)jcn, t2, agg);
    k4a_wt<<<(192*COUT + 255)/256, 256, 0, stream>>>(W1, W2, wT);
    k4_out2<<<NPTS/32, 256, 0, stream>>>(x, agg, wT, b2, out);
  } else {
    unsigned short* cj = (unsigned short*)(ws + WS_CJ_F);
    float* agg = (float*)(ws + WS_AGG_F);
    float* wT  = (float*)(ws + WS_WT_F);
    k2_knn_fb<<<512, 256, 0, stream>>>(s4, cj);
    k3_merge_fb<<<NPTS/64, 256, 0, stream>>>(s4, (const float4*)h, cj, agg);
    k4a_wt<<<(192*COUT + 255)/256, 256, 0, stream>>>(W1, W2, wT);
    k4_out2<<<NPTS/32, 256, 0, stream>>>(x, agg, wT, b2, out);
  }
}

// Round 13
// 188.172 us; speedup vs baseline: 1.2906x; 1.2906x over previous
//
#include <hip/hip_runtime.h>
#include <hip/hip_bf16.h>

// GravNetConv: N=16384, C_IN=128, S=4, P=32, K=16, C_OUT=128.
// Mask path: [k1] proj (fp64 s) -> [k2t] threshold via radix-ladder histogram with
// FUSED operand pack (bf16x2 split + threshold fold) -> [k2b_mfma] N^2 Gram via
// mfma_f32_32x32x16_bf16 (A=j, B=queries), per-lane sign-bit pack + shfl_xor(32)
// merge -> dense bitmask, coalesced uint4 stores (32 MB) -> [k3_sel2] low-LDS decode
// with batched mask loads + 2-way gather ILP + 4-way unrolled aggregation ->
// rank-based top-16 -> [k4a/k4_out2] out = x@W1^T + agg@W2^T + b2.
// Fallback path (ws_size < 41MB): round-2 kernels.
// NOTE (r12): dense-mask stream is the proven optimum; compact-list variant (r12)
// regressed 188.7 -> 242.9 us (scattered u16 access, latency-bound). Reverted.

#define NPTS 16384
#define CIN  128
#define SD   4
#define PD   32
#define KNN  16
#define COUT 128
#define FLTMAX 3.4028234663852886e+38f
#define NBIN 33
#define QPB  8      // k3 queries per block
#define QCAP 512    // per-query candidate cap
#define MCAP 192    // k3 per-query qualifier cap (ultra-rare recompute fallback beyond)
#define EPAD 1e-3f  // mask-inclusion pad >> bf16x2 Gram error bound (~2e-4)

typedef float v2f __attribute__((ext_vector_type(2)));
typedef unsigned int uint;
typedef unsigned long long u64;
typedef unsigned short u16;
typedef __attribute__((ext_vector_type(8))) short bf16x8;
typedef __attribute__((ext_vector_type(16))) float f32x16;

// ---- shared offsets (both paths) ----
#define WS_S4     0            // N * float4 = 256 KB
#define WS_H      0x40000      // N * 32 f32 = 2 MB
// ---- mask-path offsets ----
#define WS_AGG_M  0x280000     // [N][64] f32 = 4 MB (written by k3, after k2b)
#define WS_SA     0x280000     // aliases AGG: N*16 bf16 = 512 KB, dead before k3
#define WS_SB     0x300000     // aliases AGG: N*16 bf16 = 512 KB, dead before k3
#define WS_WT_M   0x680000     // [192][128] f32 = 96 KB
#define WS_MASK   0x700000     // 128 chunks * N uint4 = 32 MB
#define WS_NEED_M 0x2700000    // 40.9 MB
// ---- fallback offsets ----
#define WS_CJ_F   0x400000
#define WS_AGG_F  0xC00000
#define WS_WT_F   0x1000000
#define JS   16
#define TJF  (NPTS/JS)

__device__ __forceinline__ float d2f(const float4 a, const float4 b) {
  v2f d0 = {a.x - b.x, a.y - b.y};
  v2f d1 = {a.z - b.z, a.w - b.w};
  v2f pr = d0*d0 + d1*d1;
  return pr.x + pr.y;
}

__device__ __forceinline__ u16 f2bf(float x) {   // RNE float->bf16
  uint u = __float_as_uint(x);
  uint r = (u + 0x7FFFu + ((u >> 16) & 1u)) >> 16;
  return (u16)r;
}
__device__ __forceinline__ float bf2f(u16 h) {
  return __uint_as_float(((uint)h) << 16);
}

// ---------------- Kernel 1: s (fp64 accumulate) and h projections ----------------
__global__ __launch_bounds__(256) void k1_proj(
    const float* __restrict__ x, const float* __restrict__ Ws, const float* __restrict__ bs,
    const float* __restrict__ Wh, const float* __restrict__ bh,
    float4* __restrict__ s4, float* __restrict__ h) {
  __shared__ float  lw[36*128];
  __shared__ float  lx[64*132];
  __shared__ double rs[3*64*5];
  __shared__ float  rh[3*64*33];
  const int t = threadIdx.x;
  const int row0 = blockIdx.x * 64;
  for (int i2 = t; i2 < 36*128; i2 += 256)
    lw[i2] = (i2 < 512) ? Ws[i2] : Wh[i2 - 512];
#pragma unroll
  for (int g = 0; g < 8; ++g) {
    int fi = g*256 + t;
    int r = fi >> 5, c4 = fi & 31;
    *(float4*)&lx[r*132 + c4*4] = *(const float4*)&x[(size_t)(row0 + r)*CIN + c4*4];
  }
  __syncthreads();
  const int kq = t >> 6;
  const int r  = t & 63;
  const int kb = kq * 32;
  double sacc[4] = {0.0, 0.0, 0.0, 0.0};
  float  hacc[32];
#pragma unroll
  for (int p = 0; p < 32; ++p) hacc[p] = 0.f;
#pragma unroll
  for (int k4 = 0; k4 < 8; ++k4) {
    float4 xv = *(const float4*)&lx[r*132 + kb + k4*4];
    int kg = kb + k4*4;
#pragma unroll
    for (int p = 0; p < 4; ++p) {
      float4 wv = *(const float4*)&lw[p*128 + kg];
      sacc[p] = fma((double)xv.x, (double)wv.x, sacc[p]);
      sacc[p] = fma((double)xv.y, (double)wv.y, sacc[p]);
      sacc[p] = fma((double)xv.z, (double)wv.z, sacc[p]);
      sacc[p] = fma((double)xv.w, (double)wv.w, sacc[p]);
    }
#pragma unroll
    for (int p = 0; p < 32; ++p) {
      float4 wv = *(const float4*)&lw[(4+p)*128 + kg];
      hacc[p] = fmaf(xv.x, wv.x, fmaf(xv.y, wv.y, fmaf(xv.z, wv.z, fmaf(xv.w, wv.w, hacc[p]))));
    }
  }
  if (kq > 0) {
    const int bq = kq - 1;
#pragma unroll
    for (int d = 0; d < 4; ++d) rs[(bq*64 + r)*5 + d] = sacc[d];
#pragma unroll
    for (int p = 0; p < 32; ++p) rh[(bq*64 + r)*33 + p] = hacc[p];
  }
  __syncthreads();
  if (kq == 0) {
    const int row = row0 + r;
    float so[4];
#pragma unroll
    for (int d = 0; d < 4; ++d) {
      double sd = sacc[d] + rs[(0*64 + r)*5 + d] + rs[(1*64 + r)*5 + d]
                + rs[(2*64 + r)*5 + d] + (double)bs[d];
      so[d] = (float)sd;
    }
    s4[row] = make_float4(so[0], so[1], so[2], so[3]);
#pragma unroll
    for (int p4 = 0; p4 < 8; ++p4) {
      float o[4];
#pragma unroll
      for (int c = 0; c < 4; ++c) {
        int p = p4*4 + c;
        o[c] = hacc[p] + rh[(0*64 + r)*33 + p] + rh[(1*64 + r)*33 + p]
             + rh[(2*64 + r)*33 + p] + bh[p];
      }
      *(float4*)&h[(size_t)row*PD + p4*4] = make_float4(o[0], o[1], o[2], o[3]);
    }
  }
}

// ---------------- Kernel 2t: threshold via radix-ladder histogram + FUSED pack ------
__global__ __launch_bounds__(256) void k2t_thresh(
    const float4* __restrict__ s4, uint4* __restrict__ sA, uint4* __restrict__ sB) {
  __shared__ float4 tile[2064];
  __shared__ uint   lhist[256*NBIN];
  const int t = threadIdx.x;
#pragma unroll
  for (int g = 0; g < 8; ++g) {
    int j = g*256 + t;
    tile[j + (j >> 7)] = s4[j];
  }
#pragma unroll
  for (int b = 0; b < NBIN; ++b) lhist[t*NBIN + b] = 0u;
  const int ql = t >> 4, tq = t & 15;
  const int q  = blockIdx.x*16 + ql;
  const float4 sq = s4[q];
  __syncthreads();
  float tau = d2f(sq, tile[tq*129]);
#pragma unroll
  for (int m = 1; m < 16; m <<= 1) tau = fmaxf(tau, __shfl_xor(tau, m, 16));
  const int ktop = (int)(__float_as_uint(tau) >> 21);
  const int hb = t*NBIN;
#pragma unroll 4
  for (int u = 0; u < 128; ++u) {
    float4 p = tile[tq*129 + u];
    float e = d2f(sq, p);
    int key = (int)(__float_as_uint(e) >> 21);
    int rel = ktop - key;
    rel = rel < 0 ? 0 : (rel > 32 ? 32 : rel);
    atomicAdd(&lhist[hb + rel], 1u);
  }
  __syncthreads();
  uint c0 = 0, c1 = 0;
  const int qb = ql*16;
  for (int u = 0; u < 16; ++u) {
    c0 += lhist[(qb + u)*NBIN + tq*2];
    c1 += (tq*2 + 1 < NBIN) ? lhist[(qb + u)*NBIN + tq*2 + 1] : 0u;
  }
  int S = (int)(c0 + c1);
#pragma unroll
  for (int d = 1; d < 16; d <<= 1) {
    int v = __shfl_down(S, d, 16);
    S += (tq + d < 16) ? v : 0;
  }
  int g = -1;
  if (S >= KNN) g = 2*tq;
  if (S - (int)c0 >= KNN) g = 2*tq + 1;
#pragma unroll
  for (int m = 1; m < 16; m <<= 1) g = max(g, __shfl_xor(g, m, 16));
  if (tq == 0) {
    uint K = (uint)(ktop - g);
    const float tv = __uint_as_float((K << 21) | 0x1FFFFFu);
    // ---- fused pack ----
    float sv[4] = {sq.x, sq.y, sq.z, sq.w};
    const float n2 = sq.x*sq.x + sq.y*sq.y + sq.z*sq.z + sq.w*sq.w;
    u16 hbv[4], lbv[4];
#pragma unroll
    for (int d = 0; d < 4; ++d) {
      u16 hh = f2bf(sv[d]);
      hbv[d] = hh;
      lbv[d] = f2bf(sv[d] - bf2f(hh));
    }
    const float aq = -0.5f*(n2 - tv) + EPAD;
    const float bn = -0.5f*n2;
    u16 aqh = f2bf(aq); u16 aql = f2bf(aq - bf2f(aqh));
    u16 bnh = f2bf(bn); u16 bnl = f2bf(bn - bf2f(bnh));
    const uint oneone = 0x3F803F80u;
    uint a0 = (uint)hbv[0] | ((uint)hbv[1] << 16);
    uint a1 = (uint)hbv[2] | ((uint)hbv[3] << 16);
    uint l0 = (uint)lbv[0] | ((uint)lbv[1] << 16);
    uint l1 = (uint)lbv[2] | ((uint)lbv[3] << 16);
    uint aqw = (uint)aqh | ((uint)aql << 16);
    uint bnw = (uint)bnh | ((uint)bnl << 16);
    uint4 A0; A0.x = a0; A0.y = a1; A0.z = a0; A0.w = a1;
    uint4 A1; A1.x = l0; A1.y = l1; A1.z = oneone; A1.w = aqw;
    uint4 B0; B0.x = a0; B0.y = a1; B0.z = l0; B0.w = l1;
    uint4 B1; B1.x = a0; B1.y = a1; B1.z = bnw; B1.w = oneone;
    sA[(size_t)q*2]     = A0;
    sA[(size_t)q*2 + 1] = A1;
    sB[(size_t)q*2]     = B0;
    sB[(size_t)q*2 + 1] = B1;
  }
}

// per-lane pack of 16 predicate bits from a 32x32 MFMA accumulator.
__device__ __forceinline__ uint packbits16(const f32x16 a, const int shft) {
  uint b[4];
#pragma unroll
  for (int g = 0; g < 4; ++g) {
    uint bg = 0u;
#pragma unroll
    for (int e = 3; e >= 0; --e)
      bg = bg + bg + ((~__float_as_uint(a[4*g + e])) >> 31);
    b[g] = bg;
  }
  return (b[0] | (b[1] << 8) | (b[2] << 16) | (b[3] << 24)) << shft;
}

// ---------------- Kernel 2b: N^2 Gram via 32x32x16 MFMA, per-lane bit pack -----------
__global__ __launch_bounds__(256) void k2b_mfma(
    const u16* __restrict__ sA, const u16* __restrict__ sB, uint4* __restrict__ maskw) {
  __shared__ u16 lB[1024*16];                // 32 KB: 1024 j-rows x 32 B
  const int t   = threadIdx.x;
  const int wv  = t >> 6, ln = t & 63;
  const int l31 = ln & 31, hi = ln >> 5;
  const int qbase = (blockIdx.x >> 4) * 256 + wv * 64;
  const int j0    = (blockIdx.x & 15) * 1024;
  for (int r = t; r < 1024; r += 256) {
    const uint4* src = (const uint4*)&sB[(size_t)(j0 + r)*16];
    uint4 v0 = src[0], v1 = src[1];
    *(uint4*)&lB[r*16]     = v0;
    *(uint4*)&lB[r*16 + 8] = v1;
  }
  const bf16x8 qf0 = *(const bf16x8*)&sA[(size_t)(qbase + l31)*16 + hi*8];
  const bf16x8 qf1 = *(const bf16x8*)&sA[(size_t)(qbase + 32 + l31)*16 + hi*8];
  __syncthreads();
  const int sh = hi * 4;
  const f32x16 zc = {0.f,0.f,0.f,0.f,0.f,0.f,0.f,0.f,0.f,0.f,0.f,0.f,0.f,0.f,0.f,0.f};
#pragma unroll 1
  for (int cc = 0; cc < 8; ++cc) {
    uint w0[4], w1[4];
#pragma unroll
    for (int jt = 0; jt < 4; ++jt) {
      const bf16x8 af = *(const bf16x8*)&lB[(cc*128 + jt*32 + l31)*16 + hi*8];
      f32x16 a0 = __builtin_amdgcn_mfma_f32_32x32x16_bf16(af, qf0, zc, 0, 0, 0);
      f32x16 a1 = __builtin_amdgcn_mfma_f32_32x32x16_bf16(af, qf1, zc, 0, 0, 0);
      w0[jt] = packbits16(a0, sh);
      w1[jt] = packbits16(a1, sh);
    }
    uint of[4];
#pragma unroll
    for (int jt = 0; jt < 4; ++jt) {
      uint f0 = w0[jt] | (uint)__shfl_xor((int)w0[jt], 32);
      uint f1 = w1[jt] | (uint)__shfl_xor((int)w1[jt], 32);
      of[jt] = hi ? f1 : f0;
    }
    const int c = (blockIdx.x & 15)*8 + cc;
    uint4 o; o.x = of[0]; o.y = of[1]; o.z = of[2]; o.w = of[3];
    maskw[(size_t)c*NPTS + qbase + ln] = o;
  }
}

// ---------------- Kernel 3: low-LDS decode + exact re-rank + aggregation -------------
// block = 8 queries x 32 lanes. r9 LDS layout (31 KB) + ILP fixes:
//  - phase A: all 4 mask uint4s issued before any use (parallel HBM latency)
//  - pass 1: 2-way manual unroll (two independent jl->s4 gather chains in flight)
//  - aggregation: 4-way unroll (four independent win->h gather chains in flight)
__global__ __launch_bounds__(256) void k3_sel2(
    const float4* __restrict__ s4, const float* __restrict__ h,
    const uint4* __restrict__ maskw, float* __restrict__ agg) {
  __shared__ unsigned short jl[QPB*QCAP];   // 8 KB
  __shared__ u16  cls[QPB*QCAP];            // 8 KB
  __shared__ u64  qbuf[QPB*MCAP];           // 12 KB
  __shared__ u64  win[QPB*KNN];             // 1 KB
  __shared__ uint hist[QPB*32];             // 1 KB
  __shared__ uint cnts[QPB];
  __shared__ uint mc[QPB];
  const int t  = threadIdx.x;
  const int ql = t >> 5, ln = t & 31;
  const int q  = blockIdx.x*QPB + ql;
  if (ln == 0) { cnts[ql] = 0u; mc[ql] = 0u; }
  hist[ql*32 + ln] = 0u;
  if (ln < KNN) win[ql*KNN + ln] = 0ull;
  const float4 sq = s4[q];
  __syncthreads();
  // ---- phase A: batch-issue all 4 mask loads, then decode (order-free compaction) ----
  const int qa = t & 7;
  const int cg = t >> 3;
  uint4 m[4];
#pragma unroll
  for (int u = 0; u < 4; ++u)
    m[u] = maskw[(size_t)(cg + u*32)*NPTS + blockIdx.x*QPB + qa];
  int pc = 0;
#pragma unroll
  for (int u = 0; u < 4; ++u)
    pc += __popc(m[u].x) + __popc(m[u].y) + __popc(m[u].z) + __popc(m[u].w);
  int base = (int)atomicAdd(&cnts[qa], (uint)pc);
#pragma unroll
  for (int u = 0; u < 4; ++u) {
    uint wvs[4] = {m[u].x, m[u].y, m[u].z, m[u].w};
#pragma unroll
    for (int w = 0; w < 4; ++w) {
      uint bits = wvs[w];
      const int jb = (cg + u*32)*128 + w*32;
      while (bits) {
        int b = __builtin_ctz(bits); bits &= bits - 1;
        if (base < QCAP) jl[qa*QCAP + base] = (unsigned short)(jb + b);
        ++base;
      }
    }
  }
  __syncthreads();
  const int cnt = min((int)cnts[ql], QCAP);
  // ---- pass 1: gather d2 once (2-way ILP), store class, track kmax ----
  uint kmax = 0u;
  {
    int u = ln;
    for (; u + 32 < cnt; u += 64) {
      int ja = jl[ql*QCAP + u];
      int jb = jl[ql*QCAP + u + 32];
      float ea = d2f(sq, s4[ja]);
      float eb = d2f(sq, s4[jb]);
      uint ca = __float_as_uint(ea) >> 21;
      uint cb = __float_as_uint(eb) >> 21;
      cls[ql*QCAP + u]      = (u16)ca;
      cls[ql*QCAP + u + 32] = (u16)cb;
      kmax = max(kmax, max(ca, cb));
    }
    if (u < cnt) {
      int j = jl[ql*QCAP + u];
      float e = d2f(sq, s4[j]);
      uint cv = __float_as_uint(e) >> 21;
      cls[ql*QCAP + u] = (u16)cv;
      kmax = max(kmax, cv);
    }
  }
#pragma unroll
  for (int m2 = 1; m2 < 32; m2 <<= 1) kmax = max(kmax, (uint)__shfl_xor((int)kmax, m2, 32));
  // ---- histogram from class array (own-lane positions only) ----
  for (int u = ln; u < cnt; u += 32) {
    uint cv = cls[ql*QCAP + u];
    uint rel = min(kmax - cv, 31u);
    atomicAdd(&hist[ql*32 + rel], 1u);
  }
  __syncthreads();
  // ---- boundary: largest r* with cum(r*) >= need; bcls = kmax - r* ----
  uint cum = hist[ql*32 + ln];
#pragma unroll
  for (int d = 1; d < 32; d <<= 1) {
    uint v = (uint)__shfl_down((int)cum, d, 32);
    if (ln + d < 32) cum += v;
  }
  const uint need = (uint)(cnt < KNN ? cnt : KNN);
  u64 bal = __ballot(cum >= need);
  uint half = (uint)(bal >> (((t >> 5) & 1) * 32));
  const uint rstar = 31u - (uint)__builtin_clz(half);
  const uint bcls = kmax - rstar;
  __syncthreads();
  // ---- compact qualifiers: recompute exact d2 (bit-identical), build u64 key ----
  for (int u = ln; u < cnt; u += 32) {
    if ((uint)cls[ql*QCAP + u] <= bcls) {
      int j = jl[ql*QCAP + u];
      float e = d2f(sq, s4[j]);
      u64 key = ((u64)__float_as_uint(e) << 14) | (uint)j;
      uint pos = atomicAdd(&mc[ql], 1u);
      if (pos < MCAP) qbuf[ql*MCAP + pos] = key;
    }
  }
  __syncthreads();
  const int mcnt = (int)mc[ql];
  if (mcnt <= MCAP) {
    for (int w = ln; w < mcnt; w += 32) {
      u64 key = qbuf[ql*MCAP + w];
      int rank = 0;
      for (int v = 0; v < mcnt; ++v) rank += (qbuf[ql*MCAP + v] < key) ? 1 : 0;
      if (rank < KNN) win[ql*KNN + rank] = key;
    }
  } else {
    // ultra-rare correct fallback: rank each qualifier against ALL candidates
    for (int u = ln; u < cnt; u += 32) {
      if ((uint)cls[ql*QCAP + u] <= bcls) {
        int j = jl[ql*QCAP + u];
        float e = d2f(sq, s4[j]);
        u64 key = ((u64)__float_as_uint(e) << 14) | (uint)j;
        int rank = 0;
        for (int v = 0; v < cnt; ++v) {
          int jv = jl[ql*QCAP + v];
          float ev = d2f(sq, s4[jv]);
          u64 kv2 = ((u64)__float_as_uint(ev) << 14) | (uint)jv;
          rank += (kv2 < key) ? 1 : 0;
        }
        if (rank < KNN) win[ql*KNN + rank] = key;
      }
    }
  }
  __syncthreads();
  // ---- aggregation: 4-way unrolled (independent win->h gather chains) ----
  float sum = 0.f, mx = -FLTMAX;
#pragma unroll
  for (int r4 = 0; r4 < 4; ++r4) {
    u64 k0 = win[ql*KNN + r4*4 + 0];
    u64 k1 = win[ql*KNN + r4*4 + 1];
    u64 k2 = win[ql*KNN + r4*4 + 2];
    u64 k3v = win[ql*KNN + r4*4 + 3];
    int j0 = (int)(k0 & 16383u), j1 = (int)(k1 & 16383u);
    int j2 = (int)(k2 & 16383u), j3 = (int)(k3v & 16383u);
    float h0 = h[(size_t)j0*PD + ln];
    float h1 = h[(size_t)j1*PD + ln];
    float h2 = h[(size_t)j2*PD + ln];
    float h3 = h[(size_t)j3*PD + ln];
    float w0 = __expf(-10.f * __uint_as_float((uint)(k0 >> 14)));
    float w1 = __expf(-10.f * __uint_as_float((uint)(k1 >> 14)));
    float w2 = __expf(-10.f * __uint_as_float((uint)(k2 >> 14)));
    float w3 = __expf(-10.f * __uint_as_float((uint)(k3v >> 14)));
    float m0 = w0*h0, m1 = w1*h1, m2 = w2*h2, m3 = w3*h3;
    sum += m0 + m1 + m2 + m3;
    mx = fmaxf(mx, fmaxf(fmaxf(m0, m1), fmaxf(m2, m3)));
  }
  agg[(size_t)q*64 + ln]      = sum * 0.0625f;
  agg[(size_t)q*64 + 32 + ln] = mx;
}

// ================= Fallback path (round-2, proven) =================
__global__ __launch_bounds__(256) void k2_knn_fb(
    const float4* __restrict__ s4, unsigned short* __restrict__ cand_j) {
  __shared__ float4 tile[TJF];
  __shared__ int    lbuf[256*33];
  const int t  = threadIdx.x;
  const int ib = blockIdx.x & 31;
  const int jc = blockIdx.x >> 5;
  const int jbase = jc * TJF;
#pragma unroll
  for (int g = 0; g < 4; ++g) tile[g*256 + t] = s4[jbase + g*256 + t];
  const int ia = ib*256 + t;
  const int ic = ia + 8192;
  const float4 sa = s4[ia];
  const float4 sc = s4[ic];
  __syncthreads();
  float va[KNN], vb[KNN]; int ja[KNN], jb[KNN];
#pragma unroll
  for (int q = 0; q < KNN; ++q) { va[q] = FLTMAX; ja[q] = 0; vb[q] = FLTMAX; jb[q] = 0; }
  float cma = FLTMAX, cmb = FLTMAX;
  int cpa = 0, cpb = 0, ca = 0, cb = 0;
  auto insertA = [&](float e, int jj) {
#pragma unroll
    for (int q = 0; q < KNN; ++q) if (q == cpa) { va[q] = e; ja[q] = jj; }
    cma = va[0]; cpa = 0;
#pragma unroll
    for (int q = 1; q < KNN; ++q) { if (va[q] > cma) { cma = va[q]; cpa = q; } }
  };
  auto insertB = [&](float e, int jj) {
#pragma unroll
    for (int q = 0; q < KNN; ++q) if (q == cpb) { vb[q] = e; jb[q] = jj; }
    cmb = vb[0]; cpb = 0;
#pragma unroll
    for (int q = 1; q < KNN; ++q) { if (vb[q] > cmb) { cmb = vb[q]; cpb = q; } }
  };
  auto compactA = [&]() {
    for (int u = 0; u < ca; ++u) {
      int jj = lbuf[t*33 + u];
      float e = d2f(sa, tile[jj]);
      if (e < cma) insertA(e, jj);
    }
    ca = 0;
  };
  auto compactB = [&]() {
    for (int u = 0; u < cb; ++u) {
      int jj = lbuf[t*33 + 16 + u];
      float e = d2f(sc, tile[jj]);
      if (e < cmb) insertB(e, jj);
    }
    cb = 0;
  };
  for (int ob = 0; ob < TJF/8; ++ob) {
#pragma unroll
    for (int u = 0; u < 8; ++u) {
      int jj = ob*8 + u;
      float4 p = tile[jj];
      float ea = d2f(sa, p);
      float eb = d2f(sc, p);
      if (ea < cma) { lbuf[t*33 + ca] = jj; ++ca; }
      if (eb < cmb) { lbuf[t*33 + 16 + cb] = jj; ++cb; }
    }
    if (__any(ca > 8)) compactA();
    if (__any(cb > 8)) compactB();
  }
  compactA(); compactB();
#pragma unroll
  for (int q = 0; q < KNN; ++q) {
    int c = jc*KNN + q;
    cand_j[(size_t)c*NPTS + ia] = (unsigned short)(ja[q] + jbase);
    cand_j[(size_t)c*NPTS + ic] = (unsigned short)(jb[q] + jbase);
  }
}

__global__ __launch_bounds__(256) void k3_merge_fb(
    const float4* __restrict__ s4, const float4* __restrict__ h4,
    const unsigned short* __restrict__ cand_j, float* __restrict__ agg) {
  __shared__ float le[64*67];
  __shared__ int   lj[64*67];
  const int t  = threadIdx.x;
  const int il = t & 63, tq = t >> 6;
  const int i  = blockIdx.x*64 + il;
  const float4 si = s4[i];
  float val[KNN]; int vid[KNN];
#pragma unroll
  for (int q = 0; q < KNN; ++q) { val[q] = FLTMAX; vid[q] = 0; }
  float cmax = FLTMAX; int cpos = 0;
  for (int u = 0; u < 64; ++u) {
    int c = tq*64 + u;
    int j = cand_j[(size_t)c*NPTS + i];
    float e = d2f(si, s4[j]);
    if (e < cmax) {
#pragma unroll
      for (int q = 0; q < KNN; ++q) if (q == cpos) { val[q] = e; vid[q] = j; }
      cmax = val[0]; cpos = 0;
#pragma unroll
      for (int q = 1; q < KNN; ++q) { if (val[q] > cmax) { cmax = val[q]; cpos = q; } }
    }
  }
#pragma unroll
  for (int q = 0; q < KNN; ++q) {
    le[il*67 + tq*16 + q] = val[q];
    lj[il*67 + tq*16 + q] = vid[q];
  }
  __syncthreads();
  if (t < 64) {
    float mv[KNN]; int mj[KNN];
#pragma unroll
    for (int q = 0; q < KNN; ++q) { mv[q] = FLTMAX; mj[q] = 0; }
    float cm2 = FLTMAX; int cp2 = 0;
    for (int u = 0; u < 64; ++u) {
      float e = le[t*67 + u];
      int   j = lj[t*67 + u];
      if (e < cm2) {
#pragma unroll
        for (int q = 0; q < KNN; ++q) if (q == cp2) { mv[q] = e; mj[q] = j; }
        cm2 = mv[0]; cp2 = 0;
#pragma unroll
        for (int q = 1; q < KNN; ++q) { if (mv[q] > cm2) { cm2 = mv[q]; cp2 = q; } }
      }
    }
#pragma unroll
    for (int q = 0; q < KNN; ++q) {
      le[t*67 + q] = __expf(-10.f * mv[q]);
      lj[t*67 + q] = mj[q];
    }
  }
  __syncthreads();
  float ms[8], mm[8];
#pragma unroll
  for (int p = 0; p < 8; ++p) { ms[p] = 0.f; mm[p] = -FLTMAX; }
#pragma unroll 1
  for (int q = 0; q < KNN; ++q) {
    float w = le[il*67 + q];
    int   j = lj[il*67 + q];
    float4 a = h4[(size_t)j*8 + tq*2];
    float4 b = h4[(size_t)j*8 + tq*2 + 1];
    float m0 = a.x*w, m1 = a.y*w, m2 = a.z*w, m3 = a.w*w;
    float m4 = b.x*w, m5 = b.y*w, m6 = b.z*w, m7 = b.w*w;
    ms[0] += m0; mm[0] = fmaxf(mm[0], m0);
    ms[1] += m1; mm[1] = fmaxf(mm[1], m1);
    ms[2] += m2; mm[2] = fmaxf(mm[2], m2);
    ms[3] += m3; mm[3] = fmaxf(mm[3], m3);
    ms[4] += m4; mm[4] = fmaxf(mm[4], m4);
    ms[5] += m5; mm[5] = fmaxf(mm[5], m5);
    ms[6] += m6; mm[6] = fmaxf(mm[6], m6);
    ms[7] += m7; mm[7] = fmaxf(mm[7], m7);
  }
  float4 o0 = make_float4(ms[0]*0.0625f, ms[1]*0.0625f, ms[2]*0.0625f, ms[3]*0.0625f);
  float4 o1 = make_float4(ms[4]*0.0625f, ms[5]*0.0625f, ms[6]*0.0625f, ms[7]*0.0625f);
  *(float4*)&agg[(size_t)i*64 + tq*8]      = o0;
  *(float4*)&agg[(size_t)i*64 + tq*8 + 4]  = o1;
  *(float4*)&agg[(size_t)i*64 + 32 + tq*8]     = make_float4(mm[0], mm[1], mm[2], mm[3]);
  *(float4*)&agg[(size_t)i*64 + 32 + tq*8 + 4] = make_float4(mm[4], mm[5], mm[6], mm[7]);
}

// ---------------- Kernel 4a: pack/transpose weights ----------------
__global__ __launch_bounds__(256) void k4a_wt(
    const float* __restrict__ W1, const float* __restrict__ W2, float* __restrict__ wT) {
  int idx = blockIdx.x*256 + threadIdx.x;
  if (idx >= 192*COUT) return;
  int k = idx >> 7, c = idx & 127;
  float v = (k < 128) ? W1[(size_t)c*128 + k] : W2[(size_t)c*64 + (k - 128)];
  wT[(size_t)k*COUT + c] = v;
}

// ---------------- Kernel 4: out = x@W1^T + agg@W2^T + b2 (32x128 tile, 4x4/thread) ----------
__global__ __launch_bounds__(256) void k4_out2(
    const float* __restrict__ x, const float* __restrict__ agg,
    const float* __restrict__ wT, const float* __restrict__ b2,
    float* __restrict__ out) {
  __shared__ float xa[32*192];
  const int t = threadIdx.x;
  const int row0 = blockIdx.x * 32;
#pragma unroll
  for (int g = 0; g < 4; ++g) {
    int fi = g*256 + t;
    int r = fi >> 5, c4 = fi & 31;
    *(float4*)&xa[r*192 + c4*4] = *(const float4*)&x[(size_t)(row0+r)*CIN + c4*4];
  }
#pragma unroll
  for (int g = 0; g < 2; ++g) {
    int fi = g*256 + t;
    int r = fi >> 4, c4 = fi & 15;
    *(float4*)&xa[r*192 + 128 + c4*4] = *(const float4*)&agg[(size_t)(row0+r)*64 + c4*4];
  }
  __syncthreads();
  const int c4 = t & 31;
  const int rg = t >> 5;
  float acc[4][4];
#pragma unroll
  for (int r = 0; r < 4; ++r) { acc[r][0]=0.f; acc[r][1]=0.f; acc[r][2]=0.f; acc[r][3]=0.f; }
  for (int k = 0; k < 192; k += 4) {
    float4 w0 = *(const float4*)&wT[(size_t)(k+0)*COUT + c4*4];
    float4 w1 = *(const float4*)&wT[(size_t)(k+1)*COUT + c4*4];
    float4 w2 = *(const float4*)&wT[(size_t)(k+2)*COUT + c4*4];
    float4 w3 = *(const float4*)&wT[(size_t)(k+3)*COUT + c4*4];
#pragma unroll
    for (int r = 0; r < 4; ++r) {
      float4 xv = *(const float4*)&xa[(rg*4 + r)*192 + k];
      acc[r][0] = fmaf(xv.x, w0.x, fmaf(xv.y, w1.x, fmaf(xv.z, w2.x, fmaf(xv.w, w3.x, acc[r][0]))));
      acc[r][1] = fmaf(xv.x, w0.y, fmaf(xv.y, w1.y, fmaf(xv.z, w2.y, fmaf(xv.w, w3.y, acc[r][1]))));
      acc[r][2] = fmaf(xv.x, w0.z, fmaf(xv.y, w1.z, fmaf(xv.z, w2.z, fmaf(xv.w, w3.z, acc[r][2]))));
      acc[r][3] = fmaf(xv.x, w0.w, fmaf(xv.y, w1.w, fmaf(xv.z, w2.w, fmaf(xv.w, w3.w, acc[r][3]))));
    }
  }
  float4 bias = *(const float4*)&b2[c4*4];
#pragma unroll
  for (int r = 0; r < 4; ++r) {
    float4 o = make_float4(acc[r][0]+bias.x, acc[r][1]+bias.y, acc[r][2]+bias.z, acc[r][3]+bias.w);
    *(float4*)&out[(size_t)(row0 + rg*4 + r)*COUT + c4*4] = o;
  }
}

extern "C" void kernel_launch(void* const* d_in, const int* in_sizes, int n_in,
                              void* d_out, int out_size, void* d_ws, size_t ws_size,
                              hipStream_t stream) {
  const float* x  = (const float*)d_in[0];
  const float* Ws = (const float*)d_in[1];
  const float* bs = (const float*)d_in[2];
  const float* Wh = (const float*)d_in[3];
  const float* bh = (const float*)d_in[4];
  const float* W1 = (const float*)d_in[5];
  const float* W2 = (const float*)d_in[6];
  const float* b2 = (const float*)d_in[7];
  float* out = (float*)d_out;

  char* ws = (char*)d_ws;
  float4* s4 = (float4*)(ws + WS_S4);
  float*  h  = (float*) (ws + WS_H);

  k1_proj<<<NPTS/64, 256, 0, stream>>>(x, Ws, bs, Wh, bh, s4, h);

  if (ws_size >= (size_t)WS_NEED_M) {
    float* agg = (float*)(ws + WS_AGG_M);
    float* wT  = (float*)(ws + WS_WT_M);
    uint4* sa  = (uint4*)(ws + WS_SA);
    uint4* sb  = (uint4*)(ws + WS_SB);
    uint4* mw  = (uint4*)(ws + WS_MASK);
    k2t_thresh<<<NPTS/16, 256, 0, stream>>>(s4, sa, sb);
    k2b_mfma<<<1024, 256, 0, stream>>>((const u16*)sa, (const u16*)sb, mw);
    k3_sel2<<<NPTS/QPB, 256, 0, stream>>>(s4, h, (const uint4*)mw, agg);
    k4a_wt<<<(192*COUT + 255)/256, 256, 0, stream>>>(W1, W2, wT);
    k4_out2<<<NPTS/32, 256, 0, stream>>>(x, agg, wT, b2, out);
  } else {
    unsigned short* cj = (unsigned short*)(ws + WS_CJ_F);
    float* agg = (float*)(ws + WS_AGG_F);
    float* wT  = (float*)(ws + WS_WT_F);
    k2_knn_fb<<<512, 256, 0, stream>>>(s4, cj);
    k3_merge_fb<<<NPTS/64, 256, 0, stream>>>(s4, (const float4*)h, cj, agg);
    k4a_wt<<<(192*COUT + 255)/256, 256, 0, stream>>>(W1, W2, wT);
    k4_out2<<<NPTS/32, 256, 0, stream>>>(x, agg, wT, b2, out);
  }
}

// Round 14
// 187.544 us; speedup vs baseline: 1.2949x; 1.0033x over previous
//
#include <hip/hip_runtime.h>
#include <hip/hip_bf16.h>

// GravNetConv: N=16384, C_IN=128, S=4, P=32, K=16, C_OUT=128.
// Mask path: [k1] proj (fp64 s) -> [k2t] threshold via radix-ladder histogram with
// FUSED operand pack + FUSED weight transpose (was k4a) -> [k2b_mfma] N^2 Gram via
// mfma_f32_32x32x16_bf16 (A=j, B=queries), bank-swizzled LDS (8-way -> 4-way),
// per-lane sign-bit pack + shfl_xor(32) merge -> dense bitmask (32 MB) ->
// [k3_sel2] low-LDS decode, 4-way gather ILP, exact re-rank -> aggregation ->
// [k4_out2] out = x@W1^T + agg@W2^T + b2.
// Fallback path (ws_size < 41MB): round-2 kernels.
// NOTE (r12): compact-list variant regressed 188.7 -> 242.9 us (scattered u16
// access, latency-bound); dense coalesced mask stream is the proven optimum.

#define NPTS 16384
#define CIN  128
#define SD   4
#define PD   32
#define KNN  16
#define COUT 128
#define FLTMAX 3.4028234663852886e+38f
#define NBIN 33
#define QPB  8      // k3 queries per block
#define QCAP 512    // per-query candidate cap
#define MCAP 192    // k3 per-query qualifier cap (ultra-rare recompute fallback beyond)
#define EPAD 1e-3f  // mask-inclusion pad >> bf16x2 Gram error bound (~2e-4)

typedef float v2f __attribute__((ext_vector_type(2)));
typedef unsigned int uint;
typedef unsigned long long u64;
typedef unsigned short u16;
typedef __attribute__((ext_vector_type(8))) short bf16x8;
typedef __attribute__((ext_vector_type(16))) float f32x16;

// ---- shared offsets (both paths) ----
#define WS_S4     0            // N * float4 = 256 KB
#define WS_H      0x40000      // N * 32 f32 = 2 MB
// ---- mask-path offsets ----
#define WS_AGG_M  0x280000     // [N][64] f32 = 4 MB (written by k3, after k2b)
#define WS_SA     0x280000     // aliases AGG: N*16 bf16 = 512 KB, dead before k3
#define WS_SB     0x300000     // aliases AGG: N*16 bf16 = 512 KB, dead before k3
#define WS_WT_M   0x680000     // [192][128] f32 = 96 KB
#define WS_MASK   0x700000     // 128 chunks * N uint4 = 32 MB
#define WS_NEED_M 0x2700000    // 40.9 MB
// ---- fallback offsets ----
#define WS_CJ_F   0x400000
#define WS_AGG_F  0xC00000
#define WS_WT_F   0x1000000
#define JS   16
#define TJF  (NPTS/JS)

__device__ __forceinline__ float d2f(const float4 a, const float4 b) {
  v2f d0 = {a.x - b.x, a.y - b.y};
  v2f d1 = {a.z - b.z, a.w - b.w};
  v2f pr = d0*d0 + d1*d1;
  return pr.x + pr.y;
}

__device__ __forceinline__ u16 f2bf(float x) {   // RNE float->bf16
  uint u = __float_as_uint(x);
  uint r = (u + 0x7FFFu + ((u >> 16) & 1u)) >> 16;
  return (u16)r;
}
__device__ __forceinline__ float bf2f(u16 h) {
  return __uint_as_float(((uint)h) << 16);
}

// ---------------- Kernel 1: s (fp64 accumulate) and h projections ----------------
__global__ __launch_bounds__(256) void k1_proj(
    const float* __restrict__ x, const float* __restrict__ Ws, const float* __restrict__ bs,
    const float* __restrict__ Wh, const float* __restrict__ bh,
    float4* __restrict__ s4, float* __restrict__ h) {
  __shared__ float  lw[36*128];
  __shared__ float  lx[64*132];
  __shared__ double rs[3*64*5];
  __shared__ float  rh[3*64*33];
  const int t = threadIdx.x;
  const int row0 = blockIdx.x * 64;
  for (int i2 = t; i2 < 36*128; i2 += 256)
    lw[i2] = (i2 < 512) ? Ws[i2] : Wh[i2 - 512];
#pragma unroll
  for (int g = 0; g < 8; ++g) {
    int fi = g*256 + t;
    int r = fi >> 5, c4 = fi & 31;
    *(float4*)&lx[r*132 + c4*4] = *(const float4*)&x[(size_t)(row0 + r)*CIN + c4*4];
  }
  __syncthreads();
  const int kq = t >> 6;
  const int r  = t & 63;
  const int kb = kq * 32;
  double sacc[4] = {0.0, 0.0, 0.0, 0.0};
  float  hacc[32];
#pragma unroll
  for (int p = 0; p < 32; ++p) hacc[p] = 0.f;
#pragma unroll
  for (int k4 = 0; k4 < 8; ++k4) {
    float4 xv = *(const float4*)&lx[r*132 + kb + k4*4];
    int kg = kb + k4*4;
#pragma unroll
    for (int p = 0; p < 4; ++p) {
      float4 wv = *(const float4*)&lw[p*128 + kg];
      sacc[p] = fma((double)xv.x, (double)wv.x, sacc[p]);
      sacc[p] = fma((double)xv.y, (double)wv.y, sacc[p]);
      sacc[p] = fma((double)xv.z, (double)wv.z, sacc[p]);
      sacc[p] = fma((double)xv.w, (double)wv.w, sacc[p]);
    }
#pragma unroll
    for (int p = 0; p < 32; ++p) {
      float4 wv = *(const float4*)&lw[(4+p)*128 + kg];
      hacc[p] = fmaf(xv.x, wv.x, fmaf(xv.y, wv.y, fmaf(xv.z, wv.z, fmaf(xv.w, wv.w, hacc[p]))));
    }
  }
  if (kq > 0) {
    const int bq = kq - 1;
#pragma unroll
    for (int d = 0; d < 4; ++d) rs[(bq*64 + r)*5 + d] = sacc[d];
#pragma unroll
    for (int p = 0; p < 32; ++p) rh[(bq*64 + r)*33 + p] = hacc[p];
  }
  __syncthreads();
  if (kq == 0) {
    const int row = row0 + r;
    float so[4];
#pragma unroll
    for (int d = 0; d < 4; ++d) {
      double sd = sacc[d] + rs[(0*64 + r)*5 + d] + rs[(1*64 + r)*5 + d]
                + rs[(2*64 + r)*5 + d] + (double)bs[d];
      so[d] = (float)sd;
    }
    s4[row] = make_float4(so[0], so[1], so[2], so[3]);
#pragma unroll
    for (int p4 = 0; p4 < 8; ++p4) {
      float o[4];
#pragma unroll
      for (int c = 0; c < 4; ++c) {
        int p = p4*4 + c;
        o[c] = hacc[p] + rh[(0*64 + r)*33 + p] + rh[(1*64 + r)*33 + p]
             + rh[(2*64 + r)*33 + p] + bh[p];
      }
      *(float4*)&h[(size_t)row*PD + p4*4] = make_float4(o[0], o[1], o[2], o[3]);
    }
  }
}

// ---------------- Kernel 2t: threshold + FUSED operand pack + FUSED weight pack -----
__global__ __launch_bounds__(256) void k2t_thresh(
    const float4* __restrict__ s4, uint4* __restrict__ sA, uint4* __restrict__ sB,
    const float* __restrict__ W1, const float* __restrict__ W2, float* __restrict__ wT) {
  __shared__ float4 tile[2064];
  __shared__ uint   lhist[256*NBIN];
  const int t = threadIdx.x;
  // fused k4a: pack/transpose weights (first 96 blocks, exactly 1 elem/thread)
  if (blockIdx.x < 96) {
    int idx = blockIdx.x*256 + t;
    int kk = idx >> 7, c = idx & 127;
    float v = (kk < 128) ? W1[(size_t)c*128 + kk] : W2[(size_t)c*64 + (kk - 128)];
    wT[(size_t)kk*COUT + c] = v;
  }
#pragma unroll
  for (int g = 0; g < 8; ++g) {
    int j = g*256 + t;
    tile[j + (j >> 7)] = s4[j];
  }
#pragma unroll
  for (int b = 0; b < NBIN; ++b) lhist[t*NBIN + b] = 0u;
  const int ql = t >> 4, tq = t & 15;
  const int q  = blockIdx.x*16 + ql;
  const float4 sq = s4[q];
  __syncthreads();
  float tau = d2f(sq, tile[tq*129]);
#pragma unroll
  for (int m = 1; m < 16; m <<= 1) tau = fmaxf(tau, __shfl_xor(tau, m, 16));
  const int ktop = (int)(__float_as_uint(tau) >> 21);
  const int hb = t*NBIN;
#pragma unroll 4
  for (int u = 0; u < 128; ++u) {
    float4 p = tile[tq*129 + u];
    float e = d2f(sq, p);
    int key = (int)(__float_as_uint(e) >> 21);
    int rel = ktop - key;
    rel = rel < 0 ? 0 : (rel > 32 ? 32 : rel);
    atomicAdd(&lhist[hb + rel], 1u);
  }
  __syncthreads();
  uint c0 = 0, c1 = 0;
  const int qb = ql*16;
  for (int u = 0; u < 16; ++u) {
    c0 += lhist[(qb + u)*NBIN + tq*2];
    c1 += (tq*2 + 1 < NBIN) ? lhist[(qb + u)*NBIN + tq*2 + 1] : 0u;
  }
  int S = (int)(c0 + c1);
#pragma unroll
  for (int d = 1; d < 16; d <<= 1) {
    int v = __shfl_down(S, d, 16);
    S += (tq + d < 16) ? v : 0;
  }
  int g = -1;
  if (S >= KNN) g = 2*tq;
  if (S - (int)c0 >= KNN) g = 2*tq + 1;
#pragma unroll
  for (int m = 1; m < 16; m <<= 1) g = max(g, __shfl_xor(g, m, 16));
  if (tq == 0) {
    uint K = (uint)(ktop - g);
    const float tv = __uint_as_float((K << 21) | 0x1FFFFFu);
    // ---- fused operand pack ----
    float sv[4] = {sq.x, sq.y, sq.z, sq.w};
    const float n2 = sq.x*sq.x + sq.y*sq.y + sq.z*sq.z + sq.w*sq.w;
    u16 hbv[4], lbv[4];
#pragma unroll
    for (int d = 0; d < 4; ++d) {
      u16 hh = f2bf(sv[d]);
      hbv[d] = hh;
      lbv[d] = f2bf(sv[d] - bf2f(hh));
    }
    const float aq = -0.5f*(n2 - tv) + EPAD;
    const float bn = -0.5f*n2;
    u16 aqh = f2bf(aq); u16 aql = f2bf(aq - bf2f(aqh));
    u16 bnh = f2bf(bn); u16 bnl = f2bf(bn - bf2f(bnh));
    const uint oneone = 0x3F803F80u;
    uint a0 = (uint)hbv[0] | ((uint)hbv[1] << 16);
    uint a1 = (uint)hbv[2] | ((uint)hbv[3] << 16);
    uint l0 = (uint)lbv[0] | ((uint)lbv[1] << 16);
    uint l1 = (uint)lbv[2] | ((uint)lbv[3] << 16);
    uint aqw = (uint)aqh | ((uint)aql << 16);
    uint bnw = (uint)bnh | ((uint)bnl << 16);
    uint4 A0; A0.x = a0; A0.y = a1; A0.z = a0; A0.w = a1;
    uint4 A1; A1.x = l0; A1.y = l1; A1.z = oneone; A1.w = aqw;
    uint4 B0; B0.x = a0; B0.y = a1; B0.z = l0; B0.w = l1;
    uint4 B1; B1.x = a0; B1.y = a1; B1.z = bnw; B1.w = oneone;
    sA[(size_t)q*2]     = A0;
    sA[(size_t)q*2 + 1] = A1;
    sB[(size_t)q*2]     = B0;
    sB[(size_t)q*2 + 1] = B1;
  }
}

// per-lane pack of 16 predicate bits from a 32x32 MFMA accumulator.
__device__ __forceinline__ uint packbits16(const f32x16 a, const int shft) {
  uint b[4];
#pragma unroll
  for (int g = 0; g < 4; ++g) {
    uint bg = 0u;
#pragma unroll
    for (int e = 3; e >= 0; --e)
      bg = bg + bg + ((~__float_as_uint(a[4*g + e])) >> 31);
    b[g] = bg;
  }
  return (b[0] | (b[1] << 8) | (b[2] << 16) | (b[3] << 24)) << shft;
}

// ---------------- Kernel 2b: N^2 Gram via 32x32x16 MFMA, per-lane bit pack -----------
// LDS bank swizzle: row r's two 16B halves are swapped when (r>>2)&1, spreading
// consecutive rows across all 32 banks (8-way -> 4-way conflict on ds_read_b128).
__global__ __launch_bounds__(256) void k2b_mfma(
    const u16* __restrict__ sA, const u16* __restrict__ sB, uint4* __restrict__ maskw) {
  __shared__ u16 lB[1024*16];                // 32 KB: 1024 j-rows x 32 B
  const int t   = threadIdx.x;
  const int wv  = t >> 6, ln = t & 63;
  const int l31 = ln & 31, hi = ln >> 5;
  const int qbase = (blockIdx.x >> 4) * 256 + wv * 64;
  const int j0    = (blockIdx.x & 15) * 1024;
  for (int r = t; r < 1024; r += 256) {
    const uint4* src = (const uint4*)&sB[(size_t)(j0 + r)*16];
    uint4 v0 = src[0], v1 = src[1];
    const int sw = (r >> 2) & 1;
    *(uint4*)&lB[r*16 + sw*8]       = v0;   // elements 0..7
    *(uint4*)&lB[r*16 + (sw^1)*8]   = v1;   // elements 8..15
  }
  const bf16x8 qf0 = *(const bf16x8*)&sA[(size_t)(qbase + l31)*16 + hi*8];
  const bf16x8 qf1 = *(const bf16x8*)&sA[(size_t)(qbase + 32 + l31)*16 + hi*8];
  __syncthreads();
  const int sh = hi * 4;
  const f32x16 zc = {0.f,0.f,0.f,0.f,0.f,0.f,0.f,0.f,0.f,0.f,0.f,0.f,0.f,0.f,0.f,0.f};
#pragma unroll 1
  for (int cc = 0; cc < 8; ++cc) {
    uint w0[4], w1[4];
#pragma unroll
    for (int jt = 0; jt < 4; ++jt) {
      const int row = cc*128 + jt*32 + l31;
      const bf16x8 af = *(const bf16x8*)&lB[row*16 + (hi ^ ((row >> 2) & 1))*8];
      f32x16 a0 = __builtin_amdgcn_mfma_f32_32x32x16_bf16(af, qf0, zc, 0, 0, 0);
      f32x16 a1 = __builtin_amdgcn_mfma_f32_32x32x16_bf16(af, qf1, zc, 0, 0, 0);
      w0[jt] = packbits16(a0, sh);
      w1[jt] = packbits16(a1, sh);
    }
    uint of[4];
#pragma unroll
    for (int jt = 0; jt < 4; ++jt) {
      uint f0 = w0[jt] | (uint)__shfl_xor((int)w0[jt], 32);
      uint f1 = w1[jt] | (uint)__shfl_xor((int)w1[jt], 32);
      of[jt] = hi ? f1 : f0;
    }
    const int c = (blockIdx.x & 15)*8 + cc;
    uint4 o; o.x = of[0]; o.y = of[1]; o.z = of[2]; o.w = of[3];
    maskw[(size_t)c*NPTS + qbase + ln] = o;
  }
}

// ---------------- Kernel 3: low-LDS decode + exact re-rank + aggregation -------------
// block = 8 queries x 32 lanes. r10 structure + 4-way gather ILP in pass 1.
__global__ __launch_bounds__(256) void k3_sel2(
    const float4* __restrict__ s4, const float* __restrict__ h,
    const uint4* __restrict__ maskw, float* __restrict__ agg) {
  __shared__ unsigned short jl[QPB*QCAP];   // 8 KB
  __shared__ u16  cls[QPB*QCAP];            // 8 KB
  __shared__ u64  qbuf[QPB*MCAP];           // 12 KB
  __shared__ u64  win[QPB*KNN];             // 1 KB
  __shared__ uint hist[QPB*32];             // 1 KB
  __shared__ uint cnts[QPB];
  __shared__ uint mc[QPB];
  const int t  = threadIdx.x;
  const int ql = t >> 5, ln = t & 31;
  const int q  = blockIdx.x*QPB + ql;
  if (ln == 0) { cnts[ql] = 0u; mc[ql] = 0u; }
  hist[ql*32 + ln] = 0u;
  if (ln < KNN) win[ql*KNN + ln] = 0ull;
  const float4 sq = s4[q];
  __syncthreads();
  // ---- phase A: batch-issue all 4 mask loads, then decode (order-free compaction) ----
  const int qa = t & 7;
  const int cg = t >> 3;
  uint4 m[4];
#pragma unroll
  for (int u = 0; u < 4; ++u)
    m[u] = maskw[(size_t)(cg + u*32)*NPTS + blockIdx.x*QPB + qa];
  int pc = 0;
#pragma unroll
  for (int u = 0; u < 4; ++u)
    pc += __popc(m[u].x) + __popc(m[u].y) + __popc(m[u].z) + __popc(m[u].w);
  int base = (int)atomicAdd(&cnts[qa], (uint)pc);
#pragma unroll
  for (int u = 0; u < 4; ++u) {
    uint wvs[4] = {m[u].x, m[u].y, m[u].z, m[u].w};
#pragma unroll
    for (int w = 0; w < 4; ++w) {
      uint bits = wvs[w];
      const int jb = (cg + u*32)*128 + w*32;
      while (bits) {
        int b = __builtin_ctz(bits); bits &= bits - 1;
        if (base < QCAP) jl[qa*QCAP + base] = (unsigned short)(jb + b);
        ++base;
      }
    }
  }
  __syncthreads();
  const int cnt = min((int)cnts[ql], QCAP);
  // ---- pass 1: gather d2 once (4-way then 2-way ILP), store class, track kmax ----
  uint kmax = 0u;
  {
    int u = ln;
    for (; u + 96 < cnt; u += 128) {
      int j0v = jl[ql*QCAP + u];
      int j1v = jl[ql*QCAP + u + 32];
      int j2v = jl[ql*QCAP + u + 64];
      int j3v = jl[ql*QCAP + u + 96];
      float e0 = d2f(sq, s4[j0v]);
      float e1 = d2f(sq, s4[j1v]);
      float e2 = d2f(sq, s4[j2v]);
      float e3 = d2f(sq, s4[j3v]);
      uint c0v = __float_as_uint(e0) >> 21;
      uint c1v = __float_as_uint(e1) >> 21;
      uint c2v = __float_as_uint(e2) >> 21;
      uint c3v = __float_as_uint(e3) >> 21;
      cls[ql*QCAP + u]      = (u16)c0v;
      cls[ql*QCAP + u + 32] = (u16)c1v;
      cls[ql*QCAP + u + 64] = (u16)c2v;
      cls[ql*QCAP + u + 96] = (u16)c3v;
      kmax = max(kmax, max(max(c0v, c1v), max(c2v, c3v)));
    }
    for (; u + 32 < cnt; u += 64) {
      int ja = jl[ql*QCAP + u];
      int jb = jl[ql*QCAP + u + 32];
      float ea = d2f(sq, s4[ja]);
      float eb = d2f(sq, s4[jb]);
      uint ca = __float_as_uint(ea) >> 21;
      uint cb = __float_as_uint(eb) >> 21;
      cls[ql*QCAP + u]      = (u16)ca;
      cls[ql*QCAP + u + 32] = (u16)cb;
      kmax = max(kmax, max(ca, cb));
    }
    if (u < cnt) {
      int j = jl[ql*QCAP + u];
      float e = d2f(sq, s4[j]);
      uint cv = __float_as_uint(e) >> 21;
      cls[ql*QCAP + u] = (u16)cv;
      kmax = max(kmax, cv);
    }
  }
#pragma unroll
  for (int m2 = 1; m2 < 32; m2 <<= 1) kmax = max(kmax, (uint)__shfl_xor((int)kmax, m2, 32));
  // ---- histogram from class array (own-lane positions only) ----
  for (int u = ln; u < cnt; u += 32) {
    uint cv = cls[ql*QCAP + u];
    uint rel = min(kmax - cv, 31u);
    atomicAdd(&hist[ql*32 + rel], 1u);
  }
  __syncthreads();
  // ---- boundary: largest r* with cum(r*) >= need; bcls = kmax - r* ----
  uint cum = hist[ql*32 + ln];
#pragma unroll
  for (int d = 1; d < 32; d <<= 1) {
    uint v = (uint)__shfl_down((int)cum, d, 32);
    if (ln + d < 32) cum += v;
  }
  const uint need = (uint)(cnt < KNN ? cnt : KNN);
  u64 bal = __ballot(cum >= need);
  uint half = (uint)(bal >> (((t >> 5) & 1) * 32));
  const uint rstar = 31u - (uint)__builtin_clz(half);
  const uint bcls = kmax - rstar;
  __syncthreads();
  // ---- compact qualifiers: recompute exact d2 (bit-identical), build u64 key ----
  for (int u = ln; u < cnt; u += 32) {
    if ((uint)cls[ql*QCAP + u] <= bcls) {
      int j = jl[ql*QCAP + u];
      float e = d2f(sq, s4[j]);
      u64 key = ((u64)__float_as_uint(e) << 14) | (uint)j;
      uint pos = atomicAdd(&mc[ql], 1u);
      if (pos < MCAP) qbuf[ql*MCAP + pos] = key;
    }
  }
  __syncthreads();
  const int mcnt = (int)mc[ql];
  if (mcnt <= MCAP) {
    for (int w = ln; w < mcnt; w += 32) {
      u64 key = qbuf[ql*MCAP + w];
      int rank = 0;
      for (int v = 0; v < mcnt; ++v) rank += (qbuf[ql*MCAP + v] < key) ? 1 : 0;
      if (rank < KNN) win[ql*KNN + rank] = key;
    }
  } else {
    // ultra-rare correct fallback: rank each qualifier against ALL candidates
    for (int u = ln; u < cnt; u += 32) {
      if ((uint)cls[ql*QCAP + u] <= bcls) {
        int j = jl[ql*QCAP + u];
        float e = d2f(sq, s4[j]);
        u64 key = ((u64)__float_as_uint(e) << 14) | (uint)j;
        int rank = 0;
        for (int v = 0; v < cnt; ++v) {
          int jv = jl[ql*QCAP + v];
          float ev = d2f(sq, s4[jv]);
          u64 kv2 = ((u64)__float_as_uint(ev) << 14) | (uint)jv;
          rank += (kv2 < key) ? 1 : 0;
        }
        if (rank < KNN) win[ql*KNN + rank] = key;
      }
    }
  }
  __syncthreads();
  // ---- aggregation: 4-way unrolled (independent win->h gather chains) ----
  float sum = 0.f, mx = -FLTMAX;
#pragma unroll
  for (int r4 = 0; r4 < 4; ++r4) {
    u64 k0 = win[ql*KNN + r4*4 + 0];
    u64 k1 = win[ql*KNN + r4*4 + 1];
    u64 k2 = win[ql*KNN + r4*4 + 2];
    u64 k3v = win[ql*KNN + r4*4 + 3];
    int j0 = (int)(k0 & 16383u), j1 = (int)(k1 & 16383u);
    int j2 = (int)(k2 & 16383u), j3 = (int)(k3v & 16383u);
    float h0 = h[(size_t)j0*PD + ln];
    float h1 = h[(size_t)j1*PD + ln];
    float h2 = h[(size_t)j2*PD + ln];
    float h3 = h[(size_t)j3*PD + ln];
    float w0 = __expf(-10.f * __uint_as_float((uint)(k0 >> 14)));
    float w1 = __expf(-10.f * __uint_as_float((uint)(k1 >> 14)));
    float w2 = __expf(-10.f * __uint_as_float((uint)(k2 >> 14)));
    float w3 = __expf(-10.f * __uint_as_float((uint)(k3v >> 14)));
    float m0 = w0*h0, m1 = w1*h1, m2 = w2*h2, m3 = w3*h3;
    sum += m0 + m1 + m2 + m3;
    mx = fmaxf(mx, fmaxf(fmaxf(m0, m1), fmaxf(m2, m3)));
  }
  agg[(size_t)q*64 + ln]      = sum * 0.0625f;
  agg[(size_t)q*64 + 32 + ln] = mx;
}

// ================= Fallback path (round-2, proven) =================
__global__ __launch_bounds__(256) void k2_knn_fb(
    const float4* __restrict__ s4, unsigned short* __restrict__ cand_j) {
  __shared__ float4 tile[TJF];
  __shared__ int    lbuf[256*33];
  const int t  = threadIdx.x;
  const int ib = blockIdx.x & 31;
  const int jc = blockIdx.x >> 5;
  const int jbase = jc * TJF;
#pragma unroll
  for (int g = 0; g < 4; ++g) tile[g*256 + t] = s4[jbase + g*256 + t];
  const int ia = ib*256 + t;
  const int ic = ia + 8192;
  const float4 sa = s4[ia];
  const float4 sc = s4[ic];
  __syncthreads();
  float va[KNN], vb[KNN]; int ja[KNN], jb[KNN];
#pragma unroll
  for (int q = 0; q < KNN; ++q) { va[q] = FLTMAX; ja[q] = 0; vb[q] = FLTMAX; jb[q] = 0; }
  float cma = FLTMAX, cmb = FLTMAX;
  int cpa = 0, cpb = 0, ca = 0, cb = 0;
  auto insertA = [&](float e, int jj) {
#pragma unroll
    for (int q = 0; q < KNN; ++q) if (q == cpa) { va[q] = e; ja[q] = jj; }
    cma = va[0]; cpa = 0;
#pragma unroll
    for (int q = 1; q < KNN; ++q) { if (va[q] > cma) { cma = va[q]; cpa = q; } }
  };
  auto insertB = [&](float e, int jj) {
#pragma unroll
    for (int q = 0; q < KNN; ++q) if (q == cpb) { vb[q] = e; jb[q] = jj; }
    cmb = vb[0]; cpb = 0;
#pragma unroll
    for (int q = 1; q < KNN; ++q) { if (vb[q] > cmb) { cmb = vb[q]; cpb = q; } }
  };
  auto compactA = [&]() {
    for (int u = 0; u < ca; ++u) {
      int jj = lbuf[t*33 + u];
      float e = d2f(sa, tile[jj]);
      if (e < cma) insertA(e, jj);
    }
    ca = 0;
  };
  auto compactB = [&]() {
    for (int u = 0; u < cb; ++u) {
      int jj = lbuf[t*33 + 16 + u];
      float e = d2f(sc, tile[jj]);
      if (e < cmb) insertB(e, jj);
    }
    cb = 0;
  };
  for (int ob = 0; ob < TJF/8; ++ob) {
#pragma unroll
    for (int u = 0; u < 8; ++u) {
      int jj = ob*8 + u;
      float4 p = tile[jj];
      float ea = d2f(sa, p);
      float eb = d2f(sc, p);
      if (ea < cma) { lbuf[t*33 + ca] = jj; ++ca; }
      if (eb < cmb) { lbuf[t*33 + 16 + cb] = jj; ++cb; }
    }
    if (__any(ca > 8)) compactA();
    if (__any(cb > 8)) compactB();
  }
  compactA(); compactB();
#pragma unroll
  for (int q = 0; q < KNN; ++q) {
    int c = jc*KNN + q;
    cand_j[(size_t)c*NPTS + ia] = (unsigned short)(ja[q] + jbase);
    cand_j[(size_t)c*NPTS + ic] = (unsigned short)(jb[q] + jbase);
  }
}

__global__ __launch_bounds__(256) void k3_merge_fb(
    const float4* __restrict__ s4, const float4* __restrict__ h4,
    const unsigned short* __restrict__ cand_j, float* __restrict__ agg) {
  __shared__ float le[64*67];
  __shared__ int   lj[64*67];
  const int t  = threadIdx.x;
  const int il = t & 63, tq = t >> 6;
  const int i  = blockIdx.x*64 + il;
  const float4 si = s4[i];
  float val[KNN]; int vid[KNN];
#pragma unroll
  for (int q = 0; q < KNN; ++q) { val[q] = FLTMAX; vid[q] = 0; }
  float cmax = FLTMAX; int cpos = 0;
  for (int u = 0; u < 64; ++u) {
    int c = tq*64 + u;
    int j = cand_j[(size_t)c*NPTS + i];
    float e = d2f(si, s4[j]);
    if (e < cmax) {
#pragma unroll
      for (int q = 0; q < KNN; ++q) if (q == cpos) { val[q] = e; vid[q] = j; }
      cmax = val[0]; cpos = 0;
#pragma unroll
      for (int q = 1; q < KNN; ++q) { if (val[q] > cmax) { cmax = val[q]; cpos = q; } }
    }
  }
#pragma unroll
  for (int q = 0; q < KNN; ++q) {
    le[il*67 + tq*16 + q] = val[q];
    lj[il*67 + tq*16 + q] = vid[q];
  }
  __syncthreads();
  if (t < 64) {
    float mv[KNN]; int mj[KNN];
#pragma unroll
    for (int q = 0; q < KNN; ++q) { mv[q] = FLTMAX; mj[q] = 0; }
    float cm2 = FLTMAX; int cp2 = 0;
    for (int u = 0; u < 64; ++u) {
      float e = le[t*67 + u];
      int   j = lj[t*67 + u];
      if (e < cm2) {
#pragma unroll
        for (int q = 0; q < KNN; ++q) if (q == cp2) { mv[q] = e; mj[q] = j; }
        cm2 = mv[0]; cp2 = 0;
#pragma unroll
        for (int q = 1; q < KNN; ++q) { if (mv[q] > cm2) { cm2 = mv[q]; cp2 = q; } }
      }
    }
#pragma unroll
    for (int q = 0; q < KNN; ++q) {
      le[t*67 + q] = __expf(-10.f * mv[q]);
      lj[t*67 + q] = mj[q];
    }
  }
  __syncthreads();
  float ms[8], mm[8];
#pragma unroll
  for (int p = 0; p < 8; ++p) { ms[p] = 0.f; mm[p] = -FLTMAX; }
#pragma unroll 1
  for (int q = 0; q < KNN; ++q) {
    float w = le[il*67 + q];
    int   j = lj[il*67 + q];
    float4 a = h4[(size_t)j*8 + tq*2];
    float4 b = h4[(size_t)j*8 + tq*2 + 1];
    float m0 = a.x*w, m1 = a.y*w, m2 = a.z*w, m3 = a.w*w;
    float m4 = b.x*w, m5 = b.y*w, m6 = b.z*w, m7 = b.w*w;
    ms[0] += m0; mm[0] = fmaxf(mm[0], m0);
    ms[1] += m1; mm[1] = fmaxf(mm[1], m1);
    ms[2] += m2; mm[2] = fmaxf(mm[2], m2);
    ms[3] += m3; mm[3] = fmaxf(mm[3], m3);
    ms[4] += m4; mm[4] = fmaxf(mm[4], m4);
    ms[5] += m5; mm[5] = fmaxf(mm[5], m5);
    ms[6] += m6; mm[6] = fmaxf(mm[6], m6);
    ms[7] += m7; mm[7] = fmaxf(mm[7], m7);
  }
  float4 o0 = make_float4(ms[0]*0.0625f, ms[1]*0.0625f, ms[2]*0.0625f, ms[3]*0.0625f);
  float4 o1 = make_float4(ms[4]*0.0625f, ms[5]*0.0625f, ms[6]*0.0625f, ms[7]*0.0625f);
  *(float4*)&agg[(size_t)i*64 + tq*8]      = o0;
  *(float4*)&agg[(size_t)i*64 + tq*8 + 4]  = o1;
  *(float4*)&agg[(size_t)i*64 + 32 + tq*8]     = make_float4(mm[0], mm[1], mm[2], mm[3]);
  *(float4*)&agg[(size_t)i*64 + 32 + tq*8 + 4] = make_float4(mm[4], mm[5], mm[6], mm[7]);
}

// ---------------- Kernel 4a: pack/transpose weights (fallback path only) -------------
__global__ __launch_bounds__(256) void k4a_wt(
    const float* __restrict__ W1, const float* __restrict__ W2, float* __restrict__ wT) {
  int idx = blockIdx.x*256 + threadIdx.x;
  if (idx >= 192*COUT) return;
  int k = idx >> 7, c = idx & 127;
  float v = (k < 128) ? W1[(size_t)c*128 + k] : W2[(size_t)c*64 + (k - 128)];
  wT[(size_t)k*COUT + c] = v;
}

// ---------------- Kernel 4: out = x@W1^T + agg@W2^T + b2 (32x128 tile, 4x4/thread) ----------
__global__ __launch_bounds__(256) void k4_out2(
    const float* __restrict__ x, const float* __restrict__ agg,
    const float* __restrict__ wT, const float* __restrict__ b2,
    float* __restrict__ out) {
  __shared__ float xa[32*192];
  const int t = threadIdx.x;
  const int row0 = blockIdx.x * 32;
#pragma unroll
  for (int g = 0; g < 4; ++g) {
    int fi = g*256 + t;
    int r = fi >> 5, c4 = fi & 31;
    *(float4*)&xa[r*192 + c4*4] = *(const float4*)&x[(size_t)(row0+r)*CIN + c4*4];
  }
#pragma unroll
  for (int g = 0; g < 2; ++g) {
    int fi = g*256 + t;
    int r = fi >> 4, c4 = fi & 15;
    *(float4*)&xa[r*192 + 128 + c4*4] = *(const float4*)&agg[(size_t)(row0+r)*64 + c4*4];
  }
  __syncthreads();
  const int c4 = t & 31;
  const int rg = t >> 5;
  float acc[4][4];
#pragma unroll
  for (int r = 0; r < 4; ++r) { acc[r][0]=0.f; acc[r][1]=0.f; acc[r][2]=0.f; acc[r][3]=0.f; }
  for (int k = 0; k < 192; k += 4) {
    float4 w0 = *(const float4*)&wT[(size_t)(k+0)*COUT + c4*4];
    float4 w1 = *(const float4*)&wT[(size_t)(k+1)*COUT + c4*4];
    float4 w2 = *(const float4*)&wT[(size_t)(k+2)*COUT + c4*4];
    float4 w3 = *(const float4*)&wT[(size_t)(k+3)*COUT + c4*4];
#pragma unroll
    for (int r = 0; r < 4; ++r) {
      float4 xv = *(const float4*)&xa[(rg*4 + r)*192 + k];
      acc[r][0] = fmaf(xv.x, w0.x, fmaf(xv.y, w1.x, fmaf(xv.z, w2.x, fmaf(xv.w, w3.x, acc[r][0]))));
      acc[r][1] = fmaf(xv.x, w0.y, fmaf(xv.y, w1.y, fmaf(xv.z, w2.y, fmaf(xv.w, w3.y, acc[r][1]))));
      acc[r][2] = fmaf(xv.x, w0.z, fmaf(xv.y, w1.z, fmaf(xv.z, w2.z, fmaf(xv.w, w3.z, acc[r][2]))));
      acc[r][3] = fmaf(xv.x, w0.w, fmaf(xv.y, w1.w, fmaf(xv.z, w2.w, fmaf(xv.w, w3.w, acc[r][3]))));
    }
  }
  float4 bias = *(const float4*)&b2[c4*4];
#pragma unroll
  for (int r = 0; r < 4; ++r) {
    float4 o = make_float4(acc[r][0]+bias.x, acc[r][1]+bias.y, acc[r][2]+bias.z, acc[r][3]+bias.w);
    *(float4*)&out[(size_t)(row0 + rg*4 + r)*COUT + c4*4] = o;
  }
}

extern "C" void kernel_launch(void* const* d_in, const int* in_sizes, int n_in,
                              void* d_out, int out_size, void* d_ws, size_t ws_size,
                              hipStream_t stream) {
  const float* x  = (const float*)d_in[0];
  const float* Ws = (const float*)d_in[1];
  const float* bs = (const float*)d_in[2];
  const float* Wh = (const float*)d_in[3];
  const float* bh = (const float*)d_in[4];
  const float* W1 = (const float*)d_in[5];
  const float* W2 = (const float*)d_in[6];
  const float* b2 = (const float*)d_in[7];
  float* out = (float*)d_out;

  char* ws = (char*)d_ws;
  float4* s4 = (float4*)(ws + WS_S4);
  float*  h  = (float*) (ws + WS_H);

  k1_proj<<<NPTS/64, 256, 0, stream>>>(x, Ws, bs, Wh, bh, s4, h);

  if (ws_size >= (size_t)WS_NEED_M) {
    float* agg = (float*)(ws + WS_AGG_M);
    float* wT  = (float*)(ws + WS_WT_M);
    uint4* sa  = (uint4*)(ws + WS_SA);
    uint4* sb  = (uint4*)(ws + WS_SB);
    uint4* mw  = (uint4*)(ws + WS_MASK);
    k2t_thresh<<<NPTS/16, 256, 0, stream>>>(s4, sa, sb, W1, W2, wT);
    k2b_mfma<<<1024, 256, 0, stream>>>((const u16*)sa, (const u16*)sb, mw);
    k3_sel2<<<NPTS/QPB, 256, 0, stream>>>(s4, h, (const uint4*)mw, agg);
    k4_out2<<<NPTS/32, 256, 0, stream>>>(x, agg, wT, b2, out);
  } else {
    unsigned short* cj = (unsigned short*)(ws + WS_CJ_F);
    float* agg = (float*)(ws + WS_AGG_F);
    float* wT  = (float*)(ws + WS_WT_F);
    k2_knn_fb<<<512, 256, 0, stream>>>(s4, cj);
    k3_merge_fb<<<NPTS/64, 256, 0, stream>>>(s4, (const float4*)h, cj, agg);
    k4a_wt<<<(192*COUT + 255)/256, 256, 0, stream>>>(W1, W2, wT);
    k4_out2<<<NPTS/32, 256, 0, stream>>>(x, agg, wT, b2, out);
  }
}

// Round 15
// 183.727 us; speedup vs baseline: 1.3218x; 1.0208x over previous
//
#include <hip/hip_runtime.h>
#include <hip/hip_bf16.h>

// GravNetConv: N=16384, C_IN=128, S=4, P=32, K=16, C_OUT=128.
// Mask path: [k1] proj (fp64 s) -> [k2t] threshold via radix-ladder histogram with
// FUSED operand pack + FUSED weight transpose -> [k2b_mfma] N^2 Gram via
// mfma_f32_32x32x16_bf16 (A=j, B=queries), j-split grid (2048 blocks x 512 j,
// 16 KB LDS -> 10 blocks/CU), bank-swizzled LDS, per-lane sign-bit pack +
// shfl_xor(32) merge -> dense bitmask (32 MB) -> [k3_sel2] low-LDS decode,
// 4-way gather ILP, exact re-rank -> aggregation -> [k4_out2].
// Fallback path (ws_size < 41MB): round-2 kernels.
// NOTE (r12): compact-list variant regressed 188.7 -> 242.9 us; dense coalesced
// mask stream is the proven optimum on this chip (latency >> bytes).

#define NPTS 16384
#define CIN  128
#define SD   4
#define PD   32
#define KNN  16
#define COUT 128
#define FLTMAX 3.4028234663852886e+38f
#define NBIN 33
#define QPB  8      // k3 queries per block
#define QCAP 512    // per-query candidate cap
#define MCAP 192    // k3 per-query qualifier cap (ultra-rare recompute fallback beyond)
#define EPAD 1e-3f  // mask-inclusion pad >> bf16x2 Gram error bound (~2e-4)

typedef float v2f __attribute__((ext_vector_type(2)));
typedef unsigned int uint;
typedef unsigned long long u64;
typedef unsigned short u16;
typedef __attribute__((ext_vector_type(8))) short bf16x8;
typedef __attribute__((ext_vector_type(16))) float f32x16;

// ---- shared offsets (both paths) ----
#define WS_S4     0            // N * float4 = 256 KB
#define WS_H      0x40000      // N * 32 f32 = 2 MB
// ---- mask-path offsets ----
#define WS_AGG_M  0x280000     // [N][64] f32 = 4 MB (written by k3, after k2b)
#define WS_SA     0x280000     // aliases AGG: N*16 bf16 = 512 KB, dead before k3
#define WS_SB     0x300000     // aliases AGG: N*16 bf16 = 512 KB, dead before k3
#define WS_WT_M   0x680000     // [192][128] f32 = 96 KB
#define WS_MASK   0x700000     // 128 chunks * N uint4 = 32 MB
#define WS_NEED_M 0x2700000    // 40.9 MB
// ---- fallback offsets ----
#define WS_CJ_F   0x400000
#define WS_AGG_F  0xC00000
#define WS_WT_F   0x1000000
#define JS   16
#define TJF  (NPTS/JS)

__device__ __forceinline__ float d2f(const float4 a, const float4 b) {
  v2f d0 = {a.x - b.x, a.y - b.y};
  v2f d1 = {a.z - b.z, a.w - b.w};
  v2f pr = d0*d0 + d1*d1;
  return pr.x + pr.y;
}

__device__ __forceinline__ u16 f2bf(float x) {   // RNE float->bf16
  uint u = __float_as_uint(x);
  uint r = (u + 0x7FFFu + ((u >> 16) & 1u)) >> 16;
  return (u16)r;
}
__device__ __forceinline__ float bf2f(u16 h) {
  return __uint_as_float(((uint)h) << 16);
}

// ---------------- Kernel 1: s (fp64 accumulate) and h projections ----------------
__global__ __launch_bounds__(256) void k1_proj(
    const float* __restrict__ x, const float* __restrict__ Ws, const float* __restrict__ bs,
    const float* __restrict__ Wh, const float* __restrict__ bh,
    float4* __restrict__ s4, float* __restrict__ h) {
  __shared__ float  lw[36*128];
  __shared__ float  lx[64*132];
  __shared__ double rs[3*64*5];
  __shared__ float  rh[3*64*33];
  const int t = threadIdx.x;
  const int row0 = blockIdx.x * 64;
  for (int i2 = t; i2 < 36*128; i2 += 256)
    lw[i2] = (i2 < 512) ? Ws[i2] : Wh[i2 - 512];
#pragma unroll
  for (int g = 0; g < 8; ++g) {
    int fi = g*256 + t;
    int r = fi >> 5, c4 = fi & 31;
    *(float4*)&lx[r*132 + c4*4] = *(const float4*)&x[(size_t)(row0 + r)*CIN + c4*4];
  }
  __syncthreads();
  const int kq = t >> 6;
  const int r  = t & 63;
  const int kb = kq * 32;
  double sacc[4] = {0.0, 0.0, 0.0, 0.0};
  float  hacc[32];
#pragma unroll
  for (int p = 0; p < 32; ++p) hacc[p] = 0.f;
#pragma unroll
  for (int k4 = 0; k4 < 8; ++k4) {
    float4 xv = *(const float4*)&lx[r*132 + kb + k4*4];
    int kg = kb + k4*4;
#pragma unroll
    for (int p = 0; p < 4; ++p) {
      float4 wv = *(const float4*)&lw[p*128 + kg];
      sacc[p] = fma((double)xv.x, (double)wv.x, sacc[p]);
      sacc[p] = fma((double)xv.y, (double)wv.y, sacc[p]);
      sacc[p] = fma((double)xv.z, (double)wv.z, sacc[p]);
      sacc[p] = fma((double)xv.w, (double)wv.w, sacc[p]);
    }
#pragma unroll
    for (int p = 0; p < 32; ++p) {
      float4 wv = *(const float4*)&lw[(4+p)*128 + kg];
      hacc[p] = fmaf(xv.x, wv.x, fmaf(xv.y, wv.y, fmaf(xv.z, wv.z, fmaf(xv.w, wv.w, hacc[p]))));
    }
  }
  if (kq > 0) {
    const int bq = kq - 1;
#pragma unroll
    for (int d = 0; d < 4; ++d) rs[(bq*64 + r)*5 + d] = sacc[d];
#pragma unroll
    for (int p = 0; p < 32; ++p) rh[(bq*64 + r)*33 + p] = hacc[p];
  }
  __syncthreads();
  if (kq == 0) {
    const int row = row0 + r;
    float so[4];
#pragma unroll
    for (int d = 0; d < 4; ++d) {
      double sd = sacc[d] + rs[(0*64 + r)*5 + d] + rs[(1*64 + r)*5 + d]
                + rs[(2*64 + r)*5 + d] + (double)bs[d];
      so[d] = (float)sd;
    }
    s4[row] = make_float4(so[0], so[1], so[2], so[3]);
#pragma unroll
    for (int p4 = 0; p4 < 8; ++p4) {
      float o[4];
#pragma unroll
      for (int c = 0; c < 4; ++c) {
        int p = p4*4 + c;
        o[c] = hacc[p] + rh[(0*64 + r)*33 + p] + rh[(1*64 + r)*33 + p]
             + rh[(2*64 + r)*33 + p] + bh[p];
      }
      *(float4*)&h[(size_t)row*PD + p4*4] = make_float4(o[0], o[1], o[2], o[3]);
    }
  }
}

// ---------------- Kernel 2t: threshold + FUSED operand pack + FUSED weight pack -----
__global__ __launch_bounds__(256) void k2t_thresh(
    const float4* __restrict__ s4, uint4* __restrict__ sA, uint4* __restrict__ sB,
    const float* __restrict__ W1, const float* __restrict__ W2, float* __restrict__ wT) {
  __shared__ float4 tile[2064];
  __shared__ uint   lhist[256*NBIN];
  const int t = threadIdx.x;
  // fused k4a: pack/transpose weights (first 96 blocks, exactly 1 elem/thread)
  if (blockIdx.x < 96) {
    int idx = blockIdx.x*256 + t;
    int kk = idx >> 7, c = idx & 127;
    float v = (kk < 128) ? W1[(size_t)c*128 + kk] : W2[(size_t)c*64 + (kk - 128)];
    wT[(size_t)kk*COUT + c] = v;
  }
#pragma unroll
  for (int g = 0; g < 8; ++g) {
    int j = g*256 + t;
    tile[j + (j >> 7)] = s4[j];
  }
#pragma unroll
  for (int b = 0; b < NBIN; ++b) lhist[t*NBIN + b] = 0u;
  const int ql = t >> 4, tq = t & 15;
  const int q  = blockIdx.x*16 + ql;
  const float4 sq = s4[q];
  __syncthreads();
  float tau = d2f(sq, tile[tq*129]);
#pragma unroll
  for (int m = 1; m < 16; m <<= 1) tau = fmaxf(tau, __shfl_xor(tau, m, 16));
  const int ktop = (int)(__float_as_uint(tau) >> 21);
  const int hb = t*NBIN;
#pragma unroll 4
  for (int u = 0; u < 128; ++u) {
    float4 p = tile[tq*129 + u];
    float e = d2f(sq, p);
    int key = (int)(__float_as_uint(e) >> 21);
    int rel = ktop - key;
    rel = rel < 0 ? 0 : (rel > 32 ? 32 : rel);
    atomicAdd(&lhist[hb + rel], 1u);
  }
  __syncthreads();
  uint c0 = 0, c1 = 0;
  const int qb = ql*16;
  for (int u = 0; u < 16; ++u) {
    c0 += lhist[(qb + u)*NBIN + tq*2];
    c1 += (tq*2 + 1 < NBIN) ? lhist[(qb + u)*NBIN + tq*2 + 1] : 0u;
  }
  int S = (int)(c0 + c1);
#pragma unroll
  for (int d = 1; d < 16; d <<= 1) {
    int v = __shfl_down(S, d, 16);
    S += (tq + d < 16) ? v : 0;
  }
  int g = -1;
  if (S >= KNN) g = 2*tq;
  if (S - (int)c0 >= KNN) g = 2*tq + 1;
#pragma unroll
  for (int m = 1; m < 16; m <<= 1) g = max(g, __shfl_xor(g, m, 16));
  if (tq == 0) {
    uint K = (uint)(ktop - g);
    const float tv = __uint_as_float((K << 21) | 0x1FFFFFu);
    // ---- fused operand pack ----
    float sv[4] = {sq.x, sq.y, sq.z, sq.w};
    const float n2 = sq.x*sq.x + sq.y*sq.y + sq.z*sq.z + sq.w*sq.w;
    u16 hbv[4], lbv[4];
#pragma unroll
    for (int d = 0; d < 4; ++d) {
      u16 hh = f2bf(sv[d]);
      hbv[d] = hh;
      lbv[d] = f2bf(sv[d] - bf2f(hh));
    }
    const float aq = -0.5f*(n2 - tv) + EPAD;
    const float bn = -0.5f*n2;
    u16 aqh = f2bf(aq); u16 aql = f2bf(aq - bf2f(aqh));
    u16 bnh = f2bf(bn); u16 bnl = f2bf(bn - bf2f(bnh));
    const uint oneone = 0x3F803F80u;
    uint a0 = (uint)hbv[0] | ((uint)hbv[1] << 16);
    uint a1 = (uint)hbv[2] | ((uint)hbv[3] << 16);
    uint l0 = (uint)lbv[0] | ((uint)lbv[1] << 16);
    uint l1 = (uint)lbv[2] | ((uint)lbv[3] << 16);
    uint aqw = (uint)aqh | ((uint)aql << 16);
    uint bnw = (uint)bnh | ((uint)bnl << 16);
    uint4 A0; A0.x = a0; A0.y = a1; A0.z = a0; A0.w = a1;
    uint4 A1; A1.x = l0; A1.y = l1; A1.z = oneone; A1.w = aqw;
    uint4 B0; B0.x = a0; B0.y = a1; B0.z = l0; B0.w = l1;
    uint4 B1; B1.x = a0; B1.y = a1; B1.z = bnw; B1.w = oneone;
    sA[(size_t)q*2]     = A0;
    sA[(size_t)q*2 + 1] = A1;
    sB[(size_t)q*2]     = B0;
    sB[(size_t)q*2 + 1] = B1;
  }
}

// per-lane pack of 16 predicate bits from a 32x32 MFMA accumulator.
__device__ __forceinline__ uint packbits16(const f32x16 a, const int shft) {
  uint b[4];
#pragma unroll
  for (int g = 0; g < 4; ++g) {
    uint bg = 0u;
#pragma unroll
    for (int e = 3; e >= 0; --e)
      bg = bg + bg + ((~__float_as_uint(a[4*g + e])) >> 31);
    b[g] = bg;
  }
  return (b[0] | (b[1] << 8) | (b[2] << 16) | (b[3] << 24)) << shft;
}

// ---------------- Kernel 2b: N^2 Gram via 32x32x16 MFMA, per-lane bit pack -----------
// j-SPLIT grid: 64 q-blocks x 32 j-chunks (512 j each) = 2048 blocks, 16 KB LDS
// -> up to 10 blocks/CU resident (was 4-5): staging of one block overlaps compute
// of co-resident neighbors. Bank swizzle: row halves swapped when (r>>2)&1.
__global__ __launch_bounds__(256) void k2b_mfma(
    const u16* __restrict__ sA, const u16* __restrict__ sB, uint4* __restrict__ maskw) {
  __shared__ u16 lB[512*16];                 // 16 KB: 512 j-rows x 32 B
  const int t   = threadIdx.x;
  const int wv  = t >> 6, ln = t & 63;
  const int l31 = ln & 31, hi = ln >> 5;
  const int qbase = (blockIdx.x >> 5) * 256 + wv * 64;
  const int jc    = blockIdx.x & 31;         // j-chunk of 512
  const int j0    = jc * 512;
  for (int r = t; r < 512; r += 256) {
    const uint4* src = (const uint4*)&sB[(size_t)(j0 + r)*16];
    uint4 v0 = src[0], v1 = src[1];
    const int sw = (r >> 2) & 1;
    *(uint4*)&lB[r*16 + sw*8]       = v0;   // elements 0..7
    *(uint4*)&lB[r*16 + (sw^1)*8]   = v1;   // elements 8..15
  }
  const bf16x8 qf0 = *(const bf16x8*)&sA[(size_t)(qbase + l31)*16 + hi*8];
  const bf16x8 qf1 = *(const bf16x8*)&sA[(size_t)(qbase + 32 + l31)*16 + hi*8];
  __syncthreads();
  const int sh = hi * 4;
  const f32x16 zc = {0.f,0.f,0.f,0.f,0.f,0.f,0.f,0.f,0.f,0.f,0.f,0.f,0.f,0.f,0.f,0.f};
#pragma unroll 1
  for (int cc = 0; cc < 4; ++cc) {
    uint w0[4], w1[4];
#pragma unroll
    for (int jt = 0; jt < 4; ++jt) {
      const int row = cc*128 + jt*32 + l31;
      const bf16x8 af = *(const bf16x8*)&lB[row*16 + (hi ^ ((row >> 2) & 1))*8];
      f32x16 a0 = __builtin_amdgcn_mfma_f32_32x32x16_bf16(af, qf0, zc, 0, 0, 0);
      f32x16 a1 = __builtin_amdgcn_mfma_f32_32x32x16_bf16(af, qf1, zc, 0, 0, 0);
      w0[jt] = packbits16(a0, sh);
      w1[jt] = packbits16(a1, sh);
    }
    uint of[4];
#pragma unroll
    for (int jt = 0; jt < 4; ++jt) {
      uint f0 = w0[jt] | (uint)__shfl_xor((int)w0[jt], 32);
      uint f1 = w1[jt] | (uint)__shfl_xor((int)w1[jt], 32);
      of[jt] = hi ? f1 : f0;
    }
    const int c = jc*4 + cc;                 // chunk index 0..127
    uint4 o; o.x = of[0]; o.y = of[1]; o.z = of[2]; o.w = of[3];
    maskw[(size_t)c*NPTS + qbase + ln] = o;
  }
}

// ---------------- Kernel 3: low-LDS decode + exact re-rank + aggregation -------------
// block = 8 queries x 32 lanes. r10 structure + 4-way gather ILP in pass 1.
__global__ __launch_bounds__(256) void k3_sel2(
    const float4* __restrict__ s4, const float* __restrict__ h,
    const uint4* __restrict__ maskw, float* __restrict__ agg) {
  __shared__ unsigned short jl[QPB*QCAP];   // 8 KB
  __shared__ u16  cls[QPB*QCAP];            // 8 KB
  __shared__ u64  qbuf[QPB*MCAP];           // 12 KB
  __shared__ u64  win[QPB*KNN];             // 1 KB
  __shared__ uint hist[QPB*32];             // 1 KB
  __shared__ uint cnts[QPB];
  __shared__ uint mc[QPB];
  const int t  = threadIdx.x;
  const int ql = t >> 5, ln = t & 31;
  const int q  = blockIdx.x*QPB + ql;
  if (ln == 0) { cnts[ql] = 0u; mc[ql] = 0u; }
  hist[ql*32 + ln] = 0u;
  if (ln < KNN) win[ql*KNN + ln] = 0ull;
  const float4 sq = s4[q];
  __syncthreads();
  // ---- phase A: batch-issue all 4 mask loads, then decode (order-free compaction) ----
  const int qa = t & 7;
  const int cg = t >> 3;
  uint4 m[4];
#pragma unroll
  for (int u = 0; u < 4; ++u)
    m[u] = maskw[(size_t)(cg + u*32)*NPTS + blockIdx.x*QPB + qa];
  int pc = 0;
#pragma unroll
  for (int u = 0; u < 4; ++u)
    pc += __popc(m[u].x) + __popc(m[u].y) + __popc(m[u].z) + __popc(m[u].w);
  int base = (int)atomicAdd(&cnts[qa], (uint)pc);
#pragma unroll
  for (int u = 0; u < 4; ++u) {
    uint wvs[4] = {m[u].x, m[u].y, m[u].z, m[u].w};
#pragma unroll
    for (int w = 0; w < 4; ++w) {
      uint bits = wvs[w];
      const int jb = (cg + u*32)*128 + w*32;
      while (bits) {
        int b = __builtin_ctz(bits); bits &= bits - 1;
        if (base < QCAP) jl[qa*QCAP + base] = (unsigned short)(jb + b);
        ++base;
      }
    }
  }
  __syncthreads();
  const int cnt = min((int)cnts[ql], QCAP);
  // ---- pass 1: gather d2 once (4-way then 2-way ILP), store class, track kmax ----
  uint kmax = 0u;
  {
    int u = ln;
    for (; u + 96 < cnt; u += 128) {
      int j0v = jl[ql*QCAP + u];
      int j1v = jl[ql*QCAP + u + 32];
      int j2v = jl[ql*QCAP + u + 64];
      int j3v = jl[ql*QCAP + u + 96];
      float e0 = d2f(sq, s4[j0v]);
      float e1 = d2f(sq, s4[j1v]);
      float e2 = d2f(sq, s4[j2v]);
      float e3 = d2f(sq, s4[j3v]);
      uint c0v = __float_as_uint(e0) >> 21;
      uint c1v = __float_as_uint(e1) >> 21;
      uint c2v = __float_as_uint(e2) >> 21;
      uint c3v = __float_as_uint(e3) >> 21;
      cls[ql*QCAP + u]      = (u16)c0v;
      cls[ql*QCAP + u + 32] = (u16)c1v;
      cls[ql*QCAP + u + 64] = (u16)c2v;
      cls[ql*QCAP + u + 96] = (u16)c3v;
      kmax = max(kmax, max(max(c0v, c1v), max(c2v, c3v)));
    }
    for (; u + 32 < cnt; u += 64) {
      int ja = jl[ql*QCAP + u];
      int jb = jl[ql*QCAP + u + 32];
      float ea = d2f(sq, s4[ja]);
      float eb = d2f(sq, s4[jb]);
      uint ca = __float_as_uint(ea) >> 21;
      uint cb = __float_as_uint(eb) >> 21;
      cls[ql*QCAP + u]      = (u16)ca;
      cls[ql*QCAP + u + 32] = (u16)cb;
      kmax = max(kmax, max(ca, cb));
    }
    if (u < cnt) {
      int j = jl[ql*QCAP + u];
      float e = d2f(sq, s4[j]);
      uint cv = __float_as_uint(e) >> 21;
      cls[ql*QCAP + u] = (u16)cv;
      kmax = max(kmax, cv);
    }
  }
#pragma unroll
  for (int m2 = 1; m2 < 32; m2 <<= 1) kmax = max(kmax, (uint)__shfl_xor((int)kmax, m2, 32));
  // ---- histogram from class array (own-lane positions only) ----
  for (int u = ln; u < cnt; u += 32) {
    uint cv = cls[ql*QCAP + u];
    uint rel = min(kmax - cv, 31u);
    atomicAdd(&hist[ql*32 + rel], 1u);
  }
  __syncthreads();
  // ---- boundary: largest r* with cum(r*) >= need; bcls = kmax - r* ----
  uint cum = hist[ql*32 + ln];
#pragma unroll
  for (int d = 1; d < 32; d <<= 1) {
    uint v = (uint)__shfl_down((int)cum, d, 32);
    if (ln + d < 32) cum += v;
  }
  const uint need = (uint)(cnt < KNN ? cnt : KNN);
  u64 bal = __ballot(cum >= need);
  uint half = (uint)(bal >> (((t >> 5) & 1) * 32));
  const uint rstar = 31u - (uint)__builtin_clz(half);
  const uint bcls = kmax - rstar;
  __syncthreads();
  // ---- compact qualifiers: recompute exact d2 (bit-identical), build u64 key ----
  for (int u = ln; u < cnt; u += 32) {
    if ((uint)cls[ql*QCAP + u] <= bcls) {
      int j = jl[ql*QCAP + u];
      float e = d2f(sq, s4[j]);
      u64 key = ((u64)__float_as_uint(e) << 14) | (uint)j;
      uint pos = atomicAdd(&mc[ql], 1u);
      if (pos < MCAP) qbuf[ql*MCAP + pos] = key;
    }
  }
  __syncthreads();
  const int mcnt = (int)mc[ql];
  if (mcnt <= MCAP) {
    for (int w = ln; w < mcnt; w += 32) {
      u64 key = qbuf[ql*MCAP + w];
      int rank = 0;
      for (int v = 0; v < mcnt; ++v) rank += (qbuf[ql*MCAP + v] < key) ? 1 : 0;
      if (rank < KNN) win[ql*KNN + rank] = key;
    }
  } else {
    // ultra-rare correct fallback: rank each qualifier against ALL candidates
    for (int u = ln; u < cnt; u += 32) {
      if ((uint)cls[ql*QCAP + u] <= bcls) {
        int j = jl[ql*QCAP + u];
        float e = d2f(sq, s4[j]);
        u64 key = ((u64)__float_as_uint(e) << 14) | (uint)j;
        int rank = 0;
        for (int v = 0; v < cnt; ++v) {
          int jv = jl[ql*QCAP + v];
          float ev = d2f(sq, s4[jv]);
          u64 kv2 = ((u64)__float_as_uint(ev) << 14) | (uint)jv;
          rank += (kv2 < key) ? 1 : 0;
        }
        if (rank < KNN) win[ql*KNN + rank] = key;
      }
    }
  }
  __syncthreads();
  // ---- aggregation: 4-way unrolled (independent win->h gather chains) ----
  float sum = 0.f, mx = -FLTMAX;
#pragma unroll
  for (int r4 = 0; r4 < 4; ++r4) {
    u64 k0 = win[ql*KNN + r4*4 + 0];
    u64 k1 = win[ql*KNN + r4*4 + 1];
    u64 k2 = win[ql*KNN + r4*4 + 2];
    u64 k3v = win[ql*KNN + r4*4 + 3];
    int j0 = (int)(k0 & 16383u), j1 = (int)(k1 & 16383u);
    int j2 = (int)(k2 & 16383u), j3 = (int)(k3v & 16383u);
    float h0 = h[(size_t)j0*PD + ln];
    float h1 = h[(size_t)j1*PD + ln];
    float h2 = h[(size_t)j2*PD + ln];
    float h3 = h[(size_t)j3*PD + ln];
    float w0 = __expf(-10.f * __uint_as_float((uint)(k0 >> 14)));
    float w1 = __expf(-10.f * __uint_as_float((uint)(k1 >> 14)));
    float w2 = __expf(-10.f * __uint_as_float((uint)(k2 >> 14)));
    float w3 = __expf(-10.f * __uint_as_float((uint)(k3v >> 14)));
    float m0 = w0*h0, m1 = w1*h1, m2 = w2*h2, m3 = w3*h3;
    sum += m0 + m1 + m2 + m3;
    mx = fmaxf(mx, fmaxf(fmaxf(m0, m1), fmaxf(m2, m3)));
  }
  agg[(size_t)q*64 + ln]      = sum * 0.0625f;
  agg[(size_t)q*64 + 32 + ln] = mx;
}

// ================= Fallback path (round-2, proven) =================
__global__ __launch_bounds__(256) void k2_knn_fb(
    const float4* __restrict__ s4, unsigned short* __restrict__ cand_j) {
  __shared__ float4 tile[TJF];
  __shared__ int    lbuf[256*33];
  const int t  = threadIdx.x;
  const int ib = blockIdx.x & 31;
  const int jc = blockIdx.x >> 5;
  const int jbase = jc * TJF;
#pragma unroll
  for (int g = 0; g < 4; ++g) tile[g*256 + t] = s4[jbase + g*256 + t];
  const int ia = ib*256 + t;
  const int ic = ia + 8192;
  const float4 sa = s4[ia];
  const float4 sc = s4[ic];
  __syncthreads();
  float va[KNN], vb[KNN]; int ja[KNN], jb[KNN];
#pragma unroll
  for (int q = 0; q < KNN; ++q) { va[q] = FLTMAX; ja[q] = 0; vb[q] = FLTMAX; jb[q] = 0; }
  float cma = FLTMAX, cmb = FLTMAX;
  int cpa = 0, cpb = 0, ca = 0, cb = 0;
  auto insertA = [&](float e, int jj) {
#pragma unroll
    for (int q = 0; q < KNN; ++q) if (q == cpa) { va[q] = e; ja[q] = jj; }
    cma = va[0]; cpa = 0;
#pragma unroll
    for (int q = 1; q < KNN; ++q) { if (va[q] > cma) { cma = va[q]; cpa = q; } }
  };
  auto insertB = [&](float e, int jj) {
#pragma unroll
    for (int q = 0; q < KNN; ++q) if (q == cpb) { vb[q] = e; jb[q] = jj; }
    cmb = vb[0]; cpb = 0;
#pragma unroll
    for (int q = 1; q < KNN; ++q) { if (vb[q] > cmb) { cmb = vb[q]; cpb = q; } }
  };
  auto compactA = [&]() {
    for (int u = 0; u < ca; ++u) {
      int jj = lbuf[t*33 + u];
      float e = d2f(sa, tile[jj]);
      if (e < cma) insertA(e, jj);
    }
    ca = 0;
  };
  auto compactB = [&]() {
    for (int u = 0; u < cb; ++u) {
      int jj = lbuf[t*33 + 16 + u];
      float e = d2f(sc, tile[jj]);
      if (e < cmb) insertB(e, jj);
    }
    cb = 0;
  };
  for (int ob = 0; ob < TJF/8; ++ob) {
#pragma unroll
    for (int u = 0; u < 8; ++u) {
      int jj = ob*8 + u;
      float4 p = tile[jj];
      float ea = d2f(sa, p);
      float eb = d2f(sc, p);
      if (ea < cma) { lbuf[t*33 + ca] = jj; ++ca; }
      if (eb < cmb) { lbuf[t*33 + 16 + cb] = jj; ++cb; }
    }
    if (__any(ca > 8)) compactA();
    if (__any(cb > 8)) compactB();
  }
  compactA(); compactB();
#pragma unroll
  for (int q = 0; q < KNN; ++q) {
    int c = jc*KNN + q;
    cand_j[(size_t)c*NPTS + ia] = (unsigned short)(ja[q] + jbase);
    cand_j[(size_t)c*NPTS + ic] = (unsigned short)(jb[q] + jbase);
  }
}

__global__ __launch_bounds__(256) void k3_merge_fb(
    const float4* __restrict__ s4, const float4* __restrict__ h4,
    const unsigned short* __restrict__ cand_j, float* __restrict__ agg) {
  __shared__ float le[64*67];
  __shared__ int   lj[64*67];
  const int t  = threadIdx.x;
  const int il = t & 63, tq = t >> 6;
  const int i  = blockIdx.x*64 + il;
  const float4 si = s4[i];
  float val[KNN]; int vid[KNN];
#pragma unroll
  for (int q = 0; q < KNN; ++q) { val[q] = FLTMAX; vid[q] = 0; }
  float cmax = FLTMAX; int cpos = 0;
  for (int u = 0; u < 64; ++u) {
    int c = tq*64 + u;
    int j = cand_j[(size_t)c*NPTS + i];
    float e = d2f(si, s4[j]);
    if (e < cmax) {
#pragma unroll
      for (int q = 0; q < KNN; ++q) if (q == cpos) { val[q] = e; vid[q] = j; }
      cmax = val[0]; cpos = 0;
#pragma unroll
      for (int q = 1; q < KNN; ++q) { if (val[q] > cmax) { cmax = val[q]; cpos = q; } }
    }
  }
#pragma unroll
  for (int q = 0; q < KNN; ++q) {
    le[il*67 + tq*16 + q] = val[q];
    lj[il*67 + tq*16 + q] = vid[q];
  }
  __syncthreads();
  if (t < 64) {
    float mv[KNN]; int mj[KNN];
#pragma unroll
    for (int q = 0; q < KNN; ++q) { mv[q] = FLTMAX; mj[q] = 0; }
    float cm2 = FLTMAX; int cp2 = 0;
    for (int u = 0; u < 64; ++u) {
      float e = le[t*67 + u];
      int   j = lj[t*67 + u];
      if (e < cm2) {
#pragma unroll
        for (int q = 0; q < KNN; ++q) if (q == cp2) { mv[q] = e; mj[q] = j; }
        cm2 = mv[0]; cp2 = 0;
#pragma unroll
        for (int q = 1; q < KNN; ++q) { if (mv[q] > cm2) { cm2 = mv[q]; cp2 = q; } }
      }
    }
#pragma unroll
    for (int q = 0; q < KNN; ++q) {
      le[t*67 + q] = __expf(-10.f * mv[q]);
      lj[t*67 + q] = mj[q];
    }
  }
  __syncthreads();
  float ms[8], mm[8];
#pragma unroll
  for (int p = 0; p < 8; ++p) { ms[p] = 0.f; mm[p] = -FLTMAX; }
#pragma unroll 1
  for (int q = 0; q < KNN; ++q) {
    float w = le[il*67 + q];
    int   j = lj[il*67 + q];
    float4 a = h4[(size_t)j*8 + tq*2];
    float4 b = h4[(size_t)j*8 + tq*2 + 1];
    float m0 = a.x*w, m1 = a.y*w, m2 = a.z*w, m3 = a.w*w;
    float m4 = b.x*w, m5 = b.y*w, m6 = b.z*w, m7 = b.w*w;
    ms[0] += m0; mm[0] = fmaxf(mm[0], m0);
    ms[1] += m1; mm[1] = fmaxf(mm[1], m1);
    ms[2] += m2; mm[2] = fmaxf(mm[2], m2);
    ms[3] += m3; mm[3] = fmaxf(mm[3], m3);
    ms[4] += m4; mm[4] = fmaxf(mm[4], m4);
    ms[5] += m5; mm[5] = fmaxf(mm[5], m5);
    ms[6] += m6; mm[6] = fmaxf(mm[6], m6);
    ms[7] += m7; mm[7] = fmaxf(mm[7], m7);
  }
  float4 o0 = make_float4(ms[0]*0.0625f, ms[1]*0.0625f, ms[2]*0.0625f, ms[3]*0.0625f);
  float4 o1 = make_float4(ms[4]*0.0625f, ms[5]*0.0625f, ms[6]*0.0625f, ms[7]*0.0625f);
  *(float4*)&agg[(size_t)i*64 + tq*8]      = o0;
  *(float4*)&agg[(size_t)i*64 + tq*8 + 4]  = o1;
  *(float4*)&agg[(size_t)i*64 + 32 + tq*8]     = make_float4(mm[0], mm[1], mm[2], mm[3]);
  *(float4*)&agg[(size_t)i*64 + 32 + tq*8 + 4] = make_float4(mm[4], mm[5], mm[6], mm[7]);
}

// ---------------- Kernel 4a: pack/transpose weights (fallback path only) -------------
__global__ __launch_bounds__(256) void k4a_wt(
    const float* __restrict__ W1, const float* __restrict__ W2, float* __restrict__ wT) {
  int idx = blockIdx.x*256 + threadIdx.x;
  if (idx >= 192*COUT) return;
  int k = idx >> 7, c = idx & 127;
  float v = (k < 128) ? W1[(size_t)c*128 + k] : W2[(size_t)c*64 + (k - 128)];
  wT[(size_t)k*COUT + c] = v;
}

// ---------------- Kernel 4: out = x@W1^T + agg@W2^T + b2 (32x128 tile, 4x4/thread) ----------
__global__ __launch_bounds__(256) void k4_out2(
    const float* __restrict__ x, const float* __restrict__ agg,
    const float* __restrict__ wT, const float* __restrict__ b2,
    float* __restrict__ out) {
  __shared__ float xa[32*192];
  const int t = threadIdx.x;
  const int row0 = blockIdx.x * 32;
#pragma unroll
  for (int g = 0; g < 4; ++g) {
    int fi = g*256 + t;
    int r = fi >> 5, c4 = fi & 31;
    *(float4*)&xa[r*192 + c4*4] = *(const float4*)&x[(size_t)(row0+r)*CIN + c4*4];
  }
#pragma unroll
  for (int g = 0; g < 2; ++g) {
    int fi = g*256 + t;
    int r = fi >> 4, c4 = fi & 15;
    *(float4*)&xa[r*192 + 128 + c4*4] = *(const float4*)&agg[(size_t)(row0+r)*64 + c4*4];
  }
  __syncthreads();
  const int c4 = t & 31;
  const int rg = t >> 5;
  float acc[4][4];
#pragma unroll
  for (int r = 0; r < 4; ++r) { acc[r][0]=0.f; acc[r][1]=0.f; acc[r][2]=0.f; acc[r][3]=0.f; }
  for (int k = 0; k < 192; k += 4) {
    float4 w0 = *(const float4*)&wT[(size_t)(k+0)*COUT + c4*4];
    float4 w1 = *(const float4*)&wT[(size_t)(k+1)*COUT + c4*4];
    float4 w2 = *(const float4*)&wT[(size_t)(k+2)*COUT + c4*4];
    float4 w3 = *(const float4*)&wT[(size_t)(k+3)*COUT + c4*4];
#pragma unroll
    for (int r = 0; r < 4; ++r) {
      float4 xv = *(const float4*)&xa[(rg*4 + r)*192 + k];
      acc[r][0] = fmaf(xv.x, w0.x, fmaf(xv.y, w1.x, fmaf(xv.z, w2.x, fmaf(xv.w, w3.x, acc[r][0]))));
      acc[r][1] = fmaf(xv.x, w0.y, fmaf(xv.y, w1.y, fmaf(xv.z, w2.y, fmaf(xv.w, w3.y, acc[r][1]))));
      acc[r][2] = fmaf(xv.x, w0.z, fmaf(xv.y, w1.z, fmaf(xv.z, w2.z, fmaf(xv.w, w3.z, acc[r][2]))));
      acc[r][3] = fmaf(xv.x, w0.w, fmaf(xv.y, w1.w, fmaf(xv.z, w2.w, fmaf(xv.w, w3.w, acc[r][3]))));
    }
  }
  float4 bias = *(const float4*)&b2[c4*4];
#pragma unroll
  for (int r = 0; r < 4; ++r) {
    float4 o = make_float4(acc[r][0]+bias.x, acc[r][1]+bias.y, acc[r][2]+bias.z, acc[r][3]+bias.w);
    *(float4*)&out[(size_t)(row0 + rg*4 + r)*COUT + c4*4] = o;
  }
}

extern "C" void kernel_launch(void* const* d_in, const int* in_sizes, int n_in,
                              void* d_out, int out_size, void* d_ws, size_t ws_size,
                              hipStream_t stream) {
  const float* x  = (const float*)d_in[0];
  const float* Ws = (const float*)d_in[1];
  const float* bs = (const float*)d_in[2];
  const float* Wh = (const float*)d_in[3];
  const float* bh = (const float*)d_in[4];
  const float* W1 = (const float*)d_in[5];
  const float* W2 = (const float*)d_in[6];
  const float* b2 = (const float*)d_in[7];
  float* out = (float*)d_out;

  char* ws = (char*)d_ws;
  float4* s4 = (float4*)(ws + WS_S4);
  float*  h  = (float*) (ws + WS_H);

  k1_proj<<<NPTS/64, 256, 0, stream>>>(x, Ws, bs, Wh, bh, s4, h);

  if (ws_size >= (size_t)WS_NEED_M) {
    float* agg = (float*)(ws + WS_AGG_M);
    float* wT  = (float*)(ws + WS_WT_M);
    uint4* sa  = (uint4*)(ws + WS_SA);
    uint4* sb  = (uint4*)(ws + WS_SB);
    uint4* mw  = (uint4*)(ws + WS_MASK);
    k2t_thresh<<<NPTS/16, 256, 0, stream>>>(s4, sa, sb, W1, W2, wT);
    k2b_mfma<<<2048, 256, 0, stream>>>((const u16*)sa, (const u16*)sb, mw);
    k3_sel2<<<NPTS/QPB, 256, 0, stream>>>(s4, h, (const uint4*)mw, agg);
    k4_out2<<<NPTS/32, 256, 0, stream>>>(x, agg, wT, b2, out);
  } else {
    unsigned short* cj = (unsigned short*)(ws + WS_CJ_F);
    float* agg = (float*)(ws + WS_AGG_F);
    float* wT  = (float*)(ws + WS_WT_F);
    k2_knn_fb<<<512, 256, 0, stream>>>(s4, cj);
    k3_merge_fb<<<NPTS/64, 256, 0, stream>>>(s4, (const float4*)h, cj, agg);
    k4a_wt<<<(192*COUT + 255)/256, 256, 0, stream>>>(W1, W2, wT);
    k4_out2<<<NPTS/32, 256, 0, stream>>>(x, agg, wT, b2, out);
  }
}

// Round 16
// 182.312 us; speedup vs baseline: 1.3321x; 1.0078x over previous
//
#include <hip/hip_runtime.h>
#include <hip/hip_bf16.h>

// GravNetConv: N=16384, C_IN=128, S=4, P=32, K=16, C_OUT=128.
// Mask path: [k1] proj (fp64 s) -> [k2t] threshold via radix-ladder histogram with
// FUSED operand pack + FUSED weight transpose -> [k2b_mfma] N^2 Gram via
// mfma_f32_32x32x16_bf16 (A=j, B=queries), j-split grid (4096 blocks x 256 j,
// 8 KB LDS -> wave-capped residency), bank-swizzled LDS, per-lane sign-bit pack +
// shfl_xor(32) merge -> dense bitmask (32 MB) -> [k3_sel2] low-LDS decode (27 KB),
// 4-way gather ILP, exact re-rank -> aggregation -> [k4_out2].
// Fallback path (ws_size < 41MB): round-2 kernels.
// NOTE (r12): compact-list variant regressed 188.7 -> 242.9 us; dense coalesced
// mask stream is the proven optimum on this chip (latency >> bytes).

#define NPTS 16384
#define CIN  128
#define SD   4
#define PD   32
#define KNN  16
#define COUT 128
#define FLTMAX 3.4028234663852886e+38f
#define NBIN 33
#define QPB  8      // k3 queries per block
#define QCAP 512    // per-query candidate cap
#define MCAP 128    // k3 per-query qualifier cap (proven r5-r8; correct fallback beyond)
#define EPAD 1e-3f  // mask-inclusion pad >> bf16x2 Gram error bound (~2e-4)

typedef float v2f __attribute__((ext_vector_type(2)));
typedef unsigned int uint;
typedef unsigned long long u64;
typedef unsigned short u16;
typedef __attribute__((ext_vector_type(8))) short bf16x8;
typedef __attribute__((ext_vector_type(16))) float f32x16;

// ---- shared offsets (both paths) ----
#define WS_S4     0            // N * float4 = 256 KB
#define WS_H      0x40000      // N * 32 f32 = 2 MB
// ---- mask-path offsets ----
#define WS_AGG_M  0x280000     // [N][64] f32 = 4 MB (written by k3, after k2b)
#define WS_SA     0x280000     // aliases AGG: N*16 bf16 = 512 KB, dead before k3
#define WS_SB     0x300000     // aliases AGG: N*16 bf16 = 512 KB, dead before k3
#define WS_WT_M   0x680000     // [192][128] f32 = 96 KB
#define WS_MASK   0x700000     // 128 chunks * N uint4 = 32 MB
#define WS_NEED_M 0x2700000    // 40.9 MB
// ---- fallback offsets ----
#define WS_CJ_F   0x400000
#define WS_AGG_F  0xC00000
#define WS_WT_F   0x1000000
#define JS   16
#define TJF  (NPTS/JS)

__device__ __forceinline__ float d2f(const float4 a, const float4 b) {
  v2f d0 = {a.x - b.x, a.y - b.y};
  v2f d1 = {a.z - b.z, a.w - b.w};
  v2f pr = d0*d0 + d1*d1;
  return pr.x + pr.y;
}

__device__ __forceinline__ u16 f2bf(float x) {   // RNE float->bf16
  uint u = __float_as_uint(x);
  uint r = (u + 0x7FFFu + ((u >> 16) & 1u)) >> 16;
  return (u16)r;
}
__device__ __forceinline__ float bf2f(u16 h) {
  return __uint_as_float(((uint)h) << 16);
}

// ---------------- Kernel 1: s (fp64 accumulate) and h projections ----------------
__global__ __launch_bounds__(256) void k1_proj(
    const float* __restrict__ x, const float* __restrict__ Ws, const float* __restrict__ bs,
    const float* __restrict__ Wh, const float* __restrict__ bh,
    float4* __restrict__ s4, float* __restrict__ h) {
  __shared__ float  lw[36*128];
  __shared__ float  lx[64*132];
  __shared__ double rs[3*64*5];
  __shared__ float  rh[3*64*33];
  const int t = threadIdx.x;
  const int row0 = blockIdx.x * 64;
  for (int i2 = t; i2 < 36*128; i2 += 256)
    lw[i2] = (i2 < 512) ? Ws[i2] : Wh[i2 - 512];
#pragma unroll
  for (int g = 0; g < 8; ++g) {
    int fi = g*256 + t;
    int r = fi >> 5, c4 = fi & 31;
    *(float4*)&lx[r*132 + c4*4] = *(const float4*)&x[(size_t)(row0 + r)*CIN + c4*4];
  }
  __syncthreads();
  const int kq = t >> 6;
  const int r  = t & 63;
  const int kb = kq * 32;
  double sacc[4] = {0.0, 0.0, 0.0, 0.0};
  float  hacc[32];
#pragma unroll
  for (int p = 0; p < 32; ++p) hacc[p] = 0.f;
#pragma unroll
  for (int k4 = 0; k4 < 8; ++k4) {
    float4 xv = *(const float4*)&lx[r*132 + kb + k4*4];
    int kg = kb + k4*4;
#pragma unroll
    for (int p = 0; p < 4; ++p) {
      float4 wv = *(const float4*)&lw[p*128 + kg];
      sacc[p] = fma((double)xv.x, (double)wv.x, sacc[p]);
      sacc[p] = fma((double)xv.y, (double)wv.y, sacc[p]);
      sacc[p] = fma((double)xv.z, (double)wv.z, sacc[p]);
      sacc[p] = fma((double)xv.w, (double)wv.w, sacc[p]);
    }
#pragma unroll
    for (int p = 0; p < 32; ++p) {
      float4 wv = *(const float4*)&lw[(4+p)*128 + kg];
      hacc[p] = fmaf(xv.x, wv.x, fmaf(xv.y, wv.y, fmaf(xv.z, wv.z, fmaf(xv.w, wv.w, hacc[p]))));
    }
  }
  if (kq > 0) {
    const int bq = kq - 1;
#pragma unroll
    for (int d = 0; d < 4; ++d) rs[(bq*64 + r)*5 + d] = sacc[d];
#pragma unroll
    for (int p = 0; p < 32; ++p) rh[(bq*64 + r)*33 + p] = hacc[p];
  }
  __syncthreads();
  if (kq == 0) {
    const int row = row0 + r;
    float so[4];
#pragma unroll
    for (int d = 0; d < 4; ++d) {
      double sd = sacc[d] + rs[(0*64 + r)*5 + d] + rs[(1*64 + r)*5 + d]
                + rs[(2*64 + r)*5 + d] + (double)bs[d];
      so[d] = (float)sd;
    }
    s4[row] = make_float4(so[0], so[1], so[2], so[3]);
#pragma unroll
    for (int p4 = 0; p4 < 8; ++p4) {
      float o[4];
#pragma unroll
      for (int c = 0; c < 4; ++c) {
        int p = p4*4 + c;
        o[c] = hacc[p] + rh[(0*64 + r)*33 + p] + rh[(1*64 + r)*33 + p]
             + rh[(2*64 + r)*33 + p] + bh[p];
      }
      *(float4*)&h[(size_t)row*PD + p4*4] = make_float4(o[0], o[1], o[2], o[3]);
    }
  }
}

// ---------------- Kernel 2t: threshold + FUSED operand pack + FUSED weight pack -----
__global__ __launch_bounds__(256) void k2t_thresh(
    const float4* __restrict__ s4, uint4* __restrict__ sA, uint4* __restrict__ sB,
    const float* __restrict__ W1, const float* __restrict__ W2, float* __restrict__ wT) {
  __shared__ float4 tile[2064];
  __shared__ uint   lhist[256*NBIN];
  const int t = threadIdx.x;
  // fused k4a: pack/transpose weights (first 96 blocks, exactly 1 elem/thread)
  if (blockIdx.x < 96) {
    int idx = blockIdx.x*256 + t;
    int kk = idx >> 7, c = idx & 127;
    float v = (kk < 128) ? W1[(size_t)c*128 + kk] : W2[(size_t)c*64 + (kk - 128)];
    wT[(size_t)kk*COUT + c] = v;
  }
#pragma unroll
  for (int g = 0; g < 8; ++g) {
    int j = g*256 + t;
    tile[j + (j >> 7)] = s4[j];
  }
#pragma unroll
  for (int b = 0; b < NBIN; ++b) lhist[t*NBIN + b] = 0u;
  const int ql = t >> 4, tq = t & 15;
  const int q  = blockIdx.x*16 + ql;
  const float4 sq = s4[q];
  __syncthreads();
  float tau = d2f(sq, tile[tq*129]);
#pragma unroll
  for (int m = 1; m < 16; m <<= 1) tau = fmaxf(tau, __shfl_xor(tau, m, 16));
  const int ktop = (int)(__float_as_uint(tau) >> 21);
  const int hb = t*NBIN;
#pragma unroll 4
  for (int u = 0; u < 128; ++u) {
    float4 p = tile[tq*129 + u];
    float e = d2f(sq, p);
    int key = (int)(__float_as_uint(e) >> 21);
    int rel = ktop - key;
    rel = rel < 0 ? 0 : (rel > 32 ? 32 : rel);
    atomicAdd(&lhist[hb + rel], 1u);
  }
  __syncthreads();
  uint c0 = 0, c1 = 0;
  const int qb = ql*16;
  for (int u = 0; u < 16; ++u) {
    c0 += lhist[(qb + u)*NBIN + tq*2];
    c1 += (tq*2 + 1 < NBIN) ? lhist[(qb + u)*NBIN + tq*2 + 1] : 0u;
  }
  int S = (int)(c0 + c1);
#pragma unroll
  for (int d = 1; d < 16; d <<= 1) {
    int v = __shfl_down(S, d, 16);
    S += (tq + d < 16) ? v : 0;
  }
  int g = -1;
  if (S >= KNN) g = 2*tq;
  if (S - (int)c0 >= KNN) g = 2*tq + 1;
#pragma unroll
  for (int m = 1; m < 16; m <<= 1) g = max(g, __shfl_xor(g, m, 16));
  if (tq == 0) {
    uint K = (uint)(ktop - g);
    const float tv = __uint_as_float((K << 21) | 0x1FFFFFu);
    // ---- fused operand pack ----
    float sv[4] = {sq.x, sq.y, sq.z, sq.w};
    const float n2 = sq.x*sq.x + sq.y*sq.y + sq.z*sq.z + sq.w*sq.w;
    u16 hbv[4], lbv[4];
#pragma unroll
    for (int d = 0; d < 4; ++d) {
      u16 hh = f2bf(sv[d]);
      hbv[d] = hh;
      lbv[d] = f2bf(sv[d] - bf2f(hh));
    }
    const float aq = -0.5f*(n2 - tv) + EPAD;
    const float bn = -0.5f*n2;
    u16 aqh = f2bf(aq); u16 aql = f2bf(aq - bf2f(aqh));
    u16 bnh = f2bf(bn); u16 bnl = f2bf(bn - bf2f(bnh));
    const uint oneone = 0x3F803F80u;
    uint a0 = (uint)hbv[0] | ((uint)hbv[1] << 16);
    uint a1 = (uint)hbv[2] | ((uint)hbv[3] << 16);
    uint l0 = (uint)lbv[0] | ((uint)lbv[1] << 16);
    uint l1 = (uint)lbv[2] | ((uint)lbv[3] << 16);
    uint aqw = (uint)aqh | ((uint)aql << 16);
    uint bnw = (uint)bnh | ((uint)bnl << 16);
    uint4 A0; A0.x = a0; A0.y = a1; A0.z = a0; A0.w = a1;
    uint4 A1; A1.x = l0; A1.y = l1; A1.z = oneone; A1.w = aqw;
    uint4 B0; B0.x = a0; B0.y = a1; B0.z = l0; B0.w = l1;
    uint4 B1; B1.x = a0; B1.y = a1; B1.z = bnw; B1.w = oneone;
    sA[(size_t)q*2]     = A0;
    sA[(size_t)q*2 + 1] = A1;
    sB[(size_t)q*2]     = B0;
    sB[(size_t)q*2 + 1] = B1;
  }
}

// per-lane pack of 16 predicate bits from a 32x32 MFMA accumulator.
__device__ __forceinline__ uint packbits16(const f32x16 a, const int shft) {
  uint b[4];
#pragma unroll
  for (int g = 0; g < 4; ++g) {
    uint bg = 0u;
#pragma unroll
    for (int e = 3; e >= 0; --e)
      bg = bg + bg + ((~__float_as_uint(a[4*g + e])) >> 31);
    b[g] = bg;
  }
  return (b[0] | (b[1] << 8) | (b[2] << 16) | (b[3] << 24)) << shft;
}

// ---------------- Kernel 2b: N^2 Gram via 32x32x16 MFMA, per-lane bit pack -----------
// j-SPLIT grid: 64 q-blocks x 64 j-chunks (256 j each) = 4096 blocks, 8 KB LDS
// -> residency wave-capped (8 blocks/CU), staging fully overlapped with compute
// of co-resident blocks. Bank swizzle: row halves swapped when (r>>2)&1.
__global__ __launch_bounds__(256) void k2b_mfma(
    const u16* __restrict__ sA, const u16* __restrict__ sB, uint4* __restrict__ maskw) {
  __shared__ u16 lB[256*16];                 // 8 KB: 256 j-rows x 32 B
  const int t   = threadIdx.x;
  const int wv  = t >> 6, ln = t & 63;
  const int l31 = ln & 31, hi = ln >> 5;
  const int qbase = (blockIdx.x >> 6) * 256 + wv * 64;
  const int jc    = blockIdx.x & 63;         // j-chunk of 256
  const int j0    = jc * 256;
  {
    const int r = t;                         // one row per thread
    const uint4* src = (const uint4*)&sB[(size_t)(j0 + r)*16];
    uint4 v0 = src[0], v1 = src[1];
    const int sw = (r >> 2) & 1;
    *(uint4*)&lB[r*16 + sw*8]       = v0;   // elements 0..7
    *(uint4*)&lB[r*16 + (sw^1)*8]   = v1;   // elements 8..15
  }
  const bf16x8 qf0 = *(const bf16x8*)&sA[(size_t)(qbase + l31)*16 + hi*8];
  const bf16x8 qf1 = *(const bf16x8*)&sA[(size_t)(qbase + 32 + l31)*16 + hi*8];
  __syncthreads();
  const int sh = hi * 4;
  const f32x16 zc = {0.f,0.f,0.f,0.f,0.f,0.f,0.f,0.f,0.f,0.f,0.f,0.f,0.f,0.f,0.f,0.f};
#pragma unroll 1
  for (int cc = 0; cc < 2; ++cc) {
    uint w0[4], w1[4];
#pragma unroll
    for (int jt = 0; jt < 4; ++jt) {
      const int row = cc*128 + jt*32 + l31;
      const bf16x8 af = *(const bf16x8*)&lB[row*16 + (hi ^ ((row >> 2) & 1))*8];
      f32x16 a0 = __builtin_amdgcn_mfma_f32_32x32x16_bf16(af, qf0, zc, 0, 0, 0);
      f32x16 a1 = __builtin_amdgcn_mfma_f32_32x32x16_bf16(af, qf1, zc, 0, 0, 0);
      w0[jt] = packbits16(a0, sh);
      w1[jt] = packbits16(a1, sh);
    }
    uint of[4];
#pragma unroll
    for (int jt = 0; jt < 4; ++jt) {
      uint f0 = w0[jt] | (uint)__shfl_xor((int)w0[jt], 32);
      uint f1 = w1[jt] | (uint)__shfl_xor((int)w1[jt], 32);
      of[jt] = hi ? f1 : f0;
    }
    const int c = jc*2 + cc;                 // chunk index 0..127
    uint4 o; o.x = of[0]; o.y = of[1]; o.z = of[2]; o.w = of[3];
    maskw[(size_t)c*NPTS + qbase + ln] = o;
  }
}

// ---------------- Kernel 3: low-LDS decode + exact re-rank + aggregation -------------
// block = 8 queries x 32 lanes. 27 KB LDS (MCAP=128). 4-way gather ILP in pass 1.
__global__ __launch_bounds__(256) void k3_sel2(
    const float4* __restrict__ s4, const float* __restrict__ h,
    const uint4* __restrict__ maskw, float* __restrict__ agg) {
  __shared__ unsigned short jl[QPB*QCAP];   // 8 KB
  __shared__ u16  cls[QPB*QCAP];            // 8 KB
  __shared__ u64  qbuf[QPB*MCAP];           // 8 KB
  __shared__ u64  win[QPB*KNN];             // 1 KB
  __shared__ uint hist[QPB*32];             // 1 KB
  __shared__ uint cnts[QPB];
  __shared__ uint mc[QPB];
  const int t  = threadIdx.x;
  const int ql = t >> 5, ln = t & 31;
  const int q  = blockIdx.x*QPB + ql;
  if (ln == 0) { cnts[ql] = 0u; mc[ql] = 0u; }
  hist[ql*32 + ln] = 0u;
  if (ln < KNN) win[ql*KNN + ln] = 0ull;
  const float4 sq = s4[q];
  __syncthreads();
  // ---- phase A: batch-issue all 4 mask loads, then decode (order-free compaction) ----
  const int qa = t & 7;
  const int cg = t >> 3;
  uint4 m[4];
#pragma unroll
  for (int u = 0; u < 4; ++u)
    m[u] = maskw[(size_t)(cg + u*32)*NPTS + blockIdx.x*QPB + qa];
  int pc = 0;
#pragma unroll
  for (int u = 0; u < 4; ++u)
    pc += __popc(m[u].x) + __popc(m[u].y) + __popc(m[u].z) + __popc(m[u].w);
  int base = (int)atomicAdd(&cnts[qa], (uint)pc);
#pragma unroll
  for (int u = 0; u < 4; ++u) {
    uint wvs[4] = {m[u].x, m[u].y, m[u].z, m[u].w};
#pragma unroll
    for (int w = 0; w < 4; ++w) {
      uint bits = wvs[w];
      const int jb = (cg + u*32)*128 + w*32;
      while (bits) {
        int b = __builtin_ctz(bits); bits &= bits - 1;
        if (base < QCAP) jl[qa*QCAP + base] = (unsigned short)(jb + b);
        ++base;
      }
    }
  }
  __syncthreads();
  const int cnt = min((int)cnts[ql], QCAP);
  // ---- pass 1: gather d2 once (4-way then 2-way ILP), store class, track kmax ----
  uint kmax = 0u;
  {
    int u = ln;
    for (; u + 96 < cnt; u += 128) {
      int j0v = jl[ql*QCAP + u];
      int j1v = jl[ql*QCAP + u + 32];
      int j2v = jl[ql*QCAP + u + 64];
      int j3v = jl[ql*QCAP + u + 96];
      float e0 = d2f(sq, s4[j0v]);
      float e1 = d2f(sq, s4[j1v]);
      float e2 = d2f(sq, s4[j2v]);
      float e3 = d2f(sq, s4[j3v]);
      uint c0v = __float_as_uint(e0) >> 21;
      uint c1v = __float_as_uint(e1) >> 21;
      uint c2v = __float_as_uint(e2) >> 21;
      uint c3v = __float_as_uint(e3) >> 21;
      cls[ql*QCAP + u]      = (u16)c0v;
      cls[ql*QCAP + u + 32] = (u16)c1v;
      cls[ql*QCAP + u + 64] = (u16)c2v;
      cls[ql*QCAP + u + 96] = (u16)c3v;
      kmax = max(kmax, max(max(c0v, c1v), max(c2v, c3v)));
    }
    for (; u + 32 < cnt; u += 64) {
      int ja = jl[ql*QCAP + u];
      int jb = jl[ql*QCAP + u + 32];
      float ea = d2f(sq, s4[ja]);
      float eb = d2f(sq, s4[jb]);
      uint ca = __float_as_uint(ea) >> 21;
      uint cb = __float_as_uint(eb) >> 21;
      cls[ql*QCAP + u]      = (u16)ca;
      cls[ql*QCAP + u + 32] = (u16)cb;
      kmax = max(kmax, max(ca, cb));
    }
    if (u < cnt) {
      int j = jl[ql*QCAP + u];
      float e = d2f(sq, s4[j]);
      uint cv = __float_as_uint(e) >> 21;
      cls[ql*QCAP + u] = (u16)cv;
      kmax = max(kmax, cv);
    }
  }
#pragma unroll
  for (int m2 = 1; m2 < 32; m2 <<= 1) kmax = max(kmax, (uint)__shfl_xor((int)kmax, m2, 32));
  // ---- histogram from class array (own-lane positions only) ----
  for (int u = ln; u < cnt; u += 32) {
    uint cv = cls[ql*QCAP + u];
    uint rel = min(kmax - cv, 31u);
    atomicAdd(&hist[ql*32 + rel], 1u);
  }
  __syncthreads();
  // ---- boundary: largest r* with cum(r*) >= need; bcls = kmax - r* ----
  uint cum = hist[ql*32 + ln];
#pragma unroll
  for (int d = 1; d < 32; d <<= 1) {
    uint v = (uint)__shfl_down((int)cum, d, 32);
    if (ln + d < 32) cum += v;
  }
  const uint need = (uint)(cnt < KNN ? cnt : KNN);
  u64 bal = __ballot(cum >= need);
  uint half = (uint)(bal >> (((t >> 5) & 1) * 32));
  const uint rstar = 31u - (uint)__builtin_clz(half);
  const uint bcls = kmax - rstar;
  __syncthreads();
  // ---- compact qualifiers: recompute exact d2 (bit-identical), build u64 key ----
  for (int u = ln; u < cnt; u += 32) {
    if ((uint)cls[ql*QCAP + u] <= bcls) {
      int j = jl[ql*QCAP + u];
      float e = d2f(sq, s4[j]);
      u64 key = ((u64)__float_as_uint(e) << 14) | (uint)j;
      uint pos = atomicAdd(&mc[ql], 1u);
      if (pos < MCAP) qbuf[ql*MCAP + pos] = key;
    }
  }
  __syncthreads();
  const int mcnt = (int)mc[ql];
  if (mcnt <= MCAP) {
    for (int w = ln; w < mcnt; w += 32) {
      u64 key = qbuf[ql*MCAP + w];
      int rank = 0;
      for (int v = 0; v < mcnt; ++v) rank += (qbuf[ql*MCAP + v] < key) ? 1 : 0;
      if (rank < KNN) win[ql*KNN + rank] = key;
    }
  } else {
    // ultra-rare correct fallback: rank each qualifier against ALL candidates
    for (int u = ln; u < cnt; u += 32) {
      if ((uint)cls[ql*QCAP + u] <= bcls) {
        int j = jl[ql*QCAP + u];
        float e = d2f(sq, s4[j]);
        u64 key = ((u64)__float_as_uint(e) << 14) | (uint)j;
        int rank = 0;
        for (int v = 0; v < cnt; ++v) {
          int jv = jl[ql*QCAP + v];
          float ev = d2f(sq, s4[jv]);
          u64 kv2 = ((u64)__float_as_uint(ev) << 14) | (uint)jv;
          rank += (kv2 < key) ? 1 : 0;
        }
        if (rank < KNN) win[ql*KNN + rank] = key;
      }
    }
  }
  __syncthreads();
  // ---- aggregation: 4-way unrolled (independent win->h gather chains) ----
  float sum = 0.f, mx = -FLTMAX;
#pragma unroll
  for (int r4 = 0; r4 < 4; ++r4) {
    u64 k0 = win[ql*KNN + r4*4 + 0];
    u64 k1 = win[ql*KNN + r4*4 + 1];
    u64 k2 = win[ql*KNN + r4*4 + 2];
    u64 k3v = win[ql*KNN + r4*4 + 3];
    int j0 = (int)(k0 & 16383u), j1 = (int)(k1 & 16383u);
    int j2 = (int)(k2 & 16383u), j3 = (int)(k3v & 16383u);
    float h0 = h[(size_t)j0*PD + ln];
    float h1 = h[(size_t)j1*PD + ln];
    float h2 = h[(size_t)j2*PD + ln];
    float h3 = h[(size_t)j3*PD + ln];
    float w0 = __expf(-10.f * __uint_as_float((uint)(k0 >> 14)));
    float w1 = __expf(-10.f * __uint_as_float((uint)(k1 >> 14)));
    float w2 = __expf(-10.f * __uint_as_float((uint)(k2 >> 14)));
    float w3 = __expf(-10.f * __uint_as_float((uint)(k3v >> 14)));
    float m0 = w0*h0, m1 = w1*h1, m2 = w2*h2, m3 = w3*h3;
    sum += m0 + m1 + m2 + m3;
    mx = fmaxf(mx, fmaxf(fmaxf(m0, m1), fmaxf(m2, m3)));
  }
  agg[(size_t)q*64 + ln]      = sum * 0.0625f;
  agg[(size_t)q*64 + 32 + ln] = mx;
}

// ================= Fallback path (round-2, proven) =================
__global__ __launch_bounds__(256) void k2_knn_fb(
    const float4* __restrict__ s4, unsigned short* __restrict__ cand_j) {
  __shared__ float4 tile[TJF];
  __shared__ int    lbuf[256*33];
  const int t  = threadIdx.x;
  const int ib = blockIdx.x & 31;
  const int jc = blockIdx.x >> 5;
  const int jbase = jc * TJF;
#pragma unroll
  for (int g = 0; g < 4; ++g) tile[g*256 + t] = s4[jbase + g*256 + t];
  const int ia = ib*256 + t;
  const int ic = ia + 8192;
  const float4 sa = s4[ia];
  const float4 sc = s4[ic];
  __syncthreads();
  float va[KNN], vb[KNN]; int ja[KNN], jb[KNN];
#pragma unroll
  for (int q = 0; q < KNN; ++q) { va[q] = FLTMAX; ja[q] = 0; vb[q] = FLTMAX; jb[q] = 0; }
  float cma = FLTMAX, cmb = FLTMAX;
  int cpa = 0, cpb = 0, ca = 0, cb = 0;
  auto insertA = [&](float e, int jj) {
#pragma unroll
    for (int q = 0; q < KNN; ++q) if (q == cpa) { va[q] = e; ja[q] = jj; }
    cma = va[0]; cpa = 0;
#pragma unroll
    for (int q = 1; q < KNN; ++q) { if (va[q] > cma) { cma = va[q]; cpa = q; } }
  };
  auto insertB = [&](float e, int jj) {
#pragma unroll
    for (int q = 0; q < KNN; ++q) if (q == cpb) { vb[q] = e; jb[q] = jj; }
    cmb = vb[0]; cpb = 0;
#pragma unroll
    for (int q = 1; q < KNN; ++q) { if (vb[q] > cmb) { cmb = vb[q]; cpb = q; } }
  };
  auto compactA = [&]() {
    for (int u = 0; u < ca; ++u) {
      int jj = lbuf[t*33 + u];
      float e = d2f(sa, tile[jj]);
      if (e < cma) insertA(e, jj);
    }
    ca = 0;
  };
  auto compactB = [&]() {
    for (int u = 0; u < cb; ++u) {
      int jj = lbuf[t*33 + 16 + u];
      float e = d2f(sc, tile[jj]);
      if (e < cmb) insertB(e, jj);
    }
    cb = 0;
  };
  for (int ob = 0; ob < TJF/8; ++ob) {
#pragma unroll
    for (int u = 0; u < 8; ++u) {
      int jj = ob*8 + u;
      float4 p = tile[jj];
      float ea = d2f(sa, p);
      float eb = d2f(sc, p);
      if (ea < cma) { lbuf[t*33 + ca] = jj; ++ca; }
      if (eb < cmb) { lbuf[t*33 + 16 + cb] = jj; ++cb; }
    }
    if (__any(ca > 8)) compactA();
    if (__any(cb > 8)) compactB();
  }
  compactA(); compactB();
#pragma unroll
  for (int q = 0; q < KNN; ++q) {
    int c = jc*KNN + q;
    cand_j[(size_t)c*NPTS + ia] = (unsigned short)(ja[q] + jbase);
    cand_j[(size_t)c*NPTS + ic] = (unsigned short)(jb[q] + jbase);
  }
}

__global__ __launch_bounds__(256) void k3_merge_fb(
    const float4* __restrict__ s4, const float4* __restrict__ h4,
    const unsigned short* __restrict__ cand_j, float* __restrict__ agg) {
  __shared__ float le[64*67];
  __shared__ int   lj[64*67];
  const int t  = threadIdx.x;
  const int il = t & 63, tq = t >> 6;
  const int i  = blockIdx.x*64 + il;
  const float4 si = s4[i];
  float val[KNN]; int vid[KNN];
#pragma unroll
  for (int q = 0; q < KNN; ++q) { val[q] = FLTMAX; vid[q] = 0; }
  float cmax = FLTMAX; int cpos = 0;
  for (int u = 0; u < 64; ++u) {
    int c = tq*64 + u;
    int j = cand_j[(size_t)c*NPTS + i];
    float e = d2f(si, s4[j]);
    if (e < cmax) {
#pragma unroll
      for (int q = 0; q < KNN; ++q) if (q == cpos) { val[q] = e; vid[q] = j; }
      cmax = val[0]; cpos = 0;
#pragma unroll
      for (int q = 1; q < KNN; ++q) { if (val[q] > cmax) { cmax = val[q]; cpos = q; } }
    }
  }
#pragma unroll
  for (int q = 0; q < KNN; ++q) {
    le[il*67 + tq*16 + q] = val[q];
    lj[il*67 + tq*16 + q] = vid[q];
  }
  __syncthreads();
  if (t < 64) {
    float mv[KNN]; int mj[KNN];
#pragma unroll
    for (int q = 0; q < KNN; ++q) { mv[q] = FLTMAX; mj[q] = 0; }
    float cm2 = FLTMAX; int cp2 = 0;
    for (int u = 0; u < 64; ++u) {
      float e = le[t*67 + u];
      int   j = lj[t*67 + u];
      if (e < cm2) {
#pragma unroll
        for (int q = 0; q < KNN; ++q) if (q == cp2) { mv[q] = e; mj[q] = j; }
        cm2 = mv[0]; cp2 = 0;
#pragma unroll
        for (int q = 1; q < KNN; ++q) { if (mv[q] > cm2) { cm2 = mv[q]; cp2 = q; } }
      }
    }
#pragma unroll
    for (int q = 0; q < KNN; ++q) {
      le[t*67 + q] = __expf(-10.f * mv[q]);
      lj[t*67 + q] = mj[q];
    }
  }
  __syncthreads();
  float ms[8], mm[8];
#pragma unroll
  for (int p = 0; p < 8; ++p) { ms[p] = 0.f; mm[p] = -FLTMAX; }
#pragma unroll 1
  for (int q = 0; q < KNN; ++q) {
    float w = le[il*67 + q];
    int   j = lj[il*67 + q];
    float4 a = h4[(size_t)j*8 + tq*2];
    float4 b = h4[(size_t)j*8 + tq*2 + 1];
    float m0 = a.x*w, m1 = a.y*w, m2 = a.z*w, m3 = a.w*w;
    float m4 = b.x*w, m5 = b.y*w, m6 = b.z*w, m7 = b.w*w;
    ms[0] += m0; mm[0] = fmaxf(mm[0], m0);
    ms[1] += m1; mm[1] = fmaxf(mm[1], m1);
    ms[2] += m2; mm[2] = fmaxf(mm[2], m2);
    ms[3] += m3; mm[3] = fmaxf(mm[3], m3);
    ms[4] += m4; mm[4] = fmaxf(mm[4], m4);
    ms[5] += m5; mm[5] = fmaxf(mm[5], m5);
    ms[6] += m6; mm[6] = fmaxf(mm[6], m6);
    ms[7] += m7; mm[7] = fmaxf(mm[7], m7);
  }
  float4 o0 = make_float4(ms[0]*0.0625f, ms[1]*0.0625f, ms[2]*0.0625f, ms[3]*0.0625f);
  float4 o1 = make_float4(ms[4]*0.0625f, ms[5]*0.0625f, ms[6]*0.0625f, ms[7]*0.0625f);
  *(float4*)&agg[(size_t)i*64 + tq*8]      = o0;
  *(float4*)&agg[(size_t)i*64 + tq*8 + 4]  = o1;
  *(float4*)&agg[(size_t)i*64 + 32 + tq*8]     = make_float4(mm[0], mm[1], mm[2], mm[3]);
  *(float4*)&agg[(size_t)i*64 + 32 + tq*8 + 4] = make_float4(mm[4], mm[5], mm[6], mm[7]);
}

// ---------------- Kernel 4a: pack/transpose weights (fallback path only) -------------
__global__ __launch_bounds__(256) void k4a_wt(
    const float* __restrict__ W1, const float* __restrict__ W2, float* __restrict__ wT) {
  int idx = blockIdx.x*256 + threadIdx.x;
  if (idx >= 192*COUT) return;
  int k = idx >> 7, c = idx & 127;
  float v = (k < 128) ? W1[(size_t)c*128 + k] : W2[(size_t)c*64 + (k - 128)];
  wT[(size_t)k*COUT + c] = v;
}

// ---------------- Kernel 4: out = x@W1^T + agg@W2^T + b2 (32x128 tile, 4x4/thread) ----------
__global__ __launch_bounds__(256) void k4_out2(
    const float* __restrict__ x, const float* __restrict__ agg,
    const float* __restrict__ wT, const float* __restrict__ b2,
    float* __restrict__ out) {
  __shared__ float xa[32*192];
  const int t = threadIdx.x;
  const int row0 = blockIdx.x * 32;
#pragma unroll
  for (int g = 0; g < 4; ++g) {
    int fi = g*256 + t;
    int r = fi >> 5, c4 = fi & 31;
    *(float4*)&xa[r*192 + c4*4] = *(const float4*)&x[(size_t)(row0+r)*CIN + c4*4];
  }
#pragma unroll
  for (int g = 0; g < 2; ++g) {
    int fi = g*256 + t;
    int r = fi >> 4, c4 = fi & 15;
    *(float4*)&xa[r*192 + 128 + c4*4] = *(const float4*)&agg[(size_t)(row0+r)*64 + c4*4];
  }
  __syncthreads();
  const int c4 = t & 31;
  const int rg = t >> 5;
  float acc[4][4];
#pragma unroll
  for (int r = 0; r < 4; ++r) { acc[r][0]=0.f; acc[r][1]=0.f; acc[r][2]=0.f; acc[r][3]=0.f; }
  for (int k = 0; k < 192; k += 4) {
    float4 w0 = *(const float4*)&wT[(size_t)(k+0)*COUT + c4*4];
    float4 w1 = *(const float4*)&wT[(size_t)(k+1)*COUT + c4*4];
    float4 w2 = *(const float4*)&wT[(size_t)(k+2)*COUT + c4*4];
    float4 w3 = *(const float4*)&wT[(size_t)(k+3)*COUT + c4*4];
#pragma unroll
    for (int r = 0; r < 4; ++r) {
      float4 xv = *(const float4*)&xa[(rg*4 + r)*192 + k];
      acc[r][0] = fmaf(xv.x, w0.x, fmaf(xv.y, w1.x, fmaf(xv.z, w2.x, fmaf(xv.w, w3.x, acc[r][0]))));
      acc[r][1] = fmaf(xv.x, w0.y, fmaf(xv.y, w1.y, fmaf(xv.z, w2.y, fmaf(xv.w, w3.y, acc[r][1]))));
      acc[r][2] = fmaf(xv.x, w0.z, fmaf(xv.y, w1.z, fmaf(xv.z, w2.z, fmaf(xv.w, w3.z, acc[r][2]))));
      acc[r][3] = fmaf(xv.x, w0.w, fmaf(xv.y, w1.w, fmaf(xv.z, w2.w, fmaf(xv.w, w3.w, acc[r][3]))));
    }
  }
  float4 bias = *(const float4*)&b2[c4*4];
#pragma unroll
  for (int r = 0; r < 4; ++r) {
    float4 o = make_float4(acc[r][0]+bias.x, acc[r][1]+bias.y, acc[r][2]+bias.z, acc[r][3]+bias.w);
    *(float4*)&out[(size_t)(row0 + rg*4 + r)*COUT + c4*4] = o;
  }
}

extern "C" void kernel_launch(void* const* d_in, const int* in_sizes, int n_in,
                              void* d_out, int out_size, void* d_ws, size_t ws_size,
                              hipStream_t stream) {
  const float* x  = (const float*)d_in[0];
  const float* Ws = (const float*)d_in[1];
  const float* bs = (const float*)d_in[2];
  const float* Wh = (const float*)d_in[3];
  const float* bh = (const float*)d_in[4];
  const float* W1 = (const float*)d_in[5];
  const float* W2 = (const float*)d_in[6];
  const float* b2 = (const float*)d_in[7];
  float* out = (float*)d_out;

  char* ws = (char*)d_ws;
  float4* s4 = (float4*)(ws + WS_S4);
  float*  h  = (float*) (ws + WS_H);

  k1_proj<<<NPTS/64, 256, 0, stream>>>(x, Ws, bs, Wh, bh, s4, h);

  if (ws_size >= (size_t)WS_NEED_M) {
    float* agg = (float*)(ws + WS_AGG_M);
    float* wT  = (float*)(ws + WS_WT_M);
    uint4* sa  = (uint4*)(ws + WS_SA);
    uint4* sb  = (uint4*)(ws + WS_SB);
    uint4* mw  = (uint4*)(ws + WS_MASK);
    k2t_thresh<<<NPTS/16, 256, 0, stream>>>(s4, sa, sb, W1, W2, wT);
    k2b_mfma<<<4096, 256, 0, stream>>>((const u16*)sa, (const u16*)sb, mw);
    k3_sel2<<<NPTS/QPB, 256, 0, stream>>>(s4, h, (const uint4*)mw, agg);
    k4_out2<<<NPTS/32, 256, 0, stream>>>(x, agg, wT, b2, out);
  } else {
    unsigned short* cj = (unsigned short*)(ws + WS_CJ_F);
    float* agg = (float*)(ws + WS_AGG_F);
    float* wT  = (float*)(ws + WS_WT_F);
    k2_knn_fb<<<512, 256, 0, stream>>>(s4, cj);
    k3_merge_fb<<<NPTS/64, 256, 0, stream>>>(s4, (const float4*)h, cj, agg);
    k4a_wt<<<(192*COUT + 255)/256, 256, 0, stream>>>(W1, W2, wT);
    k4_out2<<<NPTS/32, 256, 0, stream>>>(x, agg, wT, b2, out);
  }
}

// Round 17
// 182.011 us; speedup vs baseline: 1.3343x; 1.0017x over previous
//
#include <hip/hip_runtime.h>
#include <hip/hip_bf16.h>

// GravNetConv: N=16384, C_IN=128, S=4, P=32, K=16, C_OUT=128.  [FINAL r16: 182.3 us]
// Mask path: [k1] proj (fp64 s) -> [k2t] threshold via radix-ladder histogram with
// FUSED operand pack + FUSED weight transpose -> [k2b_mfma] N^2 Gram via
// mfma_f32_32x32x16_bf16 (A=j, B=queries), j-split grid (4096 blocks x 256 j,
// 8 KB LDS -> 32 waves/CU = HW cap), bank-swizzled LDS, per-lane sign-bit pack +
// shfl_xor(32) merge -> dense bitmask (32 MB) -> [k3_sel2] low-LDS decode (27 KB),
// 4-way gather ILP, exact re-rank -> aggregation -> [k4_out2].
// Fallback path (ws_size < 41MB): round-2 kernels.
// Session ledger: fused-select (r6), 1-wave decode (r7), compact lists (r12) all
// regressed 30-110% -- dense coalesced mask stream is the optimum on this chip
// (latency >> bytes). Occupancy j-split (r15/r16) saturated at the 32-wave cap.

#define NPTS 16384
#define CIN  128
#define SD   4
#define PD   32
#define KNN  16
#define COUT 128
#define FLTMAX 3.4028234663852886e+38f
#define NBIN 33
#define QPB  8      // k3 queries per block
#define QCAP 512    // per-query candidate cap
#define MCAP 128    // k3 per-query qualifier cap (proven r5-r8; correct fallback beyond)
#define EPAD 1e-3f  // mask-inclusion pad >> bf16x2 Gram error bound (~2e-4)

typedef float v2f __attribute__((ext_vector_type(2)));
typedef unsigned int uint;
typedef unsigned long long u64;
typedef unsigned short u16;
typedef __attribute__((ext_vector_type(8))) short bf16x8;
typedef __attribute__((ext_vector_type(16))) float f32x16;

// ---- shared offsets (both paths) ----
#define WS_S4     0            // N * float4 = 256 KB
#define WS_H      0x40000      // N * 32 f32 = 2 MB
// ---- mask-path offsets ----
#define WS_AGG_M  0x280000     // [N][64] f32 = 4 MB (written by k3, after k2b)
#define WS_SA     0x280000     // aliases AGG: N*16 bf16 = 512 KB, dead before k3
#define WS_SB     0x300000     // aliases AGG: N*16 bf16 = 512 KB, dead before k3
#define WS_WT_M   0x680000     // [192][128] f32 = 96 KB
#define WS_MASK   0x700000     // 128 chunks * N uint4 = 32 MB
#define WS_NEED_M 0x2700000    // 40.9 MB
// ---- fallback offsets ----
#define WS_CJ_F   0x400000
#define WS_AGG_F  0xC00000
#define WS_WT_F   0x1000000
#define JS   16
#define TJF  (NPTS/JS)

__device__ __forceinline__ float d2f(const float4 a, const float4 b) {
  v2f d0 = {a.x - b.x, a.y - b.y};
  v2f d1 = {a.z - b.z, a.w - b.w};
  v2f pr = d0*d0 + d1*d1;
  return pr.x + pr.y;
}

__device__ __forceinline__ u16 f2bf(float x) {   // RNE float->bf16
  uint u = __float_as_uint(x);
  uint r = (u + 0x7FFFu + ((u >> 16) & 1u)) >> 16;
  return (u16)r;
}
__device__ __forceinline__ float bf2f(u16 h) {
  return __uint_as_float(((uint)h) << 16);
}

// ---------------- Kernel 1: s (fp64 accumulate) and h projections ----------------
__global__ __launch_bounds__(256) void k1_proj(
    const float* __restrict__ x, const float* __restrict__ Ws, const float* __restrict__ bs,
    const float* __restrict__ Wh, const float* __restrict__ bh,
    float4* __restrict__ s4, float* __restrict__ h) {
  __shared__ float  lw[36*128];
  __shared__ float  lx[64*132];
  __shared__ double rs[3*64*5];
  __shared__ float  rh[3*64*33];
  const int t = threadIdx.x;
  const int row0 = blockIdx.x * 64;
  for (int i2 = t; i2 < 36*128; i2 += 256)
    lw[i2] = (i2 < 512) ? Ws[i2] : Wh[i2 - 512];
#pragma unroll
  for (int g = 0; g < 8; ++g) {
    int fi = g*256 + t;
    int r = fi >> 5, c4 = fi & 31;
    *(float4*)&lx[r*132 + c4*4] = *(const float4*)&x[(size_t)(row0 + r)*CIN + c4*4];
  }
  __syncthreads();
  const int kq = t >> 6;
  const int r  = t & 63;
  const int kb = kq * 32;
  double sacc[4] = {0.0, 0.0, 0.0, 0.0};
  float  hacc[32];
#pragma unroll
  for (int p = 0; p < 32; ++p) hacc[p] = 0.f;
#pragma unroll
  for (int k4 = 0; k4 < 8; ++k4) {
    float4 xv = *(const float4*)&lx[r*132 + kb + k4*4];
    int kg = kb + k4*4;
#pragma unroll
    for (int p = 0; p < 4; ++p) {
      float4 wv = *(const float4*)&lw[p*128 + kg];
      sacc[p] = fma((double)xv.x, (double)wv.x, sacc[p]);
      sacc[p] = fma((double)xv.y, (double)wv.y, sacc[p]);
      sacc[p] = fma((double)xv.z, (double)wv.z, sacc[p]);
      sacc[p] = fma((double)xv.w, (double)wv.w, sacc[p]);
    }
#pragma unroll
    for (int p = 0; p < 32; ++p) {
      float4 wv = *(const float4*)&lw[(4+p)*128 + kg];
      hacc[p] = fmaf(xv.x, wv.x, fmaf(xv.y, wv.y, fmaf(xv.z, wv.z, fmaf(xv.w, wv.w, hacc[p]))));
    }
  }
  if (kq > 0) {
    const int bq = kq - 1;
#pragma unroll
    for (int d = 0; d < 4; ++d) rs[(bq*64 + r)*5 + d] = sacc[d];
#pragma unroll
    for (int p = 0; p < 32; ++p) rh[(bq*64 + r)*33 + p] = hacc[p];
  }
  __syncthreads();
  if (kq == 0) {
    const int row = row0 + r;
    float so[4];
#pragma unroll
    for (int d = 0; d < 4; ++d) {
      double sd = sacc[d] + rs[(0*64 + r)*5 + d] + rs[(1*64 + r)*5 + d]
                + rs[(2*64 + r)*5 + d] + (double)bs[d];
      so[d] = (float)sd;
    }
    s4[row] = make_float4(so[0], so[1], so[2], so[3]);
#pragma unroll
    for (int p4 = 0; p4 < 8; ++p4) {
      float o[4];
#pragma unroll
      for (int c = 0; c < 4; ++c) {
        int p = p4*4 + c;
        o[c] = hacc[p] + rh[(0*64 + r)*33 + p] + rh[(1*64 + r)*33 + p]
             + rh[(2*64 + r)*33 + p] + bh[p];
      }
      *(float4*)&h[(size_t)row*PD + p4*4] = make_float4(o[0], o[1], o[2], o[3]);
    }
  }
}

// ---------------- Kernel 2t: threshold + FUSED operand pack + FUSED weight pack -----
__global__ __launch_bounds__(256) void k2t_thresh(
    const float4* __restrict__ s4, uint4* __restrict__ sA, uint4* __restrict__ sB,
    const float* __restrict__ W1, const float* __restrict__ W2, float* __restrict__ wT) {
  __shared__ float4 tile[2064];
  __shared__ uint   lhist[256*NBIN];
  const int t = threadIdx.x;
  // fused k4a: pack/transpose weights (first 96 blocks, exactly 1 elem/thread)
  if (blockIdx.x < 96) {
    int idx = blockIdx.x*256 + t;
    int kk = idx >> 7, c = idx & 127;
    float v = (kk < 128) ? W1[(size_t)c*128 + kk] : W2[(size_t)c*64 + (kk - 128)];
    wT[(size_t)kk*COUT + c] = v;
  }
#pragma unroll
  for (int g = 0; g < 8; ++g) {
    int j = g*256 + t;
    tile[j + (j >> 7)] = s4[j];
  }
#pragma unroll
  for (int b = 0; b < NBIN; ++b) lhist[t*NBIN + b] = 0u;
  const int ql = t >> 4, tq = t & 15;
  const int q  = blockIdx.x*16 + ql;
  const float4 sq = s4[q];
  __syncthreads();
  float tau = d2f(sq, tile[tq*129]);
#pragma unroll
  for (int m = 1; m < 16; m <<= 1) tau = fmaxf(tau, __shfl_xor(tau, m, 16));
  const int ktop = (int)(__float_as_uint(tau) >> 21);
  const int hb = t*NBIN;
#pragma unroll 4
  for (int u = 0; u < 128; ++u) {
    float4 p = tile[tq*129 + u];
    float e = d2f(sq, p);
    int key = (int)(__float_as_uint(e) >> 21);
    int rel = ktop - key;
    rel = rel < 0 ? 0 : (rel > 32 ? 32 : rel);
    atomicAdd(&lhist[hb + rel], 1u);
  }
  __syncthreads();
  uint c0 = 0, c1 = 0;
  const int qb = ql*16;
  for (int u = 0; u < 16; ++u) {
    c0 += lhist[(qb + u)*NBIN + tq*2];
    c1 += (tq*2 + 1 < NBIN) ? lhist[(qb + u)*NBIN + tq*2 + 1] : 0u;
  }
  int S = (int)(c0 + c1);
#pragma unroll
  for (int d = 1; d < 16; d <<= 1) {
    int v = __shfl_down(S, d, 16);
    S += (tq + d < 16) ? v : 0;
  }
  int g = -1;
  if (S >= KNN) g = 2*tq;
  if (S - (int)c0 >= KNN) g = 2*tq + 1;
#pragma unroll
  for (int m = 1; m < 16; m <<= 1) g = max(g, __shfl_xor(g, m, 16));
  if (tq == 0) {
    uint K = (uint)(ktop - g);
    const float tv = __uint_as_float((K << 21) | 0x1FFFFFu);
    // ---- fused operand pack ----
    float sv[4] = {sq.x, sq.y, sq.z, sq.w};
    const float n2 = sq.x*sq.x + sq.y*sq.y + sq.z*sq.z + sq.w*sq.w;
    u16 hbv[4], lbv[4];
#pragma unroll
    for (int d = 0; d < 4; ++d) {
      u16 hh = f2bf(sv[d]);
      hbv[d] = hh;
      lbv[d] = f2bf(sv[d] - bf2f(hh));
    }
    const float aq = -0.5f*(n2 - tv) + EPAD;
    const float bn = -0.5f*n2;
    u16 aqh = f2bf(aq); u16 aql = f2bf(aq - bf2f(aqh));
    u16 bnh = f2bf(bn); u16 bnl = f2bf(bn - bf2f(bnh));
    const uint oneone = 0x3F803F80u;
    uint a0 = (uint)hbv[0] | ((uint)hbv[1] << 16);
    uint a1 = (uint)hbv[2] | ((uint)hbv[3] << 16);
    uint l0 = (uint)lbv[0] | ((uint)lbv[1] << 16);
    uint l1 = (uint)lbv[2] | ((uint)lbv[3] << 16);
    uint aqw = (uint)aqh | ((uint)aql << 16);
    uint bnw = (uint)bnh | ((uint)bnl << 16);
    uint4 A0; A0.x = a0; A0.y = a1; A0.z = a0; A0.w = a1;
    uint4 A1; A1.x = l0; A1.y = l1; A1.z = oneone; A1.w = aqw;
    uint4 B0; B0.x = a0; B0.y = a1; B0.z = l0; B0.w = l1;
    uint4 B1; B1.x = a0; B1.y = a1; B1.z = bnw; B1.w = oneone;
    sA[(size_t)q*2]     = A0;
    sA[(size_t)q*2 + 1] = A1;
    sB[(size_t)q*2]     = B0;
    sB[(size_t)q*2 + 1] = B1;
  }
}

// per-lane pack of 16 predicate bits from a 32x32 MFMA accumulator.
__device__ __forceinline__ uint packbits16(const f32x16 a, const int shft) {
  uint b[4];
#pragma unroll
  for (int g = 0; g < 4; ++g) {
    uint bg = 0u;
#pragma unroll
    for (int e = 3; e >= 0; --e)
      bg = bg + bg + ((~__float_as_uint(a[4*g + e])) >> 31);
    b[g] = bg;
  }
  return (b[0] | (b[1] << 8) | (b[2] << 16) | (b[3] << 24)) << shft;
}

// ---------------- Kernel 2b: N^2 Gram via 32x32x16 MFMA, per-lane bit pack -----------
// j-SPLIT grid: 64 q-blocks x 64 j-chunks (256 j each) = 4096 blocks, 8 KB LDS
// -> 8 blocks/CU x 4 waves = 32 waves/CU (HW cap). Bank swizzle on row halves.
__global__ __launch_bounds__(256) void k2b_mfma(
    const u16* __restrict__ sA, const u16* __restrict__ sB, uint4* __restrict__ maskw) {
  __shared__ u16 lB[256*16];                 // 8 KB: 256 j-rows x 32 B
  const int t   = threadIdx.x;
  const int wv  = t >> 6, ln = t & 63;
  const int l31 = ln & 31, hi = ln >> 5;
  const int qbase = (blockIdx.x >> 6) * 256 + wv * 64;
  const int jc    = blockIdx.x & 63;         // j-chunk of 256
  const int j0    = jc * 256;
  {
    const int r = t;                         // one row per thread
    const uint4* src = (const uint4*)&sB[(size_t)(j0 + r)*16];
    uint4 v0 = src[0], v1 = src[1];
    const int sw = (r >> 2) & 1;
    *(uint4*)&lB[r*16 + sw*8]       = v0;   // elements 0..7
    *(uint4*)&lB[r*16 + (sw^1)*8]   = v1;   // elements 8..15
  }
  const bf16x8 qf0 = *(const bf16x8*)&sA[(size_t)(qbase + l31)*16 + hi*8];
  const bf16x8 qf1 = *(const bf16x8*)&sA[(size_t)(qbase + 32 + l31)*16 + hi*8];
  __syncthreads();
  const int sh = hi * 4;
  const f32x16 zc = {0.f,0.f,0.f,0.f,0.f,0.f,0.f,0.f,0.f,0.f,0.f,0.f,0.f,0.f,0.f,0.f};
#pragma unroll 1
  for (int cc = 0; cc < 2; ++cc) {
    uint w0[4], w1[4];
#pragma unroll
    for (int jt = 0; jt < 4; ++jt) {
      const int row = cc*128 + jt*32 + l31;
      const bf16x8 af = *(const bf16x8*)&lB[row*16 + (hi ^ ((row >> 2) & 1))*8];
      f32x16 a0 = __builtin_amdgcn_mfma_f32_32x32x16_bf16(af, qf0, zc, 0, 0, 0);
      f32x16 a1 = __builtin_amdgcn_mfma_f32_32x32x16_bf16(af, qf1, zc, 0, 0, 0);
      w0[jt] = packbits16(a0, sh);
      w1[jt] = packbits16(a1, sh);
    }
    uint of[4];
#pragma unroll
    for (int jt = 0; jt < 4; ++jt) {
      uint f0 = w0[jt] | (uint)__shfl_xor((int)w0[jt], 32);
      uint f1 = w1[jt] | (uint)__shfl_xor((int)w1[jt], 32);
      of[jt] = hi ? f1 : f0;
    }
    const int c = jc*2 + cc;                 // chunk index 0..127
    uint4 o; o.x = of[0]; o.y = of[1]; o.z = of[2]; o.w = of[3];
    maskw[(size_t)c*NPTS + qbase + ln] = o;
  }
}

// ---------------- Kernel 3: low-LDS decode + exact re-rank + aggregation -------------
// block = 8 queries x 32 lanes. 27 KB LDS (MCAP=128). 4-way gather ILP in pass 1.
__global__ __launch_bounds__(256) void k3_sel2(
    const float4* __restrict__ s4, const float* __restrict__ h,
    const uint4* __restrict__ maskw, float* __restrict__ agg) {
  __shared__ unsigned short jl[QPB*QCAP];   // 8 KB
  __shared__ u16  cls[QPB*QCAP];            // 8 KB
  __shared__ u64  qbuf[QPB*MCAP];           // 8 KB
  __shared__ u64  win[QPB*KNN];             // 1 KB
  __shared__ uint hist[QPB*32];             // 1 KB
  __shared__ uint cnts[QPB];
  __shared__ uint mc[QPB];
  const int t  = threadIdx.x;
  const int ql = t >> 5, ln = t & 31;
  const int q  = blockIdx.x*QPB + ql;
  if (ln == 0) { cnts[ql] = 0u; mc[ql] = 0u; }
  hist[ql*32 + ln] = 0u;
  if (ln < KNN) win[ql*KNN + ln] = 0ull;
  const float4 sq = s4[q];
  __syncthreads();
  // ---- phase A: batch-issue all 4 mask loads, then decode (order-free compaction) ----
  const int qa = t & 7;
  const int cg = t >> 3;
  uint4 m[4];
#pragma unroll
  for (int u = 0; u < 4; ++u)
    m[u] = maskw[(size_t)(cg + u*32)*NPTS + blockIdx.x*QPB + qa];
  int pc = 0;
#pragma unroll
  for (int u = 0; u < 4; ++u)
    pc += __popc(m[u].x) + __popc(m[u].y) + __popc(m[u].z) + __popc(m[u].w);
  int base = (int)atomicAdd(&cnts[qa], (uint)pc);
#pragma unroll
  for (int u = 0; u < 4; ++u) {
    uint wvs[4] = {m[u].x, m[u].y, m[u].z, m[u].w};
#pragma unroll
    for (int w = 0; w < 4; ++w) {
      uint bits = wvs[w];
      const int jb = (cg + u*32)*128 + w*32;
      while (bits) {
        int b = __builtin_ctz(bits); bits &= bits - 1;
        if (base < QCAP) jl[qa*QCAP + base] = (unsigned short)(jb + b);
        ++base;
      }
    }
  }
  __syncthreads();
  const int cnt = min((int)cnts[ql], QCAP);
  // ---- pass 1: gather d2 once (4-way then 2-way ILP), store class, track kmax ----
  uint kmax = 0u;
  {
    int u = ln;
    for (; u + 96 < cnt; u += 128) {
      int j0v = jl[ql*QCAP + u];
      int j1v = jl[ql*QCAP + u + 32];
      int j2v = jl[ql*QCAP + u + 64];
      int j3v = jl[ql*QCAP + u + 96];
      float e0 = d2f(sq, s4[j0v]);
      float e1 = d2f(sq, s4[j1v]);
      float e2 = d2f(sq, s4[j2v]);
      float e3 = d2f(sq, s4[j3v]);
      uint c0v = __float_as_uint(e0) >> 21;
      uint c1v = __float_as_uint(e1) >> 21;
      uint c2v = __float_as_uint(e2) >> 21;
      uint c3v = __float_as_uint(e3) >> 21;
      cls[ql*QCAP + u]      = (u16)c0v;
      cls[ql*QCAP + u + 32] = (u16)c1v;
      cls[ql*QCAP + u + 64] = (u16)c2v;
      cls[ql*QCAP + u + 96] = (u16)c3v;
      kmax = max(kmax, max(max(c0v, c1v), max(c2v, c3v)));
    }
    for (; u + 32 < cnt; u += 64) {
      int ja = jl[ql*QCAP + u];
      int jb = jl[ql*QCAP + u + 32];
      float ea = d2f(sq, s4[ja]);
      float eb = d2f(sq, s4[jb]);
      uint ca = __float_as_uint(ea) >> 21;
      uint cb = __float_as_uint(eb) >> 21;
      cls[ql*QCAP + u]      = (u16)ca;
      cls[ql*QCAP + u + 32] = (u16)cb;
      kmax = max(kmax, max(ca, cb));
    }
    if (u < cnt) {
      int j = jl[ql*QCAP + u];
      float e = d2f(sq, s4[j]);
      uint cv = __float_as_uint(e) >> 21;
      cls[ql*QCAP + u] = (u16)cv;
      kmax = max(kmax, cv);
    }
  }
#pragma unroll
  for (int m2 = 1; m2 < 32; m2 <<= 1) kmax = max(kmax, (uint)__shfl_xor((int)kmax, m2, 32));
  // ---- histogram from class array (own-lane positions only) ----
  for (int u = ln; u < cnt; u += 32) {
    uint cv = cls[ql*QCAP + u];
    uint rel = min(kmax - cv, 31u);
    atomicAdd(&hist[ql*32 + rel], 1u);
  }
  __syncthreads();
  // ---- boundary: largest r* with cum(r*) >= need; bcls = kmax - r* ----
  uint cum = hist[ql*32 + ln];
#pragma unroll
  for (int d = 1; d < 32; d <<= 1) {
    uint v = (uint)__shfl_down((int)cum, d, 32);
    if (ln + d < 32) cum += v;
  }
  const uint need = (uint)(cnt < KNN ? cnt : KNN);
  u64 bal = __ballot(cum >= need);
  uint half = (uint)(bal >> (((t >> 5) & 1) * 32));
  const uint rstar = 31u - (uint)__builtin_clz(half);
  const uint bcls = kmax - rstar;
  __syncthreads();
  // ---- compact qualifiers: recompute exact d2 (bit-identical), build u64 key ----
  for (int u = ln; u < cnt; u += 32) {
    if ((uint)cls[ql*QCAP + u] <= bcls) {
      int j = jl[ql*QCAP + u];
      float e = d2f(sq, s4[j]);
      u64 key = ((u64)__float_as_uint(e) << 14) | (uint)j;
      uint pos = atomicAdd(&mc[ql], 1u);
      if (pos < MCAP) qbuf[ql*MCAP + pos] = key;
    }
  }
  __syncthreads();
  const int mcnt = (int)mc[ql];
  if (mcnt <= MCAP) {
    for (int w = ln; w < mcnt; w += 32) {
      u64 key = qbuf[ql*MCAP + w];
      int rank = 0;
      for (int v = 0; v < mcnt; ++v) rank += (qbuf[ql*MCAP + v] < key) ? 1 : 0;
      if (rank < KNN) win[ql*KNN + rank] = key;
    }
  } else {
    // ultra-rare correct fallback: rank each qualifier against ALL candidates
    for (int u = ln; u < cnt; u += 32) {
      if ((uint)cls[ql*QCAP + u] <= bcls) {
        int j = jl[ql*QCAP + u];
        float e = d2f(sq, s4[j]);
        u64 key = ((u64)__float_as_uint(e) << 14) | (uint)j;
        int rank = 0;
        for (int v = 0; v < cnt; ++v) {
          int jv = jl[ql*QCAP + v];
          float ev = d2f(sq, s4[jv]);
          u64 kv2 = ((u64)__float_as_uint(ev) << 14) | (uint)jv;
          rank += (kv2 < key) ? 1 : 0;
        }
        if (rank < KNN) win[ql*KNN + rank] = key;
      }
    }
  }
  __syncthreads();
  // ---- aggregation: 4-way unrolled (independent win->h gather chains) ----
  float sum = 0.f, mx = -FLTMAX;
#pragma unroll
  for (int r4 = 0; r4 < 4; ++r4) {
    u64 k0 = win[ql*KNN + r4*4 + 0];
    u64 k1 = win[ql*KNN + r4*4 + 1];
    u64 k2 = win[ql*KNN + r4*4 + 2];
    u64 k3v = win[ql*KNN + r4*4 + 3];
    int j0 = (int)(k0 & 16383u), j1 = (int)(k1 & 16383u);
    int j2 = (int)(k2 & 16383u), j3 = (int)(k3v & 16383u);
    float h0 = h[(size_t)j0*PD + ln];
    float h1 = h[(size_t)j1*PD + ln];
    float h2 = h[(size_t)j2*PD + ln];
    float h3 = h[(size_t)j3*PD + ln];
    float w0 = __expf(-10.f * __uint_as_float((uint)(k0 >> 14)));
    float w1 = __expf(-10.f * __uint_as_float((uint)(k1 >> 14)));
    float w2 = __expf(-10.f * __uint_as_float((uint)(k2 >> 14)));
    float w3 = __expf(-10.f * __uint_as_float((uint)(k3v >> 14)));
    float m0 = w0*h0, m1 = w1*h1, m2 = w2*h2, m3 = w3*h3;
    sum += m0 + m1 + m2 + m3;
    mx = fmaxf(mx, fmaxf(fmaxf(m0, m1), fmaxf(m2, m3)));
  }
  agg[(size_t)q*64 + ln]      = sum * 0.0625f;
  agg[(size_t)q*64 + 32 + ln] = mx;
}

// ================= Fallback path (round-2, proven) =================
__global__ __launch_bounds__(256) void k2_knn_fb(
    const float4* __restrict__ s4, unsigned short* __restrict__ cand_j) {
  __shared__ float4 tile[TJF];
  __shared__ int    lbuf[256*33];
  const int t  = threadIdx.x;
  const int ib = blockIdx.x & 31;
  const int jc = blockIdx.x >> 5;
  const int jbase = jc * TJF;
#pragma unroll
  for (int g = 0; g < 4; ++g) tile[g*256 + t] = s4[jbase + g*256 + t];
  const int ia = ib*256 + t;
  const int ic = ia + 8192;
  const float4 sa = s4[ia];
  const float4 sc = s4[ic];
  __syncthreads();
  float va[KNN], vb[KNN]; int ja[KNN], jb[KNN];
#pragma unroll
  for (int q = 0; q < KNN; ++q) { va[q] = FLTMAX; ja[q] = 0; vb[q] = FLTMAX; jb[q] = 0; }
  float cma = FLTMAX, cmb = FLTMAX;
  int cpa = 0, cpb = 0, ca = 0, cb = 0;
  auto insertA = [&](float e, int jj) {
#pragma unroll
    for (int q = 0; q < KNN; ++q) if (q == cpa) { va[q] = e; ja[q] = jj; }
    cma = va[0]; cpa = 0;
#pragma unroll
    for (int q = 1; q < KNN; ++q) { if (va[q] > cma) { cma = va[q]; cpa = q; } }
  };
  auto insertB = [&](float e, int jj) {
#pragma unroll
    for (int q = 0; q < KNN; ++q) if (q == cpb) { vb[q] = e; jb[q] = jj; }
    cmb = vb[0]; cpb = 0;
#pragma unroll
    for (int q = 1; q < KNN; ++q) { if (vb[q] > cmb) { cmb = vb[q]; cpb = q; } }
  };
  auto compactA = [&]() {
    for (int u = 0; u < ca; ++u) {
      int jj = lbuf[t*33 + u];
      float e = d2f(sa, tile[jj]);
      if (e < cma) insertA(e, jj);
    }
    ca = 0;
  };
  auto compactB = [&]() {
    for (int u = 0; u < cb; ++u) {
      int jj = lbuf[t*33 + 16 + u];
      float e = d2f(sc, tile[jj]);
      if (e < cmb) insertB(e, jj);
    }
    cb = 0;
  };
  for (int ob = 0; ob < TJF/8; ++ob) {
#pragma unroll
    for (int u = 0; u < 8; ++u) {
      int jj = ob*8 + u;
      float4 p = tile[jj];
      float ea = d2f(sa, p);
      float eb = d2f(sc, p);
      if (ea < cma) { lbuf[t*33 + ca] = jj; ++ca; }
      if (eb < cmb) { lbuf[t*33 + 16 + cb] = jj; ++cb; }
    }
    if (__any(ca > 8)) compactA();
    if (__any(cb > 8)) compactB();
  }
  compactA(); compactB();
#pragma unroll
  for (int q = 0; q < KNN; ++q) {
    int c = jc*KNN + q;
    cand_j[(size_t)c*NPTS + ia] = (unsigned short)(ja[q] + jbase);
    cand_j[(size_t)c*NPTS + ic] = (unsigned short)(jb[q] + jbase);
  }
}

__global__ __launch_bounds__(256) void k3_merge_fb(
    const float4* __restrict__ s4, const float4* __restrict__ h4,
    const unsigned short* __restrict__ cand_j, float* __restrict__ agg) {
  __shared__ float le[64*67];
  __shared__ int   lj[64*67];
  const int t  = threadIdx.x;
  const int il = t & 63, tq = t >> 6;
  const int i  = blockIdx.x*64 + il;
  const float4 si = s4[i];
  float val[KNN]; int vid[KNN];
#pragma unroll
  for (int q = 0; q < KNN; ++q) { val[q] = FLTMAX; vid[q] = 0; }
  float cmax = FLTMAX; int cpos = 0;
  for (int u = 0; u < 64; ++u) {
    int c = tq*64 + u;
    int j = cand_j[(size_t)c*NPTS + i];
    float e = d2f(si, s4[j]);
    if (e < cmax) {
#pragma unroll
      for (int q = 0; q < KNN; ++q) if (q == cpos) { val[q] = e; vid[q] = j; }
      cmax = val[0]; cpos = 0;
#pragma unroll
      for (int q = 1; q < KNN; ++q) { if (val[q] > cmax) { cmax = val[q]; cpos = q; } }
    }
  }
#pragma unroll
  for (int q = 0; q < KNN; ++q) {
    le[il*67 + tq*16 + q] = val[q];
    lj[il*67 + tq*16 + q] = vid[q];
  }
  __syncthreads();
  if (t < 64) {
    float mv[KNN]; int mj[KNN];
#pragma unroll
    for (int q = 0; q < KNN; ++q) { mv[q] = FLTMAX; mj[q] = 0; }
    float cm2 = FLTMAX; int cp2 = 0;
    for (int u = 0; u < 64; ++u) {
      float e = le[t*67 + u];
      int   j = lj[t*67 + u];
      if (e < cm2) {
#pragma unroll
        for (int q = 0; q < KNN; ++q) if (q == cp2) { mv[q] = e; mj[q] = j; }
        cm2 = mv[0]; cp2 = 0;
#pragma unroll
        for (int q = 1; q < KNN; ++q) { if (mv[q] > cm2) { cm2 = mv[q]; cp2 = q; } }
      }
    }
#pragma unroll
    for (int q = 0; q < KNN; ++q) {
      le[t*67 + q] = __expf(-10.f * mv[q]);
      lj[t*67 + q] = mj[q];
    }
  }
  __syncthreads();
  float ms[8], mm[8];
#pragma unroll
  for (int p = 0; p < 8; ++p) { ms[p] = 0.f; mm[p] = -FLTMAX; }
#pragma unroll 1
  for (int q = 0; q < KNN; ++q) {
    float w = le[il*67 + q];
    int   j = lj[il*67 + q];
    float4 a = h4[(size_t)j*8 + tq*2];
    float4 b = h4[(size_t)j*8 + tq*2 + 1];
    float m0 = a.x*w, m1 = a.y*w, m2 = a.z*w, m3 = a.w*w;
    float m4 = b.x*w, m5 = b.y*w, m6 = b.z*w, m7 = b.w*w;
    ms[0] += m0; mm[0] = fmaxf(mm[0], m0);
    ms[1] += m1; mm[1] = fmaxf(mm[1], m1);
    ms[2] += m2; mm[2] = fmaxf(mm[2], m2);
    ms[3] += m3; mm[3] = fmaxf(mm[3], m3);
    ms[4] += m4; mm[4] = fmaxf(mm[4], m4);
    ms[5] += m5; mm[5] = fmaxf(mm[5], m5);
    ms[6] += m6; mm[6] = fmaxf(mm[6], m6);
    ms[7] += m7; mm[7] = fmaxf(mm[7], m7);
  }
  float4 o0 = make_float4(ms[0]*0.0625f, ms[1]*0.0625f, ms[2]*0.0625f, ms[3]*0.0625f);
  float4 o1 = make_float4(ms[4]*0.0625f, ms[5]*0.0625f, ms[6]*0.0625f, ms[7]*0.0625f);
  *(float4*)&agg[(size_t)i*64 + tq*8]      = o0;
  *(float4*)&agg[(size_t)i*64 + tq*8 + 4]  = o1;
  *(float4*)&agg[(size_t)i*64 + 32 + tq*8]     = make_float4(mm[0], mm[1], mm[2], mm[3]);
  *(float4*)&agg[(size_t)i*64 + 32 + tq*8 + 4] = make_float4(mm[4], mm[5], mm[6], mm[7]);
}

// ---------------- Kernel 4a: pack/transpose weights (fallback path only) -------------
__global__ __launch_bounds__(256) void k4a_wt(
    const float* __restrict__ W1, const float* __restrict__ W2, float* __restrict__ wT) {
  int idx = blockIdx.x*256 + threadIdx.x;
  if (idx >= 192*COUT) return;
  int k = idx >> 7, c = idx & 127;
  float v = (k < 128) ? W1[(size_t)c*128 + k] : W2[(size_t)c*64 + (k - 128)];
  wT[(size_t)k*COUT + c] = v;
}

// ---------------- Kernel 4: out = x@W1^T + agg@W2^T + b2 (32x128 tile, 4x4/thread) ----------
__global__ __launch_bounds__(256) void k4_out2(
    const float* __restrict__ x, const float* __restrict__ agg,
    const float* __restrict__ wT, const float* __restrict__ b2,
    float* __restrict__ out) {
  __shared__ float xa[32*192];
  const int t = threadIdx.x;
  const int row0 = blockIdx.x * 32;
#pragma unroll
  for (int g = 0; g < 4; ++g) {
    int fi = g*256 + t;
    int r = fi >> 5, c4 = fi & 31;
    *(float4*)&xa[r*192 + c4*4] = *(const float4*)&x[(size_t)(row0+r)*CIN + c4*4];
  }
#pragma unroll
  for (int g = 0; g < 2; ++g) {
    int fi = g*256 + t;
    int r = fi >> 4, c4 = fi & 15;
    *(float4*)&xa[r*192 + 128 + c4*4] = *(const float4*)&agg[(size_t)(row0+r)*64 + c4*4];
  }
  __syncthreads();
  const int c4 = t & 31;
  const int rg = t >> 5;
  float acc[4][4];
#pragma unroll
  for (int r = 0; r < 4; ++r) { acc[r][0]=0.f; acc[r][1]=0.f; acc[r][2]=0.f; acc[r][3]=0.f; }
  for (int k = 0; k < 192; k += 4) {
    float4 w0 = *(const float4*)&wT[(size_t)(k+0)*COUT + c4*4];
    float4 w1 = *(const float4*)&wT[(size_t)(k+1)*COUT + c4*4];
    float4 w2 = *(const float4*)&wT[(size_t)(k+2)*COUT + c4*4];
    float4 w3 = *(const float4*)&wT[(size_t)(k+3)*COUT + c4*4];
#pragma unroll
    for (int r = 0; r < 4; ++r) {
      float4 xv = *(const float4*)&xa[(rg*4 + r)*192 + k];
      acc[r][0] = fmaf(xv.x, w0.x, fmaf(xv.y, w1.x, fmaf(xv.z, w2.x, fmaf(xv.w, w3.x, acc[r][0]))));
      acc[r][1] = fmaf(xv.x, w0.y, fmaf(xv.y, w1.y, fmaf(xv.z, w2.y, fmaf(xv.w, w3.y, acc[r][1]))));
      acc[r][2] = fmaf(xv.x, w0.z, fmaf(xv.y, w1.z, fmaf(xv.z, w2.z, fmaf(xv.w, w3.z, acc[r][2]))));
      acc[r][3] = fmaf(xv.x, w0.w, fmaf(xv.y, w1.w, fmaf(xv.z, w2.w, fmaf(xv.w, w3.w, acc[r][3]))));
    }
  }
  float4 bias = *(const float4*)&b2[c4*4];
#pragma unroll
  for (int r = 0; r < 4; ++r) {
    float4 o = make_float4(acc[r][0]+bias.x, acc[r][1]+bias.y, acc[r][2]+bias.z, acc[r][3]+bias.w);
    *(float4*)&out[(size_t)(row0 + rg*4 + r)*COUT + c4*4] = o;
  }
}

extern "C" void kernel_launch(void* const* d_in, const int* in_sizes, int n_in,
                              void* d_out, int out_size, void* d_ws, size_t ws_size,
                              hipStream_t stream) {
  const float* x  = (const float*)d_in[0];
  const float* Ws = (const float*)d_in[1];
  const float* bs = (const float*)d_in[2];
  const float* Wh = (const float*)d_in[3];
  const float* bh = (const float*)d_in[4];
  const float* W1 = (const float*)d_in[5];
  const float* W2 = (const float*)d_in[6];
  const float* b2 = (const float*)d_in[7];
  float* out = (float*)d_out;

  char* ws = (char*)d_ws;
  float4* s4 = (float4*)(ws + WS_S4);
  float*  h  = (float*) (ws + WS_H);

  k1_proj<<<NPTS/64, 256, 0, stream>>>(x, Ws, bs, Wh, bh, s4, h);

  if (ws_size >= (size_t)WS_NEED_M) {
    float* agg = (float*)(ws + WS_AGG_M);
    float* wT  = (float*)(ws + WS_WT_M);
    uint4* sa  = (uint4*)(ws + WS_SA);
    uint4* sb  = (uint4*)(ws + WS_SB);
    uint4* mw  = (uint4*)(ws + WS_MASK);
    k2t_thresh<<<NPTS/16, 256, 0, stream>>>(s4, sa, sb, W1, W2, wT);
    k2b_mfma<<<4096, 256, 0, stream>>>((const u16*)sa, (const u16*)sb, mw);
    k3_sel2<<<NPTS/QPB, 256, 0, stream>>>(s4, h, (const uint4*)mw, agg);
    k4_out2<<<NPTS/32, 256, 0, stream>>>(x, agg, wT, b2, out);
  } else {
    unsigned short* cj = (unsigned short*)(ws + WS_CJ_F);
    float* agg = (float*)(ws + WS_AGG_F);
    float* wT  = (float*)(ws + WS_WT_F);
    k2_knn_fb<<<512, 256, 0, stream>>>(s4, cj);
    k3_merge_fb<<<NPTS/64, 256, 0, stream>>>(s4, (const float4*)h, cj, agg);
    k4a_wt<<<(192*COUT + 255)/256, 256, 0, stream>>>(W1, W2, wT);
    k4_out2<<<NPTS/32, 256, 0, stream>>>(x, agg, wT, b2, out);
  }
}